// Round 2
// baseline (1397.924 us; speedup 1.0000x reference)
//
#include <hip/hip_runtime.h>
#include <stdint.h>

#define B_    4
#define N_    2048
#define M_    2048
#define DIMX  512
#define INNER 512
#define H_    8
#define DH    64
#define MK    2049   // M+1 keys (null token at slot 0)

// ---------------------------------------------------------------------------
// Generic 64x64-tile fp32 GEMM.
// MODE 0: C0[R*Ncols+c] = tanh(acc)                      (q projection)
// MODE 1: split kv: c<512 -> k (tanh) scattered to [b,h,m+1,d]; else v
// MODE 2: C0[R*Ncols+c] = acc + bias[c]                  (out projection)
// ---------------------------------------------------------------------------
template<int MODE>
__global__ __launch_bounds__(256) void gemm_k(
    const float* __restrict__ A, const float* __restrict__ Bm,
    const float* __restrict__ bias,
    float* __restrict__ C0, float* __restrict__ C1,
    int K, int Ncols)
{
  __shared__ float As[64][17];
  __shared__ float Bs[16][64];
  const int tx = threadIdx.x, ty = threadIdx.y;
  const int tid = ty * 16 + tx;
  const int row0 = blockIdx.y * 64;
  const int c0   = blockIdx.x * 64;
  const int ar = tid >> 2,  ak = (tid & 3) * 4;
  const int bk = tid >> 4,  bc = (tid & 15) * 4;

  float acc[4][4] = {};

  for (int k0 = 0; k0 < K; k0 += 16){
    __syncthreads();
    {
      float4 t = *(const float4*)(A + (size_t)(row0 + ar) * K + (k0 + ak));
      As[ar][ak+0] = t.x; As[ar][ak+1] = t.y;
      As[ar][ak+2] = t.z; As[ar][ak+3] = t.w;
    }
    {
      float4 t = *(const float4*)(Bm + (size_t)(k0 + bk) * Ncols + (c0 + bc));
      Bs[bk][bc+0] = t.x; Bs[bk][bc+1] = t.y;
      Bs[bk][bc+2] = t.z; Bs[bk][bc+3] = t.w;
    }
    __syncthreads();
    #pragma unroll
    for (int kk = 0; kk < 16; ++kk){
      float4 bv = *(const float4*)(&Bs[kk][tx*4]);
      #pragma unroll
      for (int i = 0; i < 4; ++i){
        float a = As[ty*4 + i][kk];
        acc[i][0] += a * bv.x;
        acc[i][1] += a * bv.y;
        acc[i][2] += a * bv.z;
        acc[i][3] += a * bv.w;
      }
    }
  }

  #pragma unroll
  for (int i = 0; i < 4; ++i){
    const int R = row0 + ty*4 + i;
    #pragma unroll
    for (int j = 0; j < 4; ++j){
      const int c = c0 + tx*4 + j;
      float v = acc[i][j];
      if (MODE == 0){
        C0[(size_t)R * Ncols + c] = tanhf(v);
      } else if (MODE == 1){
        const int b = R >> 11, m = R & 2047;
        if (c < INNER){
          const int h = c >> 6, d = c & 63;
          C0[((size_t)(b*H_ + h) * MK + (m + 1)) * DH + d] = tanhf(v);
        } else {
          const int cc = c - INNER;
          const int h = cc >> 6, d = cc & 63;
          C1[((size_t)(b*H_ + h) * MK + (m + 1)) * DH + d] = v;
        }
      } else {
        C0[(size_t)R * Ncols + c] = v + bias[c];
      }
    }
  }
}

// Fill null-token slot (key index 0) for every (b,h): k = tanh(null_k), v = null_v
__global__ void fill_null_k(const float* __restrict__ nk, const float* __restrict__ nv,
                            float* __restrict__ kb, float* __restrict__ vb)
{
  const int i  = blockIdx.x * 256 + threadIdx.x;   // 0..2047 = bh*64 + d
  const int d  = i & 63, bh = i >> 6;
  const size_t off = (size_t)bh * MK * DH + d;
  kb[off] = tanhf(nk[d]);
  vb[off] = nv[d];
}

// ---------------------------------------------------------------------------
// Flash attention: 1 thread = 1 query row. K/V tiles (64 keys x 64 dims)
// staged to LDS. Deferred-rescale online softmax: only rescale o[] when the
// running max grows by > 4  ->  p <= e^4, l <= 2049*e^4 ~ 1.1e5, safely fp32.
// ---------------------------------------------------------------------------
__global__ __launch_bounds__(256) void attn_k(
    const float* __restrict__ qb, const float* __restrict__ kb,
    const float* __restrict__ vb, float* __restrict__ aob)
{
  __shared__ float ks[64*64];
  __shared__ float vs[64*64];
  const int bh = blockIdx.y;            // b*8 + h
  const int b  = bh >> 3, h = bh & 7;
  const int n  = blockIdx.x * 256 + threadIdx.x;

  float q[64], o[64];
  const float* qrow = qb + ((size_t)(b*N_ + n)) * INNER + h * DH;
  #pragma unroll
  for (int c = 0; c < 16; ++c){
    float4 t = ((const float4*)qrow)[c];
    q[c*4+0] = t.x; q[c*4+1] = t.y; q[c*4+2] = t.z; q[c*4+3] = t.w;
  }
  #pragma unroll
  for (int d = 0; d < 64; ++d) o[d] = 0.f;
  float mrun = -1e30f, lrun = 0.f;

  const float* kbase = kb + (size_t)bh * MK * DH;
  const float* vbase = vb + (size_t)bh * MK * DH;

  const int r  = threadIdx.x >> 2;        // staging: row within tile
  const int cb = (threadIdx.x & 3) * 16;  // staging: 16-elem column chunk

  for (int t0 = 0; t0 < MK; t0 += 64){
    const int cnt = (MK - t0 < 64) ? (MK - t0) : 64;
    __syncthreads();
    if (r < cnt){
      const float4* sk = (const float4*)(kbase + (size_t)(t0 + r) * DH + cb);
      const float4* sv = (const float4*)(vbase + (size_t)(t0 + r) * DH + cb);
      float4* dk = (float4*)(ks + r*64 + cb);
      float4* dv = (float4*)(vs + r*64 + cb);
      #pragma unroll
      for (int c = 0; c < 4; ++c) dk[c] = sk[c];
      #pragma unroll
      for (int c = 0; c < 4; ++c) dv[c] = sv[c];
    }
    __syncthreads();

    for (int j = 0; j < cnt; ++j){
      const float4* kr = (const float4*)(ks + j*64);
      float s0 = 0.f, s1 = 0.f, s2 = 0.f, s3 = 0.f;
      #pragma unroll
      for (int c = 0; c < 16; ++c){
        float4 t = kr[c];
        s0 += q[c*4+0] * t.x;
        s1 += q[c*4+1] * t.y;
        s2 += q[c*4+2] * t.z;
        s3 += q[c*4+3] * t.w;
      }
      float s = ((s0 + s1) + (s2 + s3)) * 0.125f;
      if (s > mrun + 4.f){
        float corr = __expf(mrun - s);
        lrun *= corr;
        #pragma unroll
        for (int d = 0; d < 64; ++d) o[d] *= corr;
        mrun = s;
      }
      float p = __expf(s - mrun);
      lrun += p;
      const float4* vr = (const float4*)(vs + j*64);
      #pragma unroll
      for (int c = 0; c < 16; ++c){
        float4 t = vr[c];
        o[c*4+0] += p * t.x;
        o[c*4+1] += p * t.y;
        o[c*4+2] += p * t.z;
        o[c*4+3] += p * t.w;
      }
    }
  }

  const float inv = 1.f / lrun;
  float* orow = aob + ((size_t)(b*N_ + n)) * INNER + h * DH;
  #pragma unroll
  for (int c = 0; c < 16; ++c){
    float4 t;
    t.x = o[c*4+0]*inv; t.y = o[c*4+1]*inv;
    t.z = o[c*4+2]*inv; t.w = o[c*4+3]*inv;
    ((float4*)orow)[c] = t;
  }
}

extern "C" void kernel_launch(void* const* d_in, const int* in_sizes, int n_in,
                              void* d_out, int out_size, void* d_ws, size_t ws_size,
                              hipStream_t stream)
{
  const float* x    = (const float*)d_in[0];
  const float* ctx  = (const float*)d_in[1];
  const float* Wq   = (const float*)d_in[2];
  const float* Wkv  = (const float*)d_in[3];
  const float* nk   = (const float*)d_in[4];
  const float* nv   = (const float*)d_in[5];
  const float* Wout = (const float*)d_in[6];
  const float* bout = (const float*)d_in[7];
  float* out = (float*)d_out;

  char* ws = (char*)d_ws;
  const size_t qS = (size_t)B_ * N_ * INNER * 4;    // 16.78 MB
  const size_t kS = (size_t)B_ * H_ * MK * DH * 4;  // 16.79 MB
  float* qb = (float*)(ws);
  float* kb = (float*)(ws + qS);
  float* vb = (float*)(ws + qS + kS);
  float* ao = (float*)(ws + qS + 2*kS);             // total ~67 MB

  dim3 blk(16, 16);
  // q = tanh(x @ Wq)        [8192 x 512] = [8192 x 512] @ [512 x 512]
  gemm_k<0><<<dim3(INNER/64, (B_*N_)/64), blk, 0, stream>>>(
      x, Wq, nullptr, qb, nullptr, DIMX, INNER);
  // kv = ctx @ Wkv          [8192 x 1024], split/scatter to k (tanh) and v
  gemm_k<1><<<dim3((2*INNER)/64, (B_*M_)/64), blk, 0, stream>>>(
      ctx, Wkv, nullptr, kb, vb, DIMX, 2*INNER);
  // null token at key slot 0
  fill_null_k<<<(B_*H_*DH)/256, 256, 0, stream>>>(nk, nv, kb, vb);
  // flash attention -> ao [b, n, h*64]
  attn_k<<<dim3(N_/256, B_*H_), 256, 0, stream>>>(qb, kb, vb, ao);
  // out = ao @ Wout + bout  [8192 x 512] -> d_out
  gemm_k<2><<<dim3(512/64, (B_*N_)/64), blk, 0, stream>>>(
      ao, Wout, bout, out, nullptr, INNER, 512);
}

// Round 3
// 425.596 us; speedup vs baseline: 3.2846x; 3.2846x over previous
//
#include <hip/hip_runtime.h>
#include <stdint.h>

#define B_    4
#define N_    2048
#define M_    2048
#define DIMX  512
#define INNER 512
#define H_    8
#define DH    64
#define MK    2049   // M+1 keys (null token at slot 0)
#define MKP   2080   // padded to 65 tiles of 32 (tail masked in-kernel)

using u16 = unsigned short;
using u32 = unsigned int;

typedef __attribute__((ext_vector_type(8))) short short8;
typedef __attribute__((ext_vector_type(4))) float f32x4;

__device__ __forceinline__ u16 f2bf(float f){
  union { float f; u32 u; } x; x.f = f;
  u32 r = 0x7fffu + ((x.u >> 16) & 1u);
  return (u16)((x.u + r) >> 16);
}

// ---------------------------------------------------------------------------
// 64x64-tile fp32 GEMM.
// MODE 0: qb[R][c]  = bf16(tanh(acc))                       (q projection)
// MODE 1: c<512 -> kb[bh][m+1][d] = bf16(tanh(acc));  else vt[bh][d][m+1] = bf16(acc)
// MODE 2: outf[R][c] = acc + bias[c]                        (out projection)
// ---------------------------------------------------------------------------
template<int MODE>
__global__ __launch_bounds__(256) void gemm_k(
    const float* __restrict__ A, const float* __restrict__ Bm,
    const float* __restrict__ bias,
    float* __restrict__ Cf, u16* __restrict__ C0, u16* __restrict__ C1,
    int K, int Ncols)
{
  __shared__ float As[64][17];
  __shared__ float Bs[16][64];
  const int tx = threadIdx.x, ty = threadIdx.y;
  const int tid = ty * 16 + tx;
  const int row0 = blockIdx.y * 64;
  const int c0   = blockIdx.x * 64;
  const int ar = tid >> 2,  ak = (tid & 3) * 4;
  const int bk = tid >> 4,  bc = (tid & 15) * 4;

  float acc[4][4] = {};

  for (int k0 = 0; k0 < K; k0 += 16){
    __syncthreads();
    {
      float4 t = *(const float4*)(A + (size_t)(row0 + ar) * K + (k0 + ak));
      As[ar][ak+0] = t.x; As[ar][ak+1] = t.y;
      As[ar][ak+2] = t.z; As[ar][ak+3] = t.w;
    }
    {
      float4 t = *(const float4*)(Bm + (size_t)(k0 + bk) * Ncols + (c0 + bc));
      Bs[bk][bc+0] = t.x; Bs[bk][bc+1] = t.y;
      Bs[bk][bc+2] = t.z; Bs[bk][bc+3] = t.w;
    }
    __syncthreads();
    #pragma unroll
    for (int kk = 0; kk < 16; ++kk){
      float4 bv = *(const float4*)(&Bs[kk][tx*4]);
      #pragma unroll
      for (int i = 0; i < 4; ++i){
        float a = As[ty*4 + i][kk];
        acc[i][0] += a * bv.x;
        acc[i][1] += a * bv.y;
        acc[i][2] += a * bv.z;
        acc[i][3] += a * bv.w;
      }
    }
  }

  #pragma unroll
  for (int i = 0; i < 4; ++i){
    const int R = row0 + ty*4 + i;
    #pragma unroll
    for (int j = 0; j < 4; ++j){
      const int c = c0 + tx*4 + j;
      float v = acc[i][j];
      if (MODE == 0){
        C0[(size_t)R * Ncols + c] = f2bf(tanhf(v));
      } else if (MODE == 1){
        const int b = R >> 11, mm = R & 2047;
        if (c < INNER){
          const int h = c >> 6, d = c & 63;
          C0[((size_t)(b*H_ + h) * MKP + (mm + 1)) * DH + d] = f2bf(tanhf(v));
        } else {
          const int cc = c - INNER;
          const int h = cc >> 6, d = cc & 63;
          C1[((size_t)(b*H_ + h) * DH + d) * MKP + (mm + 1)] = f2bf(v);
        }
      } else {
        Cf[(size_t)R * Ncols + c] = v + bias[c];
      }
    }
  }
}

// Null-token (key slot 0) for every (b,h): k = tanh(null_k), v = null_v
__global__ void fill_null_k(const float* __restrict__ nk, const float* __restrict__ nv,
                            u16* __restrict__ kb, u16* __restrict__ vt)
{
  const int i  = blockIdx.x * 256 + threadIdx.x;   // 0..2047 = bh*64 + d
  const int d  = i & 63, bh = i >> 6;
  kb[(size_t)bh * MKP * DH + d]        = f2bf(tanhf(nk[d]));
  vt[((size_t)bh * DH + d) * MKP + 0]  = f2bf(nv[d]);
}

// ---------------------------------------------------------------------------
// MFMA flash attention. Block = 4 waves, each wave owns 16 query rows.
// Per 32-key tile: stage K (XOR-swizzled rows) + Vt ([kgrp][dim][8key]) to LDS,
// QK^T via 2x2 mfma_16x16x32_bf16, in-register online softmax (shfl_xor over
// 16-lane column groups, deferred rescale THR=4), P->bf16 via per-wave P_lds,
// PV via 4 mfma. O accumulates fp32; out written fp32.
// ---------------------------------------------------------------------------
__global__ __launch_bounds__(256) void attn_mfma(
    const u16* __restrict__ qb, const u16* __restrict__ kb,
    const u16* __restrict__ vt, float* __restrict__ aob)
{
  __shared__ __align__(16) short Kl[32*64];      // 4KB, rows swizzled
  __shared__ __align__(16) short Vl[4*64*8];     // 4KB, [kgrp][dim][8key]
  __shared__ __align__(16) short Pl[4][16][40];  // 5KB, per-wave P (pad->80B rows)

  const int tid  = threadIdx.x;
  const int w    = tid >> 6;
  const int lane = tid & 63;
  const int c    = lane & 15;      // MFMA col (key for S, dim for O)
  const int g    = lane >> 4;      // lane group
  const int bh   = blockIdx.y, b = bh >> 3, h = bh & 7;
  const int qbase = blockIdx.x * 64 + w * 16;

  // Q A-fragments (row = query qbase+c, 8 contiguous dims per k-half)
  short8 qf0, qf1;
  {
    const u16* qrow = qb + ((size_t)(b*N_) + qbase + c) * INNER + h * DH;
    qf0 = *(const short8*)(qrow + g*8);
    qf1 = *(const short8*)(qrow + 32 + g*8);
  }

  f32x4 o[4] = {};                 // O accum: 4 dim-blocks x 4 query rows
  float m[4], l[4];
  #pragma unroll
  for (int r = 0; r < 4; ++r){ m[r] = -3.0e38f; l[r] = 0.f; }

  const u16* kbase = kb + (size_t)bh * MKP * DH;
  const u16* vbase = vt + (size_t)bh * DH * MKP;

  const int skey = tid >> 3, sch = tid & 7;   // K staging: key row, 16B chunk
  const int vd   = tid >> 2, vkc = tid & 3;   // V staging: dim row, 8-key chunk

  for (int kt = 0; kt < 65; ++kt){
    __syncthreads();
    {  // K tile: LDS pos (row, X) holds global chunk X ^ ((row&7)<<4)
      uint4 t = *(const uint4*)(kbase + (size_t)(kt*32 + skey) * DH
                                + ((sch ^ (skey & 7)) * 8));
      *(uint4*)((char*)Kl + skey*128 + sch*16) = t;
    }
    {  // Vt tile: Vl[kgrp][dim][8key]
      uint4 t = *(const uint4*)(vbase + (size_t)vd * MKP + kt*32 + vkc*8);
      *(uint4*)((char*)Vl + vkc*1024 + vd*16) = t;
    }
    __syncthreads();

    // ---- QK^T: S[16q x 32k] as two 16x16 tiles ----
    f32x4 sv0, sv1;
    {
      f32x4 acc = {0.f,0.f,0.f,0.f};
      const int row = c;                       // keys kt*32 + 0..15
      #pragma unroll
      for (int hh = 0; hh < 2; ++hh){
        const int cb = hh*64 + g*16;
        short8 kf = *(const short8*)((char*)Kl + row*128 + (cb ^ ((row & 7) << 4)));
        acc = __builtin_amdgcn_mfma_f32_16x16x32_bf16(hh ? qf1 : qf0, kf, acc, 0, 0, 0);
      }
      sv0 = acc;
    }
    {
      f32x4 acc = {0.f,0.f,0.f,0.f};
      const int row = 16 + c;                  // keys kt*32 + 16..31
      #pragma unroll
      for (int hh = 0; hh < 2; ++hh){
        const int cb = hh*64 + g*16;
        short8 kf = *(const short8*)((char*)Kl + row*128 + (cb ^ ((row & 7) << 4)));
        acc = __builtin_amdgcn_mfma_f32_16x16x32_bf16(hh ? qf1 : qf0, kf, acc, 0, 0, 0);
      }
      sv1 = acc;
    }
    #pragma unroll
    for (int r = 0; r < 4; ++r){ sv0[r] *= 0.125f; sv1[r] *= 0.125f; }
    if (kt == 64){                             // mask keys >= 2049
      if (c >= 1){
        #pragma unroll
        for (int r = 0; r < 4; ++r) sv0[r] = -1e30f;
      }
      #pragma unroll
      for (int r = 0; r < 4; ++r) sv1[r] = -1e30f;
    }

    // ---- online softmax (rows = queries g*4+r; cols = 16 lanes of group) ----
    float tm[4], ps[4];
    #pragma unroll
    for (int r = 0; r < 4; ++r) tm[r] = fmaxf(sv0[r], sv1[r]);
    #pragma unroll
    for (int msk = 1; msk <= 8; msk <<= 1){
      #pragma unroll
      for (int r = 0; r < 4; ++r)
        tm[r] = fmaxf(tm[r], __shfl_xor(tm[r], msk, 16));
    }
    #pragma unroll
    for (int r = 0; r < 4; ++r){
      if (tm[r] > m[r] + 4.f){                 // deferred rescale (p <= e^4)
        const float corr = __expf(m[r] - tm[r]);
        l[r] *= corr;
        #pragma unroll
        for (int D = 0; D < 4; ++D) o[D][r] *= corr;
        m[r] = tm[r];
      }
      const float p0 = __expf(sv0[r] - m[r]);
      const float p1 = __expf(sv1[r] - m[r]);
      ps[r] = p0 + p1;
      Pl[w][g*4 + r][c]      = (short)f2bf(p0);
      Pl[w][g*4 + r][16 + c] = (short)f2bf(p1);
    }
    #pragma unroll
    for (int msk = 1; msk <= 8; msk <<= 1){
      #pragma unroll
      for (int r = 0; r < 4; ++r)
        ps[r] += __shfl_xor(ps[r], msk, 16);
    }
    #pragma unroll
    for (int r = 0; r < 4; ++r) l[r] += ps[r];

    // ---- PV: O[16q x 64d] += P[16x32] @ V[32x64] ----
    short8 pf = *(const short8*)&Pl[w][c][g*8];   // A-frag: row=query c
    #pragma unroll
    for (int D = 0; D < 4; ++D){
      short8 vf = *(const short8*)((char*)Vl + g*1024 + (D*16 + c)*16);
      o[D] = __builtin_amdgcn_mfma_f32_16x16x32_bf16(pf, vf, o[D], 0, 0, 0);
    }
  }

  // ---- epilogue: normalize, write fp32 [b, n, h*64+d] ----
  #pragma unroll
  for (int r = 0; r < 4; ++r){
    const float inv = 1.f / l[r];
    const size_t nrow = (size_t)(b*N_) + qbase + g*4 + r;
    #pragma unroll
    for (int D = 0; D < 4; ++D)
      aob[nrow * INNER + h*DH + D*16 + c] = o[D][r] * inv;
  }
}

extern "C" void kernel_launch(void* const* d_in, const int* in_sizes, int n_in,
                              void* d_out, int out_size, void* d_ws, size_t ws_size,
                              hipStream_t stream)
{
  const float* x    = (const float*)d_in[0];
  const float* ctx  = (const float*)d_in[1];
  const float* Wq   = (const float*)d_in[2];
  const float* Wkv  = (const float*)d_in[3];
  const float* nk   = (const float*)d_in[4];
  const float* nv   = (const float*)d_in[5];
  const float* Wout = (const float*)d_in[6];
  const float* bout = (const float*)d_in[7];
  float* out = (float*)d_out;

  char* ws = (char*)d_ws;
  const size_t qS = (size_t)B_ * N_ * INNER * 2;      // 8.39 MB  (bf16 q)
  const size_t kS = (size_t)B_ * H_ * MKP * DH * 2;   // 8.52 MB  (bf16 k rows)
  const size_t vS = kS;                               // 8.52 MB  (bf16 v^T)
  u16*   qb = (u16*)(ws);
  u16*   kb = (u16*)(ws + qS);
  u16*   vtb= (u16*)(ws + qS + kS);
  float* ao = (float*)(ws + qS + kS + vS);            // 16.8 MB fp32

  dim3 blk(16, 16);
  // q = bf16(tanh(x @ Wq))
  gemm_k<0><<<dim3(INNER/64, (B_*N_)/64), blk, 0, stream>>>(
      x, Wq, nullptr, nullptr, qb, nullptr, DIMX, INNER);
  // kv = ctx @ Wkv -> kb (tanh, row-major) and vt (transposed)
  gemm_k<1><<<dim3((2*INNER)/64, (B_*M_)/64), blk, 0, stream>>>(
      ctx, Wkv, nullptr, nullptr, kb, vtb, DIMX, 2*INNER);
  fill_null_k<<<(B_*H_*DH)/256, 256, 0, stream>>>(nk, nv, kb, vtb);
  // MFMA flash attention -> ao fp32 [b, n, 512]
  attn_mfma<<<dim3(N_/64, B_*H_), 256, 0, stream>>>(qb, kb, vtb, ao);
  // out = ao @ Wout + bout
  gemm_k<2><<<dim3(512/64, (B_*N_)/64), blk, 0, stream>>>(
      ao, Wout, bout, out, nullptr, nullptr, INNER, 512);
}

// Round 4
// 255.548 us; speedup vs baseline: 5.4703x; 1.6654x over previous
//
#include <hip/hip_runtime.h>
#include <stdint.h>

#define B_    4
#define N_    2048
#define M_    2048
#define DIMX  512
#define INNER 512
#define H_    8
#define DH    64
#define MK    2049   // M+1 keys (null token at slot 0)
#define MKP   2112   // padded to 33 tiles of 64 (tail masked in-kernel)

using u16 = unsigned short;
using u32 = unsigned int;

typedef __attribute__((ext_vector_type(8))) short short8;
typedef __attribute__((ext_vector_type(4))) float f32x4;

__device__ __forceinline__ u16 f2bf(float f){
  union { float f; u32 u; } x; x.f = f;
  u32 r = 0x7fffu + ((x.u >> 16) & 1u);
  return (u16)((x.u + r) >> 16);
}

// ---------------------------------------------------------------------------
// fp32 -> bf16 elementwise convert (8 elems/thread)
// ---------------------------------------------------------------------------
__global__ __launch_bounds__(256) void convert_bf(
    const float* __restrict__ in, u16* __restrict__ out)
{
  const int i = blockIdx.x * 256 + threadIdx.x;
  float4 a = ((const float4*)in)[i*2];
  float4 b = ((const float4*)in)[i*2+1];
  uint4 t;
  t.x = (u32)f2bf(a.x) | ((u32)f2bf(a.y) << 16);
  t.y = (u32)f2bf(a.z) | ((u32)f2bf(a.w) << 16);
  t.z = (u32)f2bf(b.x) | ((u32)f2bf(b.y) << 16);
  t.w = (u32)f2bf(b.z) | ((u32)f2bf(b.w) << 16);
  ((uint4*)out)[i] = t;
}

// ---------------------------------------------------------------------------
// fp32 [R][C] -> bf16 [C][R] transpose-convert, 64x64 LDS tiles
// ---------------------------------------------------------------------------
__global__ __launch_bounds__(256) void transpose_wt(
    const float* __restrict__ in, u16* __restrict__ out, int R, int C)
{
  __shared__ float tl[64][65];
  const int t = threadIdx.x;
  const int c0 = blockIdx.x * 64, r0 = blockIdx.y * 64;
  const int col = t & 63, rb = t >> 6;
  #pragma unroll
  for (int j = 0; j < 16; ++j){
    const int row = rb + j*4;
    tl[row][col] = in[(size_t)(r0 + row) * C + c0 + col];
  }
  __syncthreads();
  #pragma unroll
  for (int j = 0; j < 16; ++j){
    const int orow = rb + j*4;        // output row = original col
    out[(size_t)(c0 + orow) * R + r0 + col] = f2bf(tl[col][orow]);
  }
}

// ---------------------------------------------------------------------------
// bf16 MFMA GEMM, 128x128 tile, BK=32, 4 waves (2x2 of 64x64).
// A [M][K] bf16 row-major; Bt [N][K] bf16 row-major (pre-transposed weights).
// MODE 0: qb[R][col]  = bf16(tanh(acc))
// MODE 1: col<512 -> kb[bh][m+1][d] = bf16(tanh); else vb[bh][m+1][d] = bf16
// ---------------------------------------------------------------------------
template<int MODE>
__global__ __launch_bounds__(256) void mgemm(
    const u16* __restrict__ A, const u16* __restrict__ Bt,
    u16* __restrict__ C0, u16* __restrict__ C1,
    int K, int Ncols)
{
  __shared__ __align__(16) short At[128*32];
  __shared__ __align__(16) short Bl[128*32];
  const int tid = threadIdx.x;
  const int w = tid >> 6, lane = tid & 63;
  const int c = lane & 15, g = lane >> 4;
  const int row0 = blockIdx.y * 128, col0 = blockIdx.x * 128;
  const int wr = (w >> 1) * 64, wc = (w & 1) * 64;

  f32x4 acc[4][4] = {};

  const int srow = tid >> 1, sj = (tid & 1) * 2;
  for (int k0 = 0; k0 < K; k0 += 32){
    __syncthreads();
    {
      const u16* src = A + (size_t)(row0 + srow) * K + k0 + sj*8;
      uint4 t0 = ((const uint4*)src)[0];
      uint4 t1 = ((const uint4*)src)[1];
      *(uint4*)((char*)At + srow*64 + (((sj  ) ^ ((srow>>1)&3)) << 4)) = t0;
      *(uint4*)((char*)At + srow*64 + (((sj+1) ^ ((srow>>1)&3)) << 4)) = t1;
    }
    {
      const u16* src = Bt + (size_t)(col0 + srow) * K + k0 + sj*8;
      uint4 t0 = ((const uint4*)src)[0];
      uint4 t1 = ((const uint4*)src)[1];
      *(uint4*)((char*)Bl + srow*64 + (((sj  ) ^ ((srow>>1)&3)) << 4)) = t0;
      *(uint4*)((char*)Bl + srow*64 + (((sj+1) ^ ((srow>>1)&3)) << 4)) = t1;
    }
    __syncthreads();

    short8 af[4], bf[4];
    #pragma unroll
    for (int m = 0; m < 4; ++m){
      const int row = wr + m*16 + c;
      af[m] = *(const short8*)((char*)At + row*64 + ((g ^ ((row>>1)&3)) << 4));
    }
    #pragma unroll
    for (int n = 0; n < 4; ++n){
      const int row = wc + n*16 + c;
      bf[n] = *(const short8*)((char*)Bl + row*64 + ((g ^ ((row>>1)&3)) << 4));
    }
    __builtin_amdgcn_s_setprio(1);
    #pragma unroll
    for (int m = 0; m < 4; ++m)
      #pragma unroll
      for (int n = 0; n < 4; ++n)
        acc[m][n] = __builtin_amdgcn_mfma_f32_16x16x32_bf16(af[m], bf[n], acc[m][n], 0, 0, 0);
    __builtin_amdgcn_s_setprio(0);
  }

  #pragma unroll
  for (int m = 0; m < 4; ++m){
    #pragma unroll
    for (int n = 0; n < 4; ++n){
      #pragma unroll
      for (int rr = 0; rr < 4; ++rr){
        const int R = row0 + wr + m*16 + g*4 + rr;
        const int col = col0 + wc + n*16 + c;
        const float v = acc[m][n][rr];
        if (MODE == 0){
          C0[(size_t)R * Ncols + col] = f2bf(tanhf(v));
        } else {
          const int bidx = R >> 11, mm = R & 2047;
          if (col < INNER){
            const int h = col >> 6, d = col & 63;
            C0[((size_t)(bidx*H_ + h) * MKP + (mm + 1)) * DH + d] = f2bf(tanhf(v));
          } else {
            const int cc = col - INNER;
            const int h = cc >> 6, d = cc & 63;
            C1[((size_t)(bidx*H_ + h) * MKP + (mm + 1)) * DH + d] = f2bf(v);
          }
        }
      }
    }
  }
}

// ---------------------------------------------------------------------------
// v [bh][m][d] bf16 -> vt [bh][d][m] bf16, 64x64 tiles per bh
// ---------------------------------------------------------------------------
__global__ __launch_bounds__(256) void vtrans(
    const u16* __restrict__ vb, u16* __restrict__ vt)
{
  __shared__ short tl[64][72];
  const int t = threadIdx.x;
  const int mt = blockIdx.x, bh = blockIdx.y;
  {
    const int mr = t >> 2, chb = (t & 3) * 2;
    const u16* src = vb + ((size_t)bh * MKP + mt*64 + mr) * DH + chb*8;
    uint4 a = ((const uint4*)src)[0];
    uint4 b = ((const uint4*)src)[1];
    *(uint4*)((char*)tl + mr*144 + chb*16)     = a;
    *(uint4*)((char*)tl + mr*144 + (chb+1)*16) = b;
  }
  __syncthreads();
  {
    const int d = t >> 2, chb = (t & 3) * 2;
    #pragma unroll
    for (int j = 0; j < 2; ++j){
      const int mbase = (chb + j) * 8;
      u16 s[8];
      #pragma unroll
      for (int e = 0; e < 8; ++e) s[e] = (u16)tl[mbase + e][d];
      uint4 o;
      o.x = (u32)s[0] | ((u32)s[1] << 16);
      o.y = (u32)s[2] | ((u32)s[3] << 16);
      o.z = (u32)s[4] | ((u32)s[5] << 16);
      o.w = (u32)s[6] | ((u32)s[7] << 16);
      *(uint4*)(vt + ((size_t)bh * DH + d) * MKP + mt*64 + mbase) = o;
    }
  }
}

// Null-token (key slot 0): k = tanh(null_k), v = null_v
__global__ void fill_null_k(const float* __restrict__ nk, const float* __restrict__ nv,
                            u16* __restrict__ kb, u16* __restrict__ vt)
{
  const int i  = blockIdx.x * 256 + threadIdx.x;   // 0..2047 = bh*64 + d
  const int d  = i & 63, bh = i >> 6;
  kb[(size_t)bh * MKP * DH + d]        = f2bf(tanhf(nk[d]));
  vt[((size_t)bh * DH + d) * MKP + 0]  = f2bf(nv[d]);
}

// ---------------------------------------------------------------------------
// MFMA flash attention. 4 waves x 16 query rows, KVBLK=64.
// ---------------------------------------------------------------------------
__global__ __launch_bounds__(256) void attn_mfma(
    const u16* __restrict__ qb, const u16* __restrict__ kb,
    const u16* __restrict__ vt, float* __restrict__ aob)
{
  __shared__ __align__(16) short Kl[64*64];      // 8KB, rows 128B, XOR-swizzled
  __shared__ __align__(16) short Vl[8*64*8];     // 8KB, [kgrp][dim][8key]
  __shared__ __align__(16) short Pl[4][16][72];  // 9KB, per-wave P (144B rows)

  const int tid  = threadIdx.x;
  const int w    = tid >> 6;
  const int lane = tid & 63;
  const int c    = lane & 15;
  const int g    = lane >> 4;
  const int bh   = blockIdx.y, b = bh >> 3, h = bh & 7;
  const int qbase = blockIdx.x * 64 + w * 16;

  short8 qf0, qf1;
  {
    const u16* qrow = qb + ((size_t)(b*N_) + qbase + c) * INNER + h * DH;
    qf0 = *(const short8*)(qrow + g*8);
    qf1 = *(const short8*)(qrow + 32 + g*8);
  }

  f32x4 o[4] = {};
  float m[4], l[4];
  #pragma unroll
  for (int r = 0; r < 4; ++r){ m[r] = -3.0e38f; l[r] = 0.f; }

  const u16* kbase = kb + (size_t)bh * MKP * DH;
  const u16* vbase = vt + (size_t)bh * DH * MKP;

  const int srow = tid >> 2, sch = (tid & 3) * 2;

  for (int kt = 0; kt < 33; ++kt){
    __syncthreads();
    {  // K tile: 64 keys x 64 dims; LDS chunk pos = ch ^ (row&7)
      const u16* src = kbase + (size_t)(kt*64 + srow) * DH + sch*8;
      uint4 t0 = ((const uint4*)src)[0];
      uint4 t1 = ((const uint4*)src)[1];
      *(uint4*)((char*)Kl + srow*128 + (((sch  ) ^ (srow&7)) << 4)) = t0;
      *(uint4*)((char*)Kl + srow*128 + (((sch+1) ^ (srow&7)) << 4)) = t1;
    }
    {  // Vt tile: Vl[kgrp][dim][8key]
      const u16* src = vbase + (size_t)srow * MKP + kt*64 + sch*8;
      uint4 t0 = ((const uint4*)src)[0];
      uint4 t1 = ((const uint4*)src)[1];
      *(uint4*)((char*)Vl + (sch  )*1024 + srow*16) = t0;
      *(uint4*)((char*)Vl + (sch+1)*1024 + srow*16) = t1;
    }
    __syncthreads();

    // ---- QK^T: S[16q x 64k] as 4 16x16 tiles ----
    f32x4 sv[4];
    __builtin_amdgcn_s_setprio(1);
    #pragma unroll
    for (int s = 0; s < 4; ++s){
      f32x4 a = {0.f, 0.f, 0.f, 0.f};
      const int row = s*16 + c;
      #pragma unroll
      for (int hh = 0; hh < 2; ++hh){
        short8 kf = *(const short8*)((char*)Kl + row*128
                      + ((hh*64 + g*16) ^ ((row & 7) << 4)));
        a = __builtin_amdgcn_mfma_f32_16x16x32_bf16(hh ? qf1 : qf0, kf, a, 0, 0, 0);
      }
      sv[s] = a;
    }
    __builtin_amdgcn_s_setprio(0);
    #pragma unroll
    for (int s = 0; s < 4; ++s)
      #pragma unroll
      for (int r = 0; r < 4; ++r) sv[s][r] *= 0.125f;

    if (kt == 32){                    // only key 2048 (tile-local 0) is valid
      if (c != 0){
        #pragma unroll
        for (int r = 0; r < 4; ++r) sv[0][r] = -1e30f;
      }
      #pragma unroll
      for (int s = 1; s < 4; ++s)
        #pragma unroll
        for (int r = 0; r < 4; ++r) sv[s][r] = -1e30f;
    }

    // ---- online softmax ----
    float tm[4], ps[4];
    #pragma unroll
    for (int r = 0; r < 4; ++r)
      tm[r] = fmaxf(fmaxf(sv[0][r], sv[1][r]), fmaxf(sv[2][r], sv[3][r]));
    #pragma unroll
    for (int msk = 1; msk <= 8; msk <<= 1){
      #pragma unroll
      for (int r = 0; r < 4; ++r)
        tm[r] = fmaxf(tm[r], __shfl_xor(tm[r], msk, 16));
    }
    #pragma unroll
    for (int r = 0; r < 4; ++r){
      if (tm[r] > m[r] + 4.f){        // deferred rescale (p <= e^4)
        const float corr = __expf(m[r] - tm[r]);
        l[r] *= corr;
        #pragma unroll
        for (int D = 0; D < 4; ++D) o[D][r] *= corr;
        m[r] = tm[r];
      }
      float psum = 0.f;
      #pragma unroll
      for (int s = 0; s < 4; ++s){
        const float p = __expf(sv[s][r] - m[r]);
        psum += p;
        Pl[w][g*4 + r][s*16 + c] = (short)f2bf(p);
      }
      ps[r] = psum;
    }
    #pragma unroll
    for (int msk = 1; msk <= 8; msk <<= 1){
      #pragma unroll
      for (int r = 0; r < 4; ++r)
        ps[r] += __shfl_xor(ps[r], msk, 16);
    }
    #pragma unroll
    for (int r = 0; r < 4; ++r) l[r] += ps[r];

    // ---- PV: O[16q x 64d] += P[16x64] @ V[64x64] ----
    __builtin_amdgcn_s_setprio(1);
    #pragma unroll
    for (int hh = 0; hh < 2; ++hh){
      short8 pf = *(const short8*)((char*)Pl + w*2304 + c*144 + hh*64 + g*16);
      #pragma unroll
      for (int D = 0; D < 4; ++D){
        short8 vf = *(const short8*)((char*)Vl + (hh*4 + g)*1024 + (D*16 + c)*16);
        o[D] = __builtin_amdgcn_mfma_f32_16x16x32_bf16(pf, vf, o[D], 0, 0, 0);
      }
    }
    __builtin_amdgcn_s_setprio(0);
  }

  #pragma unroll
  for (int r = 0; r < 4; ++r){
    const float inv = 1.f / l[r];
    const size_t nrow = (size_t)(b*N_) + qbase + g*4 + r;
    #pragma unroll
    for (int D = 0; D < 4; ++D)
      aob[nrow * INNER + h*DH + D*16 + c] = o[D][r] * inv;
  }
}

// ---------------------------------------------------------------------------
// fp32 out-projection: out = ao @ Wout + bout  (64x64 tile, vector ALU)
// ---------------------------------------------------------------------------
__global__ __launch_bounds__(256) void gemm_out(
    const float* __restrict__ A, const float* __restrict__ Bm,
    const float* __restrict__ bias, float* __restrict__ C,
    int K, int Ncols)
{
  __shared__ float As[64][17];
  __shared__ float Bs[16][64];
  const int tx = threadIdx.x, ty = threadIdx.y;
  const int tid = ty * 16 + tx;
  const int row0 = blockIdx.y * 64;
  const int c0   = blockIdx.x * 64;
  const int ar = tid >> 2,  ak = (tid & 3) * 4;
  const int bk = tid >> 4,  bc = (tid & 15) * 4;

  float acc[4][4] = {};

  for (int k0 = 0; k0 < K; k0 += 16){
    __syncthreads();
    {
      float4 t = *(const float4*)(A + (size_t)(row0 + ar) * K + (k0 + ak));
      As[ar][ak+0] = t.x; As[ar][ak+1] = t.y;
      As[ar][ak+2] = t.z; As[ar][ak+3] = t.w;
    }
    {
      float4 t = *(const float4*)(Bm + (size_t)(k0 + bk) * Ncols + (c0 + bc));
      Bs[bk][bc+0] = t.x; Bs[bk][bc+1] = t.y;
      Bs[bk][bc+2] = t.z; Bs[bk][bc+3] = t.w;
    }
    __syncthreads();
    #pragma unroll
    for (int kk = 0; kk < 16; ++kk){
      float4 bv = *(const float4*)(&Bs[kk][tx*4]);
      #pragma unroll
      for (int i = 0; i < 4; ++i){
        float a = As[ty*4 + i][kk];
        acc[i][0] += a * bv.x;
        acc[i][1] += a * bv.y;
        acc[i][2] += a * bv.z;
        acc[i][3] += a * bv.w;
      }
    }
  }

  #pragma unroll
  for (int i = 0; i < 4; ++i){
    const int R = row0 + ty*4 + i;
    #pragma unroll
    for (int j = 0; j < 4; ++j){
      const int col = c0 + tx*4 + j;
      C[(size_t)R * Ncols + col] = acc[i][j] + bias[col];
    }
  }
}

extern "C" void kernel_launch(void* const* d_in, const int* in_sizes, int n_in,
                              void* d_out, int out_size, void* d_ws, size_t ws_size,
                              hipStream_t stream)
{
  const float* x    = (const float*)d_in[0];
  const float* ctx  = (const float*)d_in[1];
  const float* Wq   = (const float*)d_in[2];
  const float* Wkv  = (const float*)d_in[3];
  const float* nk   = (const float*)d_in[4];
  const float* nv   = (const float*)d_in[5];
  const float* Wout = (const float*)d_in[6];
  const float* bout = (const float*)d_in[7];
  float* out = (float*)d_out;

  char* ws = (char*)d_ws;
  // layout (ao aliases xb+cb, both dead before attn writes ao)
  u16*   xb   = (u16*)(ws);                       //  8,388,608
  u16*   cb   = (u16*)(ws + 8388608);             //  8,388,608
  float* ao   = (float*)(ws);                     // 16,777,216 (alias)
  u16*   qb   = (u16*)(ws + 16777216);            //  8,388,608
  u16*   kb   = (u16*)(ws + 25165824);            //  8,650,752
  u16*   vb   = (u16*)(ws + 33816576);            //  8,650,752
  u16*   vtb  = (u16*)(ws + 42467328);            //  8,650,752
  u16*   Wqt  = (u16*)(ws + 51118080);            //    524,288
  u16*   Wkvt = (u16*)(ws + 51642368);            //  1,048,576  (end ~52.7MB)

  // prep: bf16 conversions + weight transposes
  convert_bf<<<2048, 256, 0, stream>>>(x,   xb);
  convert_bf<<<2048, 256, 0, stream>>>(ctx, cb);
  transpose_wt<<<dim3(8, 8),  256, 0, stream>>>(Wq,  Wqt,  DIMX, INNER);
  transpose_wt<<<dim3(16, 8), 256, 0, stream>>>(Wkv, Wkvt, DIMX, 2*INNER);

  // q = bf16(tanh(xb @ Wq))
  mgemm<0><<<dim3(4, 64), 256, 0, stream>>>(xb, Wqt, qb, nullptr, DIMX, INNER);
  // kv = cb @ Wkv -> kb (tanh) and vb, both row-major [bh][m+1][d]
  mgemm<1><<<dim3(8, 64), 256, 0, stream>>>(cb, Wkvt, kb, vb, DIMX, 2*INNER);
  // v -> v^T  [bh][d][m]
  vtrans<<<dim3(33, 32), 256, 0, stream>>>(vb, vtb);
  fill_null_k<<<8, 256, 0, stream>>>(nk, nv, kb, vtb);
  // MFMA flash attention -> ao fp32
  attn_mfma<<<dim3(32, 32), 256, 0, stream>>>(qb, kb, vtb, ao);
  // out = ao @ Wout + bout (fp32)
  gemm_out<<<dim3(8, 128), dim3(16, 16), 0, stream>>>(ao, Wout, bout, out, INNER, 512);
}

// Round 5
// 179.098 us; speedup vs baseline: 7.8054x; 1.4269x over previous
//
#include <hip/hip_runtime.h>
#include <stdint.h>

#define B_    4
#define N_    2048
#define M_    2048
#define DIMX  512
#define INNER 512
#define H_    8
#define DH    64
#define MK    2049   // M+1 keys (null token at slot 0)
#define MKP   2112   // padded to 33 tiles of 64 (tail masked in-kernel)

using u16 = unsigned short;
using u32 = unsigned int;

typedef __attribute__((ext_vector_type(8))) short short8;
typedef __attribute__((ext_vector_type(4))) float f32x4;

__device__ __forceinline__ u16 f2bf(float f){
  union { float f; u32 u; } x; x.f = f;
  u32 r = 0x7fffu + ((x.u >> 16) & 1u);
  return (u16)((x.u + r) >> 16);
}

// ---------------------------------------------------------------------------
// fp32 -> bf16 elementwise convert (8 elems/thread)
// ---------------------------------------------------------------------------
__global__ __launch_bounds__(256) void convert_bf(
    const float* __restrict__ in, u16* __restrict__ out)
{
  const int i = blockIdx.x * 256 + threadIdx.x;
  float4 a = ((const float4*)in)[i*2];
  float4 b = ((const float4*)in)[i*2+1];
  uint4 t;
  t.x = (u32)f2bf(a.x) | ((u32)f2bf(a.y) << 16);
  t.y = (u32)f2bf(a.z) | ((u32)f2bf(a.w) << 16);
  t.z = (u32)f2bf(b.x) | ((u32)f2bf(b.y) << 16);
  t.w = (u32)f2bf(b.z) | ((u32)f2bf(b.w) << 16);
  ((uint4*)out)[i] = t;
}

// ---------------------------------------------------------------------------
// fp32 [R][C] -> bf16 [C][R] transpose-convert, 64x64 LDS tiles
// ---------------------------------------------------------------------------
__global__ __launch_bounds__(256) void transpose_wt(
    const float* __restrict__ in, u16* __restrict__ out, int R, int C)
{
  __shared__ float tl[64][65];
  const int t = threadIdx.x;
  const int c0 = blockIdx.x * 64, r0 = blockIdx.y * 64;
  const int col = t & 63, rb = t >> 6;
  #pragma unroll
  for (int j = 0; j < 16; ++j){
    const int row = rb + j*4;
    tl[row][col] = in[(size_t)(r0 + row) * C + c0 + col];
  }
  __syncthreads();
  #pragma unroll
  for (int j = 0; j < 16; ++j){
    const int orow = rb + j*4;        // output row = original col
    out[(size_t)(c0 + orow) * R + r0 + col] = f2bf(tl[col][orow]);
  }
}

// ---------------------------------------------------------------------------
// bf16 MFMA GEMM, 128x128 tile, BK=32, 4 waves (2x2 of 64x64).
// A [M][K] bf16 row-major; Bt [N][K] bf16 row-major (pre-transposed weights).
// MODE 0: qb[R][col]  = bf16(tanh(acc) * 0.125)   (q projection, pre-scaled)
// MODE 1: col<512 -> kb[bh][m+1][d] = bf16(tanh); else vb[bh][m+1][d] = bf16
// MODE 2: Cf[R][col] = acc + bias[col]            (out projection, fp32 out)
// ---------------------------------------------------------------------------
template<int MODE>
__global__ __launch_bounds__(256) void mgemm(
    const u16* __restrict__ A, const u16* __restrict__ Bt,
    u16* __restrict__ C0, u16* __restrict__ C1,
    float* __restrict__ Cf, const float* __restrict__ bias,
    int K, int Ncols)
{
  __shared__ __align__(16) short At[128*32];
  __shared__ __align__(16) short Bl[128*32];
  const int tid = threadIdx.x;
  const int w = tid >> 6, lane = tid & 63;
  const int c = lane & 15, g = lane >> 4;
  const int row0 = blockIdx.y * 128, col0 = blockIdx.x * 128;
  const int wr = (w >> 1) * 64, wc = (w & 1) * 64;

  f32x4 acc[4][4] = {};

  const int srow = tid >> 1, sj = (tid & 1) * 2;
  for (int k0 = 0; k0 < K; k0 += 32){
    __syncthreads();
    {
      const u16* src = A + (size_t)(row0 + srow) * K + k0 + sj*8;
      uint4 t0 = ((const uint4*)src)[0];
      uint4 t1 = ((const uint4*)src)[1];
      *(uint4*)((char*)At + srow*64 + (((sj  ) ^ ((srow>>1)&3)) << 4)) = t0;
      *(uint4*)((char*)At + srow*64 + (((sj+1) ^ ((srow>>1)&3)) << 4)) = t1;
    }
    {
      const u16* src = Bt + (size_t)(col0 + srow) * K + k0 + sj*8;
      uint4 t0 = ((const uint4*)src)[0];
      uint4 t1 = ((const uint4*)src)[1];
      *(uint4*)((char*)Bl + srow*64 + (((sj  ) ^ ((srow>>1)&3)) << 4)) = t0;
      *(uint4*)((char*)Bl + srow*64 + (((sj+1) ^ ((srow>>1)&3)) << 4)) = t1;
    }
    __syncthreads();

    short8 af[4], bf[4];
    #pragma unroll
    for (int m = 0; m < 4; ++m){
      const int row = wr + m*16 + c;
      af[m] = *(const short8*)((char*)At + row*64 + ((g ^ ((row>>1)&3)) << 4));
    }
    #pragma unroll
    for (int n = 0; n < 4; ++n){
      const int row = wc + n*16 + c;
      bf[n] = *(const short8*)((char*)Bl + row*64 + ((g ^ ((row>>1)&3)) << 4));
    }
    __builtin_amdgcn_s_setprio(1);
    #pragma unroll
    for (int m = 0; m < 4; ++m)
      #pragma unroll
      for (int n = 0; n < 4; ++n)
        acc[m][n] = __builtin_amdgcn_mfma_f32_16x16x32_bf16(af[m], bf[n], acc[m][n], 0, 0, 0);
    __builtin_amdgcn_s_setprio(0);
  }

  #pragma unroll
  for (int m = 0; m < 4; ++m){
    #pragma unroll
    for (int n = 0; n < 4; ++n){
      #pragma unroll
      for (int rr = 0; rr < 4; ++rr){
        const int R = row0 + wr + m*16 + g*4 + rr;
        const int col = col0 + wc + n*16 + c;
        const float v = acc[m][n][rr];
        if (MODE == 0){
          C0[(size_t)R * Ncols + col] = f2bf(tanhf(v) * 0.125f);
        } else if (MODE == 1){
          const int bidx = R >> 11, mm = R & 2047;
          if (col < INNER){
            const int h = col >> 6, d = col & 63;
            C0[((size_t)(bidx*H_ + h) * MKP + (mm + 1)) * DH + d] = f2bf(tanhf(v));
          } else {
            const int cc = col - INNER;
            const int h = cc >> 6, d = cc & 63;
            C1[((size_t)(bidx*H_ + h) * MKP + (mm + 1)) * DH + d] = f2bf(v);
          }
        } else {
          Cf[(size_t)R * Ncols + col] = v + bias[col];
        }
      }
    }
  }
}

// ---------------------------------------------------------------------------
// v [bh][m][d] bf16 -> vt [bh][d][m] bf16, 64x64 tiles per bh
// ---------------------------------------------------------------------------
__global__ __launch_bounds__(256) void vtrans(
    const u16* __restrict__ vb, u16* __restrict__ vt)
{
  __shared__ short tl[64][72];
  const int t = threadIdx.x;
  const int mt = blockIdx.x, bh = blockIdx.y;
  {
    const int mr = t >> 2, chb = (t & 3) * 2;
    const u16* src = vb + ((size_t)bh * MKP + mt*64 + mr) * DH + chb*8;
    uint4 a = ((const uint4*)src)[0];
    uint4 b = ((const uint4*)src)[1];
    *(uint4*)((char*)tl + mr*144 + chb*16)     = a;
    *(uint4*)((char*)tl + mr*144 + (chb+1)*16) = b;
  }
  __syncthreads();
  {
    const int d = t >> 2, chb = (t & 3) * 2;
    #pragma unroll
    for (int j = 0; j < 2; ++j){
      const int mbase = (chb + j) * 8;
      u16 s[8];
      #pragma unroll
      for (int e = 0; e < 8; ++e) s[e] = (u16)tl[mbase + e][d];
      uint4 o;
      o.x = (u32)s[0] | ((u32)s[1] << 16);
      o.y = (u32)s[2] | ((u32)s[3] << 16);
      o.z = (u32)s[4] | ((u32)s[5] << 16);
      o.w = (u32)s[6] | ((u32)s[7] << 16);
      *(uint4*)(vt + ((size_t)bh * DH + d) * MKP + mt*64 + mbase) = o;
    }
  }
}

// Null-token (key slot 0): k = tanh(null_k), v = null_v
__global__ void fill_null_k(const float* __restrict__ nk, const float* __restrict__ nv,
                            u16* __restrict__ kb, u16* __restrict__ vt)
{
  const int i  = blockIdx.x * 256 + threadIdx.x;   // 0..2047 = bh*64 + d
  const int d  = i & 63, bh = i >> 6;
  kb[(size_t)bh * MKP * DH + d]        = f2bf(tanhf(nk[d]));
  vt[((size_t)bh * DH + d) * MKP + 0]  = f2bf(nv[d]);
}

// ---------------------------------------------------------------------------
// MFMA flash attention. 4 waves x 16 query rows, KVBLK=64.
// Swapped QK^T: S[key][query] -> each lane holds 16 S-values for ONE query
// (in-lane max/sum + 2 shfl_xor rounds). Double-buffered K/V LDS with
// load-early / write-late split. Q pre-scaled by 0.125. ao written bf16.
// ---------------------------------------------------------------------------
__global__ __launch_bounds__(256) void attn_mfma(
    const u16* __restrict__ qb, const u16* __restrict__ kb,
    const u16* __restrict__ vt, u16* __restrict__ aob)
{
  __shared__ __align__(16) short Kl[2][64*64];   // 16KB, rows 128B, XOR-swizzled
  __shared__ __align__(16) short Vl[2][64*64];   // 16KB, [kgrp][dim][8key]
  __shared__ __align__(16) short Pl[4][16][72];  // 9KB, per-wave P (144B rows)

  const int tid  = threadIdx.x;
  const int w    = tid >> 6;
  const int lane = tid & 63;
  const int c    = lane & 15;
  const int g    = lane >> 4;
  const int bh   = blockIdx.y, b = bh >> 3, h = bh & 7;
  const int qbase = blockIdx.x * 64 + w * 16;

  short8 qf0, qf1;
  {
    const u16* qrow = qb + ((size_t)(b*N_) + qbase + c) * INNER + h * DH;
    qf0 = *(const short8*)(qrow + g*8);
    qf1 = *(const short8*)(qrow + 32 + g*8);
  }

  f32x4 o[4] = {};                 // O accum: row = query g*4+r, col = dim c
  float m_c = -3.0e38f, l_c = 0.f; // running max/sum for query c

  const u16* kbase = kb + (size_t)bh * MKP * DH;
  const u16* vbase = vt + (size_t)bh * DH * MKP;
  const int srow = tid >> 2, sch = (tid & 3) * 2;

  // prologue: tile 0 -> buf 0
  uint4 rk0, rk1, rv0, rv1;
  {
    const u16* ksrc = kbase + (size_t)srow * DH + sch*8;
    rk0 = ((const uint4*)ksrc)[0]; rk1 = ((const uint4*)ksrc)[1];
    const u16* vsrc = vbase + (size_t)srow * MKP + sch*8;
    rv0 = ((const uint4*)vsrc)[0]; rv1 = ((const uint4*)vsrc)[1];
  }
  *(uint4*)((char*)Kl[0] + srow*128 + (((sch  ) ^ (srow&7)) << 4)) = rk0;
  *(uint4*)((char*)Kl[0] + srow*128 + (((sch+1) ^ (srow&7)) << 4)) = rk1;
  *(uint4*)((char*)Vl[0] + (sch  )*1024 + srow*16) = rv0;
  *(uint4*)((char*)Vl[0] + (sch+1)*1024 + srow*16) = rv1;

  int cur = 0;
  for (int kt = 0; kt < 33; ++kt){
    __syncthreads();
    // issue next tile's global loads early (latency hides under compute)
    if (kt < 32){
      const u16* ksrc = kbase + (size_t)((kt+1)*64 + srow) * DH + sch*8;
      rk0 = ((const uint4*)ksrc)[0]; rk1 = ((const uint4*)ksrc)[1];
      const u16* vsrc = vbase + (size_t)srow * MKP + (kt+1)*64 + sch*8;
      rv0 = ((const uint4*)vsrc)[0]; rv1 = ((const uint4*)vsrc)[1];
    }

    const char* Kc = (const char*)Kl[cur];
    const char* Vc = (const char*)Vl[cur];

    // ---- swapped QK^T: S[64k x 16q], lane holds keys {s*16+g*4+r} of query c
    f32x4 sv[4];
    __builtin_amdgcn_s_setprio(1);
    #pragma unroll
    for (int s = 0; s < 4; ++s){
      f32x4 a = {0.f, 0.f, 0.f, 0.f};
      const int row = s*16 + c;
      #pragma unroll
      for (int hh = 0; hh < 2; ++hh){
        short8 kf = *(const short8*)(Kc + row*128
                      + ((hh*64 + g*16) ^ ((row & 7) << 4)));
        a = __builtin_amdgcn_mfma_f32_16x16x32_bf16(kf, hh ? qf1 : qf0, a, 0, 0, 0);
      }
      sv[s] = a;
    }
    __builtin_amdgcn_s_setprio(0);

    if (kt == 32){                    // only key 2048 (tile-local 0) is valid
      #pragma unroll
      for (int s = 0; s < 4; ++s)
        #pragma unroll
        for (int r = 0; r < 4; ++r)
          if (s | r) sv[s][r] = -1e30f;
      if (g) sv[0][0] = -1e30f;
    }

    // ---- online softmax (in-lane over 16 keys, then 2 shfl rounds over g)
    float t0 = fmaxf(fmaxf(sv[0][0], sv[0][1]), fmaxf(sv[0][2], sv[0][3]));
    float t1 = fmaxf(fmaxf(sv[1][0], sv[1][1]), fmaxf(sv[1][2], sv[1][3]));
    float t2 = fmaxf(fmaxf(sv[2][0], sv[2][1]), fmaxf(sv[2][2], sv[2][3]));
    float t3 = fmaxf(fmaxf(sv[3][0], sv[3][1]), fmaxf(sv[3][2], sv[3][3]));
    float tm = fmaxf(fmaxf(t0, t1), fmaxf(t2, t3));
    tm = fmaxf(tm, __shfl_xor(tm, 16));
    tm = fmaxf(tm, __shfl_xor(tm, 32));

    const bool need = tm > m_c + 4.f;    // deferred rescale (p <= e^4)
    if (__any((int)need)){
      float corr = need ? __expf(m_c - tm) : 1.f;
      if (need) m_c = tm;
      l_c *= corr;
      #pragma unroll
      for (int r = 0; r < 4; ++r){
        const float cr = __shfl(corr, g*4 + r, 16);
        #pragma unroll
        for (int D = 0; D < 4; ++D) o[D][r] *= cr;
      }
    }

    float psum = 0.f;
    #pragma unroll
    for (int s = 0; s < 4; ++s){
      const float p0 = __expf(sv[s][0] - m_c);
      const float p1 = __expf(sv[s][1] - m_c);
      const float p2 = __expf(sv[s][2] - m_c);
      const float p3 = __expf(sv[s][3] - m_c);
      psum += (p0 + p1) + (p2 + p3);
      uint2 pk;
      pk.x = (u32)f2bf(p0) | ((u32)f2bf(p1) << 16);
      pk.y = (u32)f2bf(p2) | ((u32)f2bf(p3) << 16);
      *(uint2*)((char*)Pl + w*2304 + c*144 + s*32 + g*8) = pk;  // row=query c
    }
    psum += __shfl_xor(psum, 16);
    psum += __shfl_xor(psum, 32);
    l_c += psum;

    // ---- PV: O[16q x 64d] += P[16x64] @ V[64x64] ----
    __builtin_amdgcn_s_setprio(1);
    #pragma unroll
    for (int hh = 0; hh < 2; ++hh){
      short8 pf = *(const short8*)((char*)Pl + w*2304 + c*144 + hh*64 + g*16);
      #pragma unroll
      for (int D = 0; D < 4; ++D){
        short8 vf = *(const short8*)(Vc + (hh*4 + g)*1024 + (D*16 + c)*16);
        o[D] = __builtin_amdgcn_mfma_f32_16x16x32_bf16(pf, vf, o[D], 0, 0, 0);
      }
    }
    __builtin_amdgcn_s_setprio(0);

    // ---- write next tile to the other buffer (vmcnt waits inserted here)
    if (kt < 32){
      char* Kn = (char*)Kl[cur ^ 1];
      char* Vn = (char*)Vl[cur ^ 1];
      *(uint4*)(Kn + srow*128 + (((sch  ) ^ (srow&7)) << 4)) = rk0;
      *(uint4*)(Kn + srow*128 + (((sch+1) ^ (srow&7)) << 4)) = rk1;
      *(uint4*)(Vn + (sch  )*1024 + srow*16) = rv0;
      *(uint4*)(Vn + (sch+1)*1024 + srow*16) = rv1;
      cur ^= 1;
    }
  }

  // ---- epilogue: normalize, write bf16 ao[b, n, h*64+d] ----
  const float inv = 1.f / l_c;
  #pragma unroll
  for (int r = 0; r < 4; ++r){
    const float ir = __shfl(inv, g*4 + r, 16);
    const size_t nrow = (size_t)(b*N_) + qbase + g*4 + r;
    #pragma unroll
    for (int D = 0; D < 4; ++D)
      aob[nrow * INNER + h*DH + D*16 + c] = f2bf(o[D][r] * ir);
  }
}

extern "C" void kernel_launch(void* const* d_in, const int* in_sizes, int n_in,
                              void* d_out, int out_size, void* d_ws, size_t ws_size,
                              hipStream_t stream)
{
  const float* x    = (const float*)d_in[0];
  const float* ctx  = (const float*)d_in[1];
  const float* Wq   = (const float*)d_in[2];
  const float* Wkv  = (const float*)d_in[3];
  const float* nk   = (const float*)d_in[4];
  const float* nv   = (const float*)d_in[5];
  const float* Wout = (const float*)d_in[6];
  const float* bout = (const float*)d_in[7];
  float* out = (float*)d_out;

  char* ws = (char*)d_ws;
  u16*   xb    = (u16*)(ws);                      //  8,388,608
  u16*   cb    = (u16*)(ws + 8388608);            //  8,388,608
  u16*   qb    = (u16*)(ws + 16777216);           //  8,388,608
  u16*   kbB   = (u16*)(ws + 25165824);           //  8,650,752
  u16*   vbB   = (u16*)(ws + 33816576);           //  8,650,752
  u16*   vtb   = (u16*)(ws + 42467328);           //  8,650,752
  u16*   Wqt   = (u16*)(ws + 51118080);           //    524,288
  u16*   Wkvt  = (u16*)(ws + 51642368);           //  1,048,576 (end ~52.7MB)
  u16*   aoB   = xb;                              // alias: xb dead after mgemm<0>
  u16*   Woutt = cb;                              // alias: cb dead after mgemm<1>

  // prep
  convert_bf<<<2048, 256, 0, stream>>>(x,   xb);
  convert_bf<<<2048, 256, 0, stream>>>(ctx, cb);
  transpose_wt<<<dim3(8, 8),  256, 0, stream>>>(Wq,  Wqt,  DIMX, INNER);
  transpose_wt<<<dim3(16, 8), 256, 0, stream>>>(Wkv, Wkvt, DIMX, 2*INNER);

  // q = bf16(tanh(xb @ Wq) * 0.125)
  mgemm<0><<<dim3(4, 64), 256, 0, stream>>>(xb, Wqt, qb, nullptr, nullptr, nullptr, DIMX, INNER);
  // kv = cb @ Wkv -> kb (tanh) and vb, row-major [bh][m+1][d]
  mgemm<1><<<dim3(8, 64), 256, 0, stream>>>(cb, Wkvt, kbB, vbB, nullptr, nullptr, DIMX, 2*INNER);
  // Wout^T (after mgemm<1>; aliases cb)
  transpose_wt<<<dim3(8, 8), 256, 0, stream>>>(Wout, Woutt, INNER, 512);
  // v -> v^T  [bh][d][m]
  vtrans<<<dim3(33, 32), 256, 0, stream>>>(vbB, vtb);
  fill_null_k<<<8, 256, 0, stream>>>(nk, nv, kbB, vtb);
  // MFMA flash attention -> ao bf16 (aliases xb)
  attn_mfma<<<dim3(32, 32), 256, 0, stream>>>(qb, kbB, vtb, aoB);
  // out = ao @ Wout + bout (MFMA, fp32 out)
  mgemm<2><<<dim3(4, 64), 256, 0, stream>>>(aoB, Woutt, nullptr, nullptr, out, bout, INNER, 512);
}

// Round 6
// 163.094 us; speedup vs baseline: 8.5713x; 1.0981x over previous
//
#include <hip/hip_runtime.h>
#include <hip/hip_bf16.h>
#include <stdint.h>

#define B_    4
#define N_    2048
#define M_    2048
#define DIMX  512
#define INNER 512
#define H_    8
#define DH    64
#define MK    2049   // M+1 keys (null token at slot 0)
#define MKP   2112   // padded to 33 tiles of 64 (tail masked in-kernel)

#define QSCALE 0.18033688011f   // 0.125 * log2(e): softmax done in exp2 domain

using u16 = unsigned short;
using u32 = unsigned int;

typedef __attribute__((ext_vector_type(8))) short short8;
typedef __attribute__((ext_vector_type(4))) float f32x4;

#if defined(__has_builtin)
# if __has_builtin(__builtin_amdgcn_exp2f)
#  define EXP2(x) __builtin_amdgcn_exp2f(x)
# endif
#endif
#ifndef EXP2
# define EXP2(x) exp2f(x)
#endif

__device__ __forceinline__ u16 bfc(float f){
  __hip_bfloat16 h = __float2bfloat16(f);
  return *reinterpret_cast<u16*>(&h);
}
__device__ __forceinline__ u32 bfpk(float lo, float hi){
  return (u32)bfc(lo) | ((u32)bfc(hi) << 16);
}

// ---------------------------------------------------------------------------
// fp32 [R][C] -> bf16 [C][R] transpose-convert, 64x64 LDS tiles
// ---------------------------------------------------------------------------
__global__ __launch_bounds__(256) void transpose_wt(
    const float* __restrict__ in, u16* __restrict__ out, int R, int C)
{
  __shared__ float tl[64][65];
  const int t = threadIdx.x;
  const int c0 = blockIdx.x * 64, r0 = blockIdx.y * 64;
  const int col = t & 63, rb = t >> 6;
  #pragma unroll
  for (int j = 0; j < 16; ++j){
    const int row = rb + j*4;
    tl[row][col] = in[(size_t)(r0 + row) * C + c0 + col];
  }
  __syncthreads();
  #pragma unroll
  for (int j = 0; j < 16; ++j){
    const int orow = rb + j*4;
    out[(size_t)(c0 + orow) * R + r0 + col] = bfc(tl[col][orow]);
  }
}

// ---------------------------------------------------------------------------
// bf16 MFMA GEMM, 128x128 tile, BK=32, 4 waves (2x2 of 64x64).
// A: fp32 (AF32=1, converted during staging) or bf16 row-major [M][K].
// Bt [N][K] bf16 row-major (pre-transposed weights).
// MODE 0: qb[R][col]  = bf16(tanh(acc) * QSCALE)
// MODE 1: col<512 -> kb[bh][m+1][d] = bf16(tanh); else vb[bh][m+1][d] = bf16
// MODE 2: Cf[R][col] = acc + bias[col]            (fp32 out)
// ---------------------------------------------------------------------------
template<int MODE, int AF32>
__global__ __launch_bounds__(256) void mgemm(
    const void* __restrict__ Ap, const u16* __restrict__ Bt,
    u16* __restrict__ C0, u16* __restrict__ C1,
    float* __restrict__ Cf, const float* __restrict__ bias,
    int K, int Ncols)
{
  __shared__ __align__(16) short At[128*32];
  __shared__ __align__(16) short Bl[128*32];
  const int tid = threadIdx.x;
  const int w = tid >> 6, lane = tid & 63;
  const int c = lane & 15, g = lane >> 4;
  const int row0 = blockIdx.y * 128, col0 = blockIdx.x * 128;
  const int wr = (w >> 1) * 64, wc = (w & 1) * 64;

  f32x4 acc[4][4] = {};

  const int srow = tid >> 1, sj = (tid & 1) * 2;
  for (int k0 = 0; k0 < K; k0 += 32){
    __syncthreads();
    {
      uint4 t0, t1;
      if (AF32){
        const float* src = (const float*)Ap + (size_t)(row0 + srow) * K + k0 + sj*8;
        float4 a0 = ((const float4*)src)[0];
        float4 a1 = ((const float4*)src)[1];
        float4 a2 = ((const float4*)src)[2];
        float4 a3 = ((const float4*)src)[3];
        t0.x = bfpk(a0.x, a0.y); t0.y = bfpk(a0.z, a0.w);
        t0.z = bfpk(a1.x, a1.y); t0.w = bfpk(a1.z, a1.w);
        t1.x = bfpk(a2.x, a2.y); t1.y = bfpk(a2.z, a2.w);
        t1.z = bfpk(a3.x, a3.y); t1.w = bfpk(a3.z, a3.w);
      } else {
        const u16* src = (const u16*)Ap + (size_t)(row0 + srow) * K + k0 + sj*8;
        t0 = ((const uint4*)src)[0];
        t1 = ((const uint4*)src)[1];
      }
      *(uint4*)((char*)At + srow*64 + (((sj  ) ^ ((srow>>1)&3)) << 4)) = t0;
      *(uint4*)((char*)At + srow*64 + (((sj+1) ^ ((srow>>1)&3)) << 4)) = t1;
    }
    {
      const u16* src = Bt + (size_t)(col0 + srow) * K + k0 + sj*8;
      uint4 t0 = ((const uint4*)src)[0];
      uint4 t1 = ((const uint4*)src)[1];
      *(uint4*)((char*)Bl + srow*64 + (((sj  ) ^ ((srow>>1)&3)) << 4)) = t0;
      *(uint4*)((char*)Bl + srow*64 + (((sj+1) ^ ((srow>>1)&3)) << 4)) = t1;
    }
    __syncthreads();

    short8 af[4], bf[4];
    #pragma unroll
    for (int m = 0; m < 4; ++m){
      const int row = wr + m*16 + c;
      af[m] = *(const short8*)((char*)At + row*64 + ((g ^ ((row>>1)&3)) << 4));
    }
    #pragma unroll
    for (int n = 0; n < 4; ++n){
      const int row = wc + n*16 + c;
      bf[n] = *(const short8*)((char*)Bl + row*64 + ((g ^ ((row>>1)&3)) << 4));
    }
    __builtin_amdgcn_s_setprio(1);
    #pragma unroll
    for (int m = 0; m < 4; ++m)
      #pragma unroll
      for (int n = 0; n < 4; ++n)
        acc[m][n] = __builtin_amdgcn_mfma_f32_16x16x32_bf16(af[m], bf[n], acc[m][n], 0, 0, 0);
    __builtin_amdgcn_s_setprio(0);
  }

  #pragma unroll
  for (int m = 0; m < 4; ++m){
    #pragma unroll
    for (int n = 0; n < 4; ++n){
      #pragma unroll
      for (int rr = 0; rr < 4; ++rr){
        const int R = row0 + wr + m*16 + g*4 + rr;
        const int col = col0 + wc + n*16 + c;
        const float v = acc[m][n][rr];
        if (MODE == 0){
          C0[(size_t)R * Ncols + col] = bfc(tanhf(v) * QSCALE);
        } else if (MODE == 1){
          const int bidx = R >> 11, mm = R & 2047;
          if (col < INNER){
            const int h = col >> 6, d = col & 63;
            C0[((size_t)(bidx*H_ + h) * MKP + (mm + 1)) * DH + d] = bfc(tanhf(v));
          } else {
            const int cc = col - INNER;
            const int h = cc >> 6, d = cc & 63;
            C1[((size_t)(bidx*H_ + h) * MKP + (mm + 1)) * DH + d] = bfc(v);
          }
        } else {
          Cf[(size_t)R * Ncols + col] = v + bias[col];
        }
      }
    }
  }
}

// ---------------------------------------------------------------------------
// v [bh][m][d] bf16 -> vt [bh][d][m] bf16, 64x64 tiles per bh
// ---------------------------------------------------------------------------
__global__ __launch_bounds__(256) void vtrans(
    const u16* __restrict__ vb, u16* __restrict__ vt)
{
  __shared__ short tl[64][72];
  const int t = threadIdx.x;
  const int mt = blockIdx.x, bh = blockIdx.y;
  {
    const int mr = t >> 2, chb = (t & 3) * 2;
    const u16* src = vb + ((size_t)bh * MKP + mt*64 + mr) * DH + chb*8;
    uint4 a = ((const uint4*)src)[0];
    uint4 b = ((const uint4*)src)[1];
    *(uint4*)((char*)tl + mr*144 + chb*16)     = a;
    *(uint4*)((char*)tl + mr*144 + (chb+1)*16) = b;
  }
  __syncthreads();
  {
    const int d = t >> 2, chb = (t & 3) * 2;
    #pragma unroll
    for (int j = 0; j < 2; ++j){
      const int mbase = (chb + j) * 8;
      u16 s[8];
      #pragma unroll
      for (int e = 0; e < 8; ++e) s[e] = (u16)tl[mbase + e][d];
      uint4 o;
      o.x = (u32)s[0] | ((u32)s[1] << 16);
      o.y = (u32)s[2] | ((u32)s[3] << 16);
      o.z = (u32)s[4] | ((u32)s[5] << 16);
      o.w = (u32)s[6] | ((u32)s[7] << 16);
      *(uint4*)(vt + ((size_t)bh * DH + d) * MKP + mt*64 + mbase) = o;
    }
  }
}

// Null-token (key slot 0): k = tanh(null_k), v = null_v
__global__ void fill_null_k(const float* __restrict__ nk, const float* __restrict__ nv,
                            u16* __restrict__ kb, u16* __restrict__ vt)
{
  const int i  = blockIdx.x * 256 + threadIdx.x;   // 0..2047 = bh*64 + d
  const int d  = i & 63, bh = i >> 6;
  kb[(size_t)bh * MKP * DH + d]        = bfc(tanhf(nk[d]));
  vt[((size_t)bh * DH + d) * MKP + 0]  = bfc(nv[d]);
}

// ---------------------------------------------------------------------------
// MFMA flash attention. 4 waves x 16 query rows, KVBLK=64.
// Swapped QK^T (lane holds 16 S-values for one query), exp2-domain online
// softmax, deferred rescale (thr 8 in log2 units -> p <= 256).
// K, V, P all in 128B XOR-swizzled row layout (row&7 == c&7 on every read).
// Double-buffered K/V with register prefetch. LDS = 40KB -> 4 blocks/CU.
// ---------------------------------------------------------------------------
__global__ __launch_bounds__(256) void attn_mfma(
    const u16* __restrict__ qb, const u16* __restrict__ kb,
    const u16* __restrict__ vt, u16* __restrict__ aob)
{
  __shared__ __align__(16) short Kl[2][64*64];   // [key][dim], swizzled rows
  __shared__ __align__(16) short Vl[2][64*64];   // [dim][key], swizzled rows
  __shared__ __align__(16) short Pl[4][16*64];   // [w][q][key], swizzled rows

  const int tid  = threadIdx.x;
  const int w    = tid >> 6;
  const int lane = tid & 63;
  const int c    = lane & 15;
  const int g    = lane >> 4;
  const int bh   = blockIdx.y, b = bh >> 3, h = bh & 7;
  const int qbase = blockIdx.x * 64 + w * 16;
  const int xr   = (c & 7) << 4;                 // read-side row XOR

  short8 qf0, qf1;
  {
    const u16* qrow = qb + ((size_t)(b*N_) + qbase + c) * INNER + h * DH;
    qf0 = *(const short8*)(qrow + g*8);
    qf1 = *(const short8*)(qrow + 32 + g*8);
  }

  f32x4 o[4] = {};                 // O accum: row = query g*4+r, col = dim c
  float m_c = -3.0e38f, l_c = 0.f; // running max/sum (log2 domain), query c

  const u16* kbase = kb + (size_t)bh * MKP * DH;
  const u16* vbase = vt + (size_t)bh * DH * MKP;
  const int srow = tid >> 2, sch = (tid & 3) * 2;
  const int swz0 = ((sch  ) ^ (srow & 7)) << 4;
  const int swz1 = ((sch+1) ^ (srow & 7)) << 4;

  // prologue: tile 0 -> buf 0
  uint4 rk0, rk1, rv0, rv1;
  {
    const u16* ksrc = kbase + (size_t)srow * DH + sch*8;
    rk0 = ((const uint4*)ksrc)[0]; rk1 = ((const uint4*)ksrc)[1];
    const u16* vsrc = vbase + (size_t)srow * MKP + sch*8;
    rv0 = ((const uint4*)vsrc)[0]; rv1 = ((const uint4*)vsrc)[1];
  }
  *(uint4*)((char*)Kl[0] + srow*128 + swz0) = rk0;
  *(uint4*)((char*)Kl[0] + srow*128 + swz1) = rk1;
  *(uint4*)((char*)Vl[0] + srow*128 + swz0) = rv0;
  *(uint4*)((char*)Vl[0] + srow*128 + swz1) = rv1;

  int cur = 0;
  for (int kt = 0; kt < 33; ++kt){
    __syncthreads();
    // issue next tile's global loads early (latency hides under compute)
    if (kt < 32){
      const u16* ksrc = kbase + (size_t)((kt+1)*64 + srow) * DH + sch*8;
      rk0 = ((const uint4*)ksrc)[0]; rk1 = ((const uint4*)ksrc)[1];
      const u16* vsrc = vbase + (size_t)srow * MKP + (kt+1)*64 + sch*8;
      rv0 = ((const uint4*)vsrc)[0]; rv1 = ((const uint4*)vsrc)[1];
    }

    const char* Kc = (const char*)Kl[cur];
    const char* Vc = (const char*)Vl[cur];
    char*       Pw = (char*)Pl + w*2048;

    // ---- swapped QK^T: S[64k x 16q], lane holds keys {s*16+g*4+r} of query c
    f32x4 sv[4];
    __builtin_amdgcn_s_setprio(1);
    #pragma unroll
    for (int s = 0; s < 4; ++s){
      f32x4 a = {0.f, 0.f, 0.f, 0.f};
      #pragma unroll
      for (int hh = 0; hh < 2; ++hh){
        short8 kf = *(const short8*)(Kc + (s*16 + c)*128 + ((hh*64 + g*16) ^ xr));
        a = __builtin_amdgcn_mfma_f32_16x16x32_bf16(kf, hh ? qf1 : qf0, a, 0, 0, 0);
      }
      sv[s] = a;
    }
    __builtin_amdgcn_s_setprio(0);

    if (kt == 32){                    // only key 2048 (tile-local 0) is valid
      #pragma unroll
      for (int s = 0; s < 4; ++s)
        #pragma unroll
        for (int r = 0; r < 4; ++r)
          if (s | r) sv[s][r] = -1e30f;
      if (g) sv[0][0] = -1e30f;
    }

    // ---- online softmax (in-lane over 16 keys, then 2 shfl rounds over g)
    float t0 = fmaxf(fmaxf(sv[0][0], sv[0][1]), fmaxf(sv[0][2], sv[0][3]));
    float t1 = fmaxf(fmaxf(sv[1][0], sv[1][1]), fmaxf(sv[1][2], sv[1][3]));
    float t2 = fmaxf(fmaxf(sv[2][0], sv[2][1]), fmaxf(sv[2][2], sv[2][3]));
    float t3 = fmaxf(fmaxf(sv[3][0], sv[3][1]), fmaxf(sv[3][2], sv[3][3]));
    float tm = fmaxf(fmaxf(t0, t1), fmaxf(t2, t3));
    tm = fmaxf(tm, __shfl_xor(tm, 16));
    tm = fmaxf(tm, __shfl_xor(tm, 32));

    const bool need = tm > m_c + 8.f;    // deferred rescale (p <= 2^8)
    if (__any((int)need)){
      float corr = need ? EXP2(m_c - tm) : 1.f;
      if (need) m_c = tm;
      l_c *= corr;
      #pragma unroll
      for (int r = 0; r < 4; ++r){
        const float cr = __shfl(corr, g*4 + r, 16);
        #pragma unroll
        for (int D = 0; D < 4; ++D) o[D][r] *= cr;
      }
    }

    float psum = 0.f;
    #pragma unroll
    for (int s = 0; s < 4; ++s){
      const float p0 = EXP2(sv[s][0] - m_c);
      const float p1 = EXP2(sv[s][1] - m_c);
      const float p2 = EXP2(sv[s][2] - m_c);
      const float p3 = EXP2(sv[s][3] - m_c);
      psum += (p0 + p1) + (p2 + p3);
      uint2 pk;
      pk.x = bfpk(p0, p1);
      pk.y = bfpk(p2, p3);
      *(uint2*)(Pw + c*128 + ((((2*s + (g>>1)) ^ (c&7)) << 4) | ((g&1)*8))) = pk;
    }
    psum += __shfl_xor(psum, 16);
    psum += __shfl_xor(psum, 32);
    l_c += psum;

    // ---- PV: O[16q x 64d] += P[16x64] @ V[64x64] ----
    __builtin_amdgcn_s_setprio(1);
    #pragma unroll
    for (int hh = 0; hh < 2; ++hh){
      short8 pf = *(const short8*)(Pw + c*128 + (((hh*4 + g) ^ (c&7)) << 4));
      #pragma unroll
      for (int D = 0; D < 4; ++D){
        short8 vf = *(const short8*)(Vc + (D*16 + c)*128 + ((hh*64 + g*16) ^ xr));
        o[D] = __builtin_amdgcn_mfma_f32_16x16x32_bf16(pf, vf, o[D], 0, 0, 0);
      }
    }
    __builtin_amdgcn_s_setprio(0);

    // ---- write next tile to the other buffer
    if (kt < 32){
      char* Kn = (char*)Kl[cur ^ 1];
      char* Vn = (char*)Vl[cur ^ 1];
      *(uint4*)(Kn + srow*128 + swz0) = rk0;
      *(uint4*)(Kn + srow*128 + swz1) = rk1;
      *(uint4*)(Vn + srow*128 + swz0) = rv0;
      *(uint4*)(Vn + srow*128 + swz1) = rv1;
      cur ^= 1;
    }
  }

  // ---- epilogue: normalize, write bf16 ao[b, n, h*64+d] ----
  const float inv = 1.f / l_c;
  #pragma unroll
  for (int r = 0; r < 4; ++r){
    const float ir = __shfl(inv, g*4 + r, 16);
    const size_t nrow = (size_t)(b*N_) + qbase + g*4 + r;
    #pragma unroll
    for (int D = 0; D < 4; ++D)
      aob[nrow * INNER + h*DH + D*16 + c] = bfc(o[D][r] * ir);
  }
}

extern "C" void kernel_launch(void* const* d_in, const int* in_sizes, int n_in,
                              void* d_out, int out_size, void* d_ws, size_t ws_size,
                              hipStream_t stream)
{
  const float* x    = (const float*)d_in[0];
  const float* ctx  = (const float*)d_in[1];
  const float* Wq   = (const float*)d_in[2];
  const float* Wkv  = (const float*)d_in[3];
  const float* nk   = (const float*)d_in[4];
  const float* nv   = (const float*)d_in[5];
  const float* Wout = (const float*)d_in[6];
  const float* bout = (const float*)d_in[7];
  float* out = (float*)d_out;

  char* ws = (char*)d_ws;
  u16* qb    = (u16*)(ws);                       //  8,388,608
  u16* kbB   = (u16*)(ws +  8388608);            //  8,650,752
  u16* vbB   = (u16*)(ws + 17039360);            //  8,650,752
  u16* vtb   = (u16*)(ws + 25690112);            //  8,650,752
  u16* Wqt   = (u16*)(ws + 34340864);            //    524,288
  u16* Wkvt  = (u16*)(ws + 34865152);            //  1,048,576
  u16* Woutt = (u16*)(ws + 35913728);            //    524,288  (end ~36.4MB)
  u16* aoB   = vbB;                              // alias: vbB dead after vtrans

  // weight transposes (fp32 -> bf16 [N][K])
  transpose_wt<<<dim3(8, 8),  256, 0, stream>>>(Wq,   Wqt,   DIMX, INNER);
  transpose_wt<<<dim3(16, 8), 256, 0, stream>>>(Wkv,  Wkvt,  DIMX, 2*INNER);
  transpose_wt<<<dim3(8, 8),  256, 0, stream>>>(Wout, Woutt, INNER, 512);

  // q = bf16(tanh(x @ Wq) * QSCALE)   (A = fp32, converted in staging)
  mgemm<0,1><<<dim3(4, 64), 256, 0, stream>>>(x, Wqt, qb, nullptr, nullptr, nullptr, DIMX, INNER);
  // kv = ctx @ Wkv -> kb (tanh) and vb, row-major [bh][m+1][d]
  mgemm<1,1><<<dim3(8, 64), 256, 0, stream>>>(ctx, Wkvt, kbB, vbB, nullptr, nullptr, DIMX, 2*INNER);
  // v -> v^T  [bh][d][m]
  vtrans<<<dim3(33, 32), 256, 0, stream>>>(vbB, vtb);
  fill_null_k<<<8, 256, 0, stream>>>(nk, nv, kbB, vtb);
  // MFMA flash attention -> ao bf16 (aliases vbB)
  attn_mfma<<<dim3(32, 32), 256, 0, stream>>>(qb, kbB, vtb, aoB);
  // out = ao @ Wout + bout (MFMA, fp32 out)
  mgemm<2,0><<<dim3(4, 64), 256, 0, stream>>>(aoB, Woutt, nullptr, nullptr, out, bout, INNER, 512);
}

// Round 7
// 156.221 us; speedup vs baseline: 8.9484x; 1.0440x over previous
//
#include <hip/hip_runtime.h>
#include <hip/hip_bf16.h>
#include <stdint.h>

#define B_    4
#define N_    2048
#define M_    2048
#define DIMX  512
#define INNER 512
#define H_    8
#define DH    64
#define MK    2049   // M+1 keys (null token at slot 0)
#define MKP   2112   // padded to 33 tiles of 64 (tail masked in-kernel)

#define QSCALE  0.18033688011f   // 0.125 * log2(e): softmax in exp2 domain
#define SM_BIAS -11.5415605f     // static softmax max: |S_log2| <= 64*QSCALE

using u16 = unsigned short;
using u32 = unsigned int;

typedef __attribute__((ext_vector_type(8))) short short8;
typedef __attribute__((ext_vector_type(4))) float f32x4;

#if defined(__has_builtin)
# if __has_builtin(__builtin_amdgcn_exp2f)
#  define EXP2(x) __builtin_amdgcn_exp2f(x)
# endif
#endif
#ifndef EXP2
# define EXP2(x) exp2f(x)
#endif

__device__ __forceinline__ u16 bfc(float f){
  __hip_bfloat16 h = __float2bfloat16(f);
  return *reinterpret_cast<u16*>(&h);
}
__device__ __forceinline__ u32 bfpk(float lo, float hi){
  return (u32)bfc(lo) | ((u32)bfc(hi) << 16);
}

// ---------------------------------------------------------------------------
// All three weight transposes in one dispatch: fp32 [R][C] -> bf16 [C][R].
// z selects {Wq, Wkv, Wout}; 64x64 LDS tiles.
// ---------------------------------------------------------------------------
__global__ __launch_bounds__(256) void transpose_all(
    const float* __restrict__ Wq, const float* __restrict__ Wkv,
    const float* __restrict__ Wout,
    u16* __restrict__ Wqt, u16* __restrict__ Wkvt, u16* __restrict__ Woutt)
{
  const int z = blockIdx.z;
  const float* in = (z == 0) ? Wq : (z == 1) ? Wkv : Wout;
  u16* out        = (z == 0) ? Wqt : (z == 1) ? Wkvt : Woutt;
  const int C     = (z == 1) ? 1024 : 512;   // R = 512 for all
  const int R     = 512;
  if (blockIdx.x * 64 >= C) return;

  __shared__ float tl[64][65];
  const int t = threadIdx.x;
  const int c0 = blockIdx.x * 64, r0 = blockIdx.y * 64;
  const int col = t & 63, rb = t >> 6;
  #pragma unroll
  for (int j = 0; j < 16; ++j){
    const int row = rb + j*4;
    tl[row][col] = in[(size_t)(r0 + row) * C + c0 + col];
  }
  __syncthreads();
  #pragma unroll
  for (int j = 0; j < 16; ++j){
    const int orow = rb + j*4;
    out[(size_t)(c0 + orow) * R + r0 + col] = bfc(tl[col][orow]);
  }
}

// ---------------------------------------------------------------------------
// bf16 MFMA GEMM, 128x128 tile, BK=32, 4 waves (2x2 of 64x64).
// A: fp32 (AF32=1, converted during staging) or bf16 row-major [M][K].
// Bt [N][K] bf16 row-major (pre-transposed weights).
// MODE 0: qb[R][col]  = bf16(tanh(acc) * QSCALE)
// MODE 1: col<512 -> kb[bh][m+1][d] = bf16(tanh); else vb[bh][m+1][d] = bf16
// MODE 2: Cf[R][col] = acc + bias[col]            (fp32 out)
// ---------------------------------------------------------------------------
template<int MODE, int AF32>
__global__ __launch_bounds__(256) void mgemm(
    const void* __restrict__ Ap, const u16* __restrict__ Bt,
    u16* __restrict__ C0, u16* __restrict__ C1,
    float* __restrict__ Cf, const float* __restrict__ bias,
    int K, int Ncols)
{
  __shared__ __align__(16) short At[128*32];
  __shared__ __align__(16) short Bl[128*32];
  const int tid = threadIdx.x;
  const int w = tid >> 6, lane = tid & 63;
  const int c = lane & 15, g = lane >> 4;
  const int row0 = blockIdx.y * 128, col0 = blockIdx.x * 128;
  const int wr = (w >> 1) * 64, wc = (w & 1) * 64;

  f32x4 acc[4][4] = {};

  const int srow = tid >> 1, sj = (tid & 1) * 2;
  for (int k0 = 0; k0 < K; k0 += 32){
    __syncthreads();
    {
      uint4 t0, t1;
      if (AF32){
        const float* src = (const float*)Ap + (size_t)(row0 + srow) * K + k0 + sj*8;
        float4 a0 = ((const float4*)src)[0];
        float4 a1 = ((const float4*)src)[1];
        float4 a2 = ((const float4*)src)[2];
        float4 a3 = ((const float4*)src)[3];
        t0.x = bfpk(a0.x, a0.y); t0.y = bfpk(a0.z, a0.w);
        t0.z = bfpk(a1.x, a1.y); t0.w = bfpk(a1.z, a1.w);
        t1.x = bfpk(a2.x, a2.y); t1.y = bfpk(a2.z, a2.w);
        t1.z = bfpk(a3.x, a3.y); t1.w = bfpk(a3.z, a3.w);
      } else {
        const u16* src = (const u16*)Ap + (size_t)(row0 + srow) * K + k0 + sj*8;
        t0 = ((const uint4*)src)[0];
        t1 = ((const uint4*)src)[1];
      }
      *(uint4*)((char*)At + srow*64 + (((sj  ) ^ ((srow>>1)&3)) << 4)) = t0;
      *(uint4*)((char*)At + srow*64 + (((sj+1) ^ ((srow>>1)&3)) << 4)) = t1;
    }
    {
      const u16* src = Bt + (size_t)(col0 + srow) * K + k0 + sj*8;
      uint4 t0 = ((const uint4*)src)[0];
      uint4 t1 = ((const uint4*)src)[1];
      *(uint4*)((char*)Bl + srow*64 + (((sj  ) ^ ((srow>>1)&3)) << 4)) = t0;
      *(uint4*)((char*)Bl + srow*64 + (((sj+1) ^ ((srow>>1)&3)) << 4)) = t1;
    }
    __syncthreads();

    short8 af[4], bf[4];
    #pragma unroll
    for (int m = 0; m < 4; ++m){
      const int row = wr + m*16 + c;
      af[m] = *(const short8*)((char*)At + row*64 + ((g ^ ((row>>1)&3)) << 4));
    }
    #pragma unroll
    for (int n = 0; n < 4; ++n){
      const int row = wc + n*16 + c;
      bf[n] = *(const short8*)((char*)Bl + row*64 + ((g ^ ((row>>1)&3)) << 4));
    }
    __builtin_amdgcn_s_setprio(1);
    #pragma unroll
    for (int m = 0; m < 4; ++m)
      #pragma unroll
      for (int n = 0; n < 4; ++n)
        acc[m][n] = __builtin_amdgcn_mfma_f32_16x16x32_bf16(af[m], bf[n], acc[m][n], 0, 0, 0);
    __builtin_amdgcn_s_setprio(0);
  }

  #pragma unroll
  for (int m = 0; m < 4; ++m){
    #pragma unroll
    for (int n = 0; n < 4; ++n){
      #pragma unroll
      for (int rr = 0; rr < 4; ++rr){
        const int R = row0 + wr + m*16 + g*4 + rr;
        const int col = col0 + wc + n*16 + c;
        const float v = acc[m][n][rr];
        if (MODE == 0){
          C0[(size_t)R * Ncols + col] = bfc(tanhf(v) * QSCALE);
        } else if (MODE == 1){
          const int bidx = R >> 11, mm = R & 2047;
          if (col < INNER){
            const int h = col >> 6, d = col & 63;
            C0[((size_t)(bidx*H_ + h) * MKP + (mm + 1)) * DH + d] = bfc(tanhf(v));
          } else {
            const int cc = col - INNER;
            const int h = cc >> 6, d = cc & 63;
            C1[((size_t)(bidx*H_ + h) * MKP + (mm + 1)) * DH + d] = bfc(v);
          }
        } else {
          Cf[(size_t)R * Ncols + col] = v + bias[col];
        }
      }
    }
  }
}

// ---------------------------------------------------------------------------
// v [bh][m][d] bf16 -> vt [bh][d][m] bf16, 64x64 tiles per bh.
// Fused null-token fill: key slot 0 gets v = null_v, and kb[...][0][d] gets
// tanh(null_k) (done by the mt==0 blocks).
// ---------------------------------------------------------------------------
__global__ __launch_bounds__(256) void vtrans(
    const u16* __restrict__ vb, u16* __restrict__ vt,
    const float* __restrict__ nk, const float* __restrict__ nv,
    u16* __restrict__ kb)
{
  __shared__ short tl[64][72];
  const int t = threadIdx.x;
  const int mt = blockIdx.x, bh = blockIdx.y;
  {
    const int mr = t >> 2, chb = (t & 3) * 2;
    const u16* src = vb + ((size_t)bh * MKP + mt*64 + mr) * DH + chb*8;
    uint4 a = ((const uint4*)src)[0];
    uint4 b = ((const uint4*)src)[1];
    *(uint4*)((char*)tl + mr*144 + chb*16)     = a;
    *(uint4*)((char*)tl + mr*144 + (chb+1)*16) = b;
  }
  __syncthreads();
  {
    const int d = t >> 2, chb = (t & 3) * 2;
    #pragma unroll
    for (int j = 0; j < 2; ++j){
      const int mbase = (chb + j) * 8;
      u16 s[8];
      #pragma unroll
      for (int e = 0; e < 8; ++e) s[e] = (u16)tl[mbase + e][d];
      if (mt == 0 && mbase == 0) s[0] = bfc(nv[d]);   // null v at key 0
      uint4 o;
      o.x = (u32)s[0] | ((u32)s[1] << 16);
      o.y = (u32)s[2] | ((u32)s[3] << 16);
      o.z = (u32)s[4] | ((u32)s[5] << 16);
      o.w = (u32)s[6] | ((u32)s[7] << 16);
      *(uint4*)(vt + ((size_t)bh * DH + d) * MKP + mt*64 + mbase) = o;
    }
    if (mt == 0 && (t & 3) == 0)                      // null k at key 0
      kb[(size_t)bh * MKP * DH + d] = bfc(tanhf(nk[d]));
  }
}

// ---------------------------------------------------------------------------
// MFMA flash attention. 4 waves x 16 query rows, KVBLK=64.
// Swapped QK^T (lane holds 16 S-values for one query). STATIC softmax max:
// |S_log2| <= 64*QSCALE = 11.54 (q,k both tanh-bounded), folded into the
// MFMA C-init -> p = exp2(sv) directly. No max tracking, no rescale, no
// max reductions: exp2 issues immediately per QK result.
// K, V, P all in 128B XOR-swizzled row layout. Double-buffered K/V.
// ---------------------------------------------------------------------------
__global__ __launch_bounds__(256) void attn_mfma(
    const u16* __restrict__ qb, const u16* __restrict__ kb,
    const u16* __restrict__ vt, u16* __restrict__ aob)
{
  __shared__ __align__(16) short Kl[2][64*64];   // [key][dim], swizzled rows
  __shared__ __align__(16) short Vl[2][64*64];   // [dim][key], swizzled rows
  __shared__ __align__(16) short Pl[4][16*64];   // [w][q][key], swizzled rows

  const int tid  = threadIdx.x;
  const int w    = tid >> 6;
  const int lane = tid & 63;
  const int c    = lane & 15;
  const int g    = lane >> 4;
  const int bh   = blockIdx.y, b = bh >> 3, h = bh & 7;
  const int qbase = blockIdx.x * 64 + w * 16;
  const int xr   = (c & 7) << 4;                 // read-side row XOR

  short8 qf0, qf1;
  {
    const u16* qrow = qb + ((size_t)(b*N_) + qbase + c) * INNER + h * DH;
    qf0 = *(const short8*)(qrow + g*8);
    qf1 = *(const short8*)(qrow + 32 + g*8);
  }

  f32x4 o[4] = {};                 // O accum: row = query g*4+r, col = dim c
  float l_c = 0.f;                 // running sum for query c (static max)

  const u16* kbase = kb + (size_t)bh * MKP * DH;
  const u16* vbase = vt + (size_t)bh * DH * MKP;
  const int srow = tid >> 2, sch = (tid & 3) * 2;
  const int swz0 = ((sch  ) ^ (srow & 7)) << 4;
  const int swz1 = ((sch+1) ^ (srow & 7)) << 4;

  // prologue: tile 0 -> buf 0
  uint4 rk0, rk1, rv0, rv1;
  {
    const u16* ksrc = kbase + (size_t)srow * DH + sch*8;
    rk0 = ((const uint4*)ksrc)[0]; rk1 = ((const uint4*)ksrc)[1];
    const u16* vsrc = vbase + (size_t)srow * MKP + sch*8;
    rv0 = ((const uint4*)vsrc)[0]; rv1 = ((const uint4*)vsrc)[1];
  }
  *(uint4*)((char*)Kl[0] + srow*128 + swz0) = rk0;
  *(uint4*)((char*)Kl[0] + srow*128 + swz1) = rk1;
  *(uint4*)((char*)Vl[0] + srow*128 + swz0) = rv0;
  *(uint4*)((char*)Vl[0] + srow*128 + swz1) = rv1;

  int cur = 0;
  for (int kt = 0; kt < 33; ++kt){
    __syncthreads();
    // issue next tile's global loads early (latency hides under compute)
    if (kt < 32){
      const u16* ksrc = kbase + (size_t)((kt+1)*64 + srow) * DH + sch*8;
      rk0 = ((const uint4*)ksrc)[0]; rk1 = ((const uint4*)ksrc)[1];
      const u16* vsrc = vbase + (size_t)srow * MKP + (kt+1)*64 + sch*8;
      rv0 = ((const uint4*)vsrc)[0]; rv1 = ((const uint4*)vsrc)[1];
    }

    const char* Kc = (const char*)Kl[cur];
    const char* Vc = (const char*)Vl[cur];
    char*       Pw = (char*)Pl + w*2048;

    // ---- swapped QK^T: S[64k x 16q], lane holds keys {s*16+g*4+r} of query c
    // C-init = SM_BIAS folds the static-max subtraction into the MFMA.
    f32x4 sv[4];
    __builtin_amdgcn_s_setprio(1);
    #pragma unroll
    for (int s = 0; s < 4; ++s){
      f32x4 a = {SM_BIAS, SM_BIAS, SM_BIAS, SM_BIAS};
      #pragma unroll
      for (int hh = 0; hh < 2; ++hh){
        short8 kf = *(const short8*)(Kc + (s*16 + c)*128 + ((hh*64 + g*16) ^ xr));
        a = __builtin_amdgcn_mfma_f32_16x16x32_bf16(kf, hh ? qf1 : qf0, a, 0, 0, 0);
      }
      sv[s] = a;
    }
    __builtin_amdgcn_s_setprio(0);

    if (kt == 32){                    // only key 2048 (tile-local 0) is valid
      #pragma unroll
      for (int s = 0; s < 4; ++s)
        #pragma unroll
        for (int r = 0; r < 4; ++r)
          if (s | r) sv[s][r] = -1e30f;
      if (g) sv[0][0] = -1e30f;
    }

    // ---- softmax numerators: p = exp2(sv), fully parallel, no max chain
    float psum = 0.f;
    #pragma unroll
    for (int s = 0; s < 4; ++s){
      const float p0 = EXP2(sv[s][0]);
      const float p1 = EXP2(sv[s][1]);
      const float p2 = EXP2(sv[s][2]);
      const float p3 = EXP2(sv[s][3]);
      psum += (p0 + p1) + (p2 + p3);
      uint2 pk;
      pk.x = bfpk(p0, p1);
      pk.y = bfpk(p2, p3);
      *(uint2*)(Pw + c*128 + ((((2*s + (g>>1)) ^ (c&7)) << 4) | ((g&1)*8))) = pk;
    }
    psum += __shfl_xor(psum, 16);
    psum += __shfl_xor(psum, 32);
    l_c += psum;

    // ---- PV: O[16q x 64d] += P[16x64] @ V[64x64] ----
    __builtin_amdgcn_s_setprio(1);
    #pragma unroll
    for (int hh = 0; hh < 2; ++hh){
      short8 pf = *(const short8*)(Pw + c*128 + (((hh*4 + g) ^ (c&7)) << 4));
      #pragma unroll
      for (int D = 0; D < 4; ++D){
        short8 vf = *(const short8*)(Vc + (D*16 + c)*128 + ((hh*64 + g*16) ^ xr));
        o[D] = __builtin_amdgcn_mfma_f32_16x16x32_bf16(pf, vf, o[D], 0, 0, 0);
      }
    }
    __builtin_amdgcn_s_setprio(0);

    // ---- write next tile to the other buffer
    if (kt < 32){
      char* Kn = (char*)Kl[cur ^ 1];
      char* Vn = (char*)Vl[cur ^ 1];
      *(uint4*)(Kn + srow*128 + swz0) = rk0;
      *(uint4*)(Kn + srow*128 + swz1) = rk1;
      *(uint4*)(Vn + srow*128 + swz0) = rv0;
      *(uint4*)(Vn + srow*128 + swz1) = rv1;
      cur ^= 1;
    }
  }

  // ---- epilogue: normalize, write bf16 ao[b, n, h*64+d] ----
  const float inv = 1.f / l_c;
  #pragma unroll
  for (int r = 0; r < 4; ++r){
    const float ir = __shfl(inv, g*4 + r, 16);
    const size_t nrow = (size_t)(b*N_) + qbase + g*4 + r;
    #pragma unroll
    for (int D = 0; D < 4; ++D)
      aob[nrow * INNER + h*DH + D*16 + c] = bfc(o[D][r] * ir);
  }
}

extern "C" void kernel_launch(void* const* d_in, const int* in_sizes, int n_in,
                              void* d_out, int out_size, void* d_ws, size_t ws_size,
                              hipStream_t stream)
{
  const float* x    = (const float*)d_in[0];
  const float* ctx  = (const float*)d_in[1];
  const float* Wq   = (const float*)d_in[2];
  const float* Wkv  = (const float*)d_in[3];
  const float* nk   = (const float*)d_in[4];
  const float* nv   = (const float*)d_in[5];
  const float* Wout = (const float*)d_in[6];
  const float* bout = (const float*)d_in[7];
  float* out = (float*)d_out;

  char* ws = (char*)d_ws;
  u16* qb    = (u16*)(ws);                       //  8,388,608
  u16* kbB   = (u16*)(ws +  8388608);            //  8,650,752
  u16* vbB   = (u16*)(ws + 17039360);            //  8,650,752
  u16* vtb   = (u16*)(ws + 25690112);            //  8,650,752
  u16* Wqt   = (u16*)(ws + 34340864);            //    524,288
  u16* Wkvt  = (u16*)(ws + 34865152);            //  1,048,576
  u16* Woutt = (u16*)(ws + 35913728);            //    524,288  (end ~36.4MB)
  u16* aoB   = vbB;                              // alias: vbB dead after vtrans

  // weight transposes (fp32 -> bf16 [N][K]), one dispatch
  transpose_all<<<dim3(16, 8, 3), 256, 0, stream>>>(Wq, Wkv, Wout, Wqt, Wkvt, Woutt);

  // q = bf16(tanh(x @ Wq) * QSCALE)   (A = fp32, converted in staging)
  mgemm<0,1><<<dim3(4, 64), 256, 0, stream>>>(x, Wqt, qb, nullptr, nullptr, nullptr, DIMX, INNER);
  // kv = ctx @ Wkv -> kb (tanh) and vb, row-major [bh][m+1][d]
  mgemm<1,1><<<dim3(8, 64), 256, 0, stream>>>(ctx, Wkvt, kbB, vbB, nullptr, nullptr, DIMX, 2*INNER);
  // v -> v^T [bh][d][m], fused null k/v fill
  vtrans<<<dim3(33, 32), 256, 0, stream>>>(vbB, vtb, nk, nv, kbB);
  // MFMA flash attention -> ao bf16 (aliases vbB)
  attn_mfma<<<dim3(32, 32), 256, 0, stream>>>(qb, kbB, vtb, aoB);
  // out = ao @ Wout + bout (MFMA, fp32 out)
  mgemm<2,0><<<dim3(4, 64), 256, 0, stream>>>(aoB, Woutt, nullptr, nullptr, out, bout, INNER, 512);
}

// Round 8
// 121.858 us; speedup vs baseline: 11.4717x; 1.2820x over previous
//
#include <hip/hip_runtime.h>
#include <hip/hip_bf16.h>
#include <stdint.h>

#define B_    4
#define N_    2048
#define M_    2048
#define DIMX  512
#define INNER 512
#define H_    8
#define DH    64
#define MK    2049   // M+1 keys (null token at slot 0)
#define MKP   2112   // padded to 33 tiles of 64 (tail masked in-kernel)

#define QSCALE  0.18033688011f   // 0.125 * log2(e): softmax in exp2 domain
#define SM_BIAS -11.5415605f     // static softmax max: |S_log2| <= 64*QSCALE

using u16 = unsigned short;
using u32 = unsigned int;

typedef __attribute__((ext_vector_type(8))) short short8;
typedef __attribute__((ext_vector_type(4))) float f32x4;

#if defined(__has_builtin)
# if __has_builtin(__builtin_amdgcn_exp2f)
#  define EXP2(x) __builtin_amdgcn_exp2f(x)
# endif
#endif
#ifndef EXP2
# define EXP2(x) exp2f(x)
#endif

__device__ __forceinline__ u16 bfc(float f){
  __hip_bfloat16 h = __float2bfloat16(f);
  return *reinterpret_cast<u16*>(&h);
}
__device__ __forceinline__ u32 bfpk(float lo, float hi){
  return (u32)bfc(lo) | ((u32)bfc(hi) << 16);
}

// ---------------------------------------------------------------------------
// All three weight transposes in one dispatch: fp32 [R][C] -> bf16 [C][R].
// ---------------------------------------------------------------------------
__global__ __launch_bounds__(256) void transpose_all(
    const float* __restrict__ Wq, const float* __restrict__ Wkv,
    const float* __restrict__ Wout,
    u16* __restrict__ Wqt, u16* __restrict__ Wkvt, u16* __restrict__ Woutt)
{
  const int z = blockIdx.z;
  const float* in = (z == 0) ? Wq : (z == 1) ? Wkv : Wout;
  u16* out        = (z == 0) ? Wqt : (z == 1) ? Wkvt : Woutt;
  const int C     = (z == 1) ? 1024 : 512;   // R = 512 for all
  const int R     = 512;
  if (blockIdx.x * 64 >= C) return;

  __shared__ float tl[64][65];
  const int t = threadIdx.x;
  const int c0 = blockIdx.x * 64, r0 = blockIdx.y * 64;
  const int col = t & 63, rb = t >> 6;
  #pragma unroll
  for (int j = 0; j < 16; ++j){
    const int row = rb + j*4;
    tl[row][col] = in[(size_t)(r0 + row) * C + c0 + col];
  }
  __syncthreads();
  #pragma unroll
  for (int j = 0; j < 16; ++j){
    const int orow = rb + j*4;
    out[(size_t)(c0 + orow) * R + r0 + col] = bfc(tl[col][orow]);
  }
}

// ---------------------------------------------------------------------------
// Fused q + kv projection GEMM. 768 blocks: tile<256 -> q (gx=4), else kv
// (gx=8). 128x128 tile, BK=32, K=512, 4 waves. A fp32 (converted in staging).
// Register-prefetch + double-buffered LDS (single barrier per K-step).
// XCD-chunked block swizzle for L2 locality.
// ---------------------------------------------------------------------------
__global__ __launch_bounds__(256, 3) void fused_proj(
    const float* __restrict__ x, const float* __restrict__ ctx,
    const u16* __restrict__ Wqt, const u16* __restrict__ Wkvt,
    u16* __restrict__ qb, u16* __restrict__ kb, u16* __restrict__ vb)
{
  __shared__ __align__(16) short At[2][128*32];
  __shared__ __align__(16) short Bl[2][128*32];

  const int flat = blockIdx.x;
  const int tile = (flat & 7) * 96 + (flat >> 3);    // XCD-chunked, bijective
  const bool isq = tile < 256;
  const int lt   = isq ? tile : tile - 256;
  const int gx   = isq ? 4 : 8;
  const int row0 = (lt / gx) * 128, col0 = (lt % gx) * 128;
  const float* A = isq ? x : ctx;
  const u16*  Bt = isq ? Wqt : Wkvt;

  const int tid = threadIdx.x;
  const int w = tid >> 6, lane = tid & 63;
  const int c = lane & 15, g = lane >> 4;
  const int wr = (w >> 1) * 64, wc = (w & 1) * 64;

  f32x4 acc[4][4] = {};

  const int srow = tid >> 1, sj = (tid & 1) * 2;
  const int swz0 = ((sj  ) ^ ((srow >> 1) & 3)) << 4;
  const int swz1 = ((sj+1) ^ ((srow >> 1) & 3)) << 4;

  float4 a0, a1, a2, a3;
  uint4  b0, b1;
  const float* asrc = A  + (size_t)(row0 + srow) * DIMX + sj*8;
  const u16*   bsrc = Bt + (size_t)(col0 + srow) * DIMX + sj*8;

  // prologue: K-step 0 -> regs -> buf 0
  a0 = ((const float4*)asrc)[0]; a1 = ((const float4*)asrc)[1];
  a2 = ((const float4*)asrc)[2]; a3 = ((const float4*)asrc)[3];
  b0 = ((const uint4*)bsrc)[0];  b1 = ((const uint4*)bsrc)[1];
  {
    uint4 t0, t1;
    t0.x = bfpk(a0.x, a0.y); t0.y = bfpk(a0.z, a0.w);
    t0.z = bfpk(a1.x, a1.y); t0.w = bfpk(a1.z, a1.w);
    t1.x = bfpk(a2.x, a2.y); t1.y = bfpk(a2.z, a2.w);
    t1.z = bfpk(a3.x, a3.y); t1.w = bfpk(a3.z, a3.w);
    *(uint4*)((char*)At[0] + srow*64 + swz0) = t0;
    *(uint4*)((char*)At[0] + srow*64 + swz1) = t1;
    *(uint4*)((char*)Bl[0] + srow*64 + swz0) = b0;
    *(uint4*)((char*)Bl[0] + srow*64 + swz1) = b1;
  }

  int cur = 0;
  #pragma unroll 4
  for (int kk = 0; kk < 16; ++kk){
    __syncthreads();
    if (kk < 15){                       // issue next K-step loads early
      const float* an = asrc + (kk+1)*32;
      const u16*   bn = bsrc + (kk+1)*32;
      a0 = ((const float4*)an)[0]; a1 = ((const float4*)an)[1];
      a2 = ((const float4*)an)[2]; a3 = ((const float4*)an)[3];
      b0 = ((const uint4*)bn)[0];  b1 = ((const uint4*)bn)[1];
    }

    short8 af[4], bf[4];
    #pragma unroll
    for (int m = 0; m < 4; ++m){
      const int row = wr + m*16 + c;
      af[m] = *(const short8*)((char*)At[cur] + row*64 + ((g ^ ((row>>1)&3)) << 4));
    }
    #pragma unroll
    for (int n = 0; n < 4; ++n){
      const int row = wc + n*16 + c;
      bf[n] = *(const short8*)((char*)Bl[cur] + row*64 + ((g ^ ((row>>1)&3)) << 4));
    }
    __builtin_amdgcn_s_setprio(1);
    #pragma unroll
    for (int m = 0; m < 4; ++m)
      #pragma unroll
      for (int n = 0; n < 4; ++n)
        acc[m][n] = __builtin_amdgcn_mfma_f32_16x16x32_bf16(af[m], bf[n], acc[m][n], 0, 0, 0);
    __builtin_amdgcn_s_setprio(0);

    if (kk < 15){                       // convert + write next buffer
      uint4 t0, t1;
      t0.x = bfpk(a0.x, a0.y); t0.y = bfpk(a0.z, a0.w);
      t0.z = bfpk(a1.x, a1.y); t0.w = bfpk(a1.z, a1.w);
      t1.x = bfpk(a2.x, a2.y); t1.y = bfpk(a2.z, a2.w);
      t1.z = bfpk(a3.x, a3.y); t1.w = bfpk(a3.z, a3.w);
      char* An = (char*)At[cur ^ 1];
      char* Bn = (char*)Bl[cur ^ 1];
      *(uint4*)(An + srow*64 + swz0) = t0;
      *(uint4*)(An + srow*64 + swz1) = t1;
      *(uint4*)(Bn + srow*64 + swz0) = b0;
      *(uint4*)(Bn + srow*64 + swz1) = b1;
      cur ^= 1;
    }
  }

  #pragma unroll
  for (int m = 0; m < 4; ++m){
    #pragma unroll
    for (int n = 0; n < 4; ++n){
      #pragma unroll
      for (int rr = 0; rr < 4; ++rr){
        const int R = row0 + wr + m*16 + g*4 + rr;
        const int col = col0 + wc + n*16 + c;
        const float v = acc[m][n][rr];
        if (isq){
          qb[(size_t)R * INNER + col] = bfc(tanhf(v) * QSCALE);
        } else {
          const int bidx = R >> 11, mm = R & 2047;
          if (col < INNER){
            const int h = col >> 6, d = col & 63;
            kb[((size_t)(bidx*H_ + h) * MKP + (mm + 1)) * DH + d] = bfc(tanhf(v));
          } else {
            const int cc = col - INNER;
            const int h = cc >> 6, d = cc & 63;
            vb[((size_t)(bidx*H_ + h) * MKP + (mm + 1)) * DH + d] = bfc(v);
          }
        }
      }
    }
  }
}

// ---------------------------------------------------------------------------
// Out-projection GEMM: out = ao @ Wout^T + bias. A bf16 [8192][512],
// Bt bf16 [512][512]. Same dbuf/prefetch/swizzle structure, fp32 output.
// ---------------------------------------------------------------------------
__global__ __launch_bounds__(256) void mgemm_out(
    const u16* __restrict__ A, const u16* __restrict__ Bt,
    float* __restrict__ Cf, const float* __restrict__ bias)
{
  __shared__ __align__(16) short At[2][128*32];
  __shared__ __align__(16) short Bl[2][128*32];

  const int flat = blockIdx.x;                       // 256 blocks
  const int tile = (flat & 7) * 32 + (flat >> 3);    // XCD-chunked
  const int row0 = (tile >> 2) * 128, col0 = (tile & 3) * 128;

  const int tid = threadIdx.x;
  const int w = tid >> 6, lane = tid & 63;
  const int c = lane & 15, g = lane >> 4;
  const int wr = (w >> 1) * 64, wc = (w & 1) * 64;

  f32x4 acc[4][4] = {};

  const int srow = tid >> 1, sj = (tid & 1) * 2;
  const int swz0 = ((sj  ) ^ ((srow >> 1) & 3)) << 4;
  const int swz1 = ((sj+1) ^ ((srow >> 1) & 3)) << 4;

  uint4 ta0, ta1, b0, b1;
  const u16* asrc = A  + (size_t)(row0 + srow) * INNER + sj*8;
  const u16* bsrc = Bt + (size_t)(col0 + srow) * INNER + sj*8;

  ta0 = ((const uint4*)asrc)[0]; ta1 = ((const uint4*)asrc)[1];
  b0  = ((const uint4*)bsrc)[0]; b1  = ((const uint4*)bsrc)[1];
  *(uint4*)((char*)At[0] + srow*64 + swz0) = ta0;
  *(uint4*)((char*)At[0] + srow*64 + swz1) = ta1;
  *(uint4*)((char*)Bl[0] + srow*64 + swz0) = b0;
  *(uint4*)((char*)Bl[0] + srow*64 + swz1) = b1;

  int cur = 0;
  #pragma unroll 4
  for (int kk = 0; kk < 16; ++kk){
    __syncthreads();
    if (kk < 15){
      const u16* an = asrc + (kk+1)*32;
      const u16* bn = bsrc + (kk+1)*32;
      ta0 = ((const uint4*)an)[0]; ta1 = ((const uint4*)an)[1];
      b0  = ((const uint4*)bn)[0]; b1  = ((const uint4*)bn)[1];
    }

    short8 af[4], bf[4];
    #pragma unroll
    for (int m = 0; m < 4; ++m){
      const int row = wr + m*16 + c;
      af[m] = *(const short8*)((char*)At[cur] + row*64 + ((g ^ ((row>>1)&3)) << 4));
    }
    #pragma unroll
    for (int n = 0; n < 4; ++n){
      const int row = wc + n*16 + c;
      bf[n] = *(const short8*)((char*)Bl[cur] + row*64 + ((g ^ ((row>>1)&3)) << 4));
    }
    __builtin_amdgcn_s_setprio(1);
    #pragma unroll
    for (int m = 0; m < 4; ++m)
      #pragma unroll
      for (int n = 0; n < 4; ++n)
        acc[m][n] = __builtin_amdgcn_mfma_f32_16x16x32_bf16(af[m], bf[n], acc[m][n], 0, 0, 0);
    __builtin_amdgcn_s_setprio(0);

    if (kk < 15){
      char* An = (char*)At[cur ^ 1];
      char* Bn = (char*)Bl[cur ^ 1];
      *(uint4*)(An + srow*64 + swz0) = ta0;
      *(uint4*)(An + srow*64 + swz1) = ta1;
      *(uint4*)(Bn + srow*64 + swz0) = b0;
      *(uint4*)(Bn + srow*64 + swz1) = b1;
      cur ^= 1;
    }
  }

  #pragma unroll
  for (int m = 0; m < 4; ++m){
    #pragma unroll
    for (int n = 0; n < 4; ++n){
      #pragma unroll
      for (int rr = 0; rr < 4; ++rr){
        const int R = row0 + wr + m*16 + g*4 + rr;
        const int col = col0 + wc + n*16 + c;
        Cf[(size_t)R * 512 + col] = acc[m][n][rr] + bias[col];
      }
    }
  }
}

// ---------------------------------------------------------------------------
// v [bh][m][d] bf16 -> vt [bh][d][m] bf16, 64x64 tiles per bh.
// Fused null-token fill (mt==0 blocks).
// ---------------------------------------------------------------------------
__global__ __launch_bounds__(256) void vtrans(
    const u16* __restrict__ vb, u16* __restrict__ vt,
    const float* __restrict__ nk, const float* __restrict__ nv,
    u16* __restrict__ kb)
{
  __shared__ short tl[64][72];
  const int t = threadIdx.x;
  const int mt = blockIdx.x, bh = blockIdx.y;
  {
    const int mr = t >> 2, chb = (t & 3) * 2;
    const u16* src = vb + ((size_t)bh * MKP + mt*64 + mr) * DH + chb*8;
    uint4 a = ((const uint4*)src)[0];
    uint4 b = ((const uint4*)src)[1];
    *(uint4*)((char*)tl + mr*144 + chb*16)     = a;
    *(uint4*)((char*)tl + mr*144 + (chb+1)*16) = b;
  }
  __syncthreads();
  {
    const int d = t >> 2, chb = (t & 3) * 2;
    #pragma unroll
    for (int j = 0; j < 2; ++j){
      const int mbase = (chb + j) * 8;
      u16 s[8];
      #pragma unroll
      for (int e = 0; e < 8; ++e) s[e] = (u16)tl[mbase + e][d];
      if (mt == 0 && mbase == 0) s[0] = bfc(nv[d]);   // null v at key 0
      uint4 o;
      o.x = (u32)s[0] | ((u32)s[1] << 16);
      o.y = (u32)s[2] | ((u32)s[3] << 16);
      o.z = (u32)s[4] | ((u32)s[5] << 16);
      o.w = (u32)s[6] | ((u32)s[7] << 16);
      *(uint4*)(vt + ((size_t)bh * DH + d) * MKP + mt*64 + mbase) = o;
    }
    if (mt == 0 && (t & 3) == 0)                      // null k at key 0
      kb[(size_t)bh * MKP * DH + d] = bfc(tanhf(nk[d]));
  }
}

// ---------------------------------------------------------------------------
// MFMA flash attention. 4 waves x 16 query rows, KVBLK=64. Swapped QK^T,
// static softmax max folded into MFMA C-init, p = exp2(sv) directly.
// K, V, P in 128B XOR-swizzled rows. Double-buffered K/V.
// ---------------------------------------------------------------------------
__global__ __launch_bounds__(256) void attn_mfma(
    const u16* __restrict__ qb, const u16* __restrict__ kb,
    const u16* __restrict__ vt, u16* __restrict__ aob)
{
  __shared__ __align__(16) short Kl[2][64*64];
  __shared__ __align__(16) short Vl[2][64*64];
  __shared__ __align__(16) short Pl[4][16*64];

  const int tid  = threadIdx.x;
  const int w    = tid >> 6;
  const int lane = tid & 63;
  const int c    = lane & 15;
  const int g    = lane >> 4;
  const int bh   = blockIdx.y, b = bh >> 3, h = bh & 7;
  const int qbase = blockIdx.x * 64 + w * 16;
  const int xr   = (c & 7) << 4;

  short8 qf0, qf1;
  {
    const u16* qrow = qb + ((size_t)(b*N_) + qbase + c) * INNER + h * DH;
    qf0 = *(const short8*)(qrow + g*8);
    qf1 = *(const short8*)(qrow + 32 + g*8);
  }

  f32x4 o[4] = {};
  float l_c = 0.f;

  const u16* kbase = kb + (size_t)bh * MKP * DH;
  const u16* vbase = vt + (size_t)bh * DH * MKP;
  const int srow = tid >> 2, sch = (tid & 3) * 2;
  const int swz0 = ((sch  ) ^ (srow & 7)) << 4;
  const int swz1 = ((sch+1) ^ (srow & 7)) << 4;

  uint4 rk0, rk1, rv0, rv1;
  {
    const u16* ksrc = kbase + (size_t)srow * DH + sch*8;
    rk0 = ((const uint4*)ksrc)[0]; rk1 = ((const uint4*)ksrc)[1];
    const u16* vsrc = vbase + (size_t)srow * MKP + sch*8;
    rv0 = ((const uint4*)vsrc)[0]; rv1 = ((const uint4*)vsrc)[1];
  }
  *(uint4*)((char*)Kl[0] + srow*128 + swz0) = rk0;
  *(uint4*)((char*)Kl[0] + srow*128 + swz1) = rk1;
  *(uint4*)((char*)Vl[0] + srow*128 + swz0) = rv0;
  *(uint4*)((char*)Vl[0] + srow*128 + swz1) = rv1;

  int cur = 0;
  for (int kt = 0; kt < 33; ++kt){
    __syncthreads();
    if (kt < 32){
      const u16* ksrc = kbase + (size_t)((kt+1)*64 + srow) * DH + sch*8;
      rk0 = ((const uint4*)ksrc)[0]; rk1 = ((const uint4*)ksrc)[1];
      const u16* vsrc = vbase + (size_t)srow * MKP + (kt+1)*64 + sch*8;
      rv0 = ((const uint4*)vsrc)[0]; rv1 = ((const uint4*)vsrc)[1];
    }

    const char* Kc = (const char*)Kl[cur];
    const char* Vc = (const char*)Vl[cur];
    char*       Pw = (char*)Pl + w*2048;

    f32x4 sv[4];
    __builtin_amdgcn_s_setprio(1);
    #pragma unroll
    for (int s = 0; s < 4; ++s){
      f32x4 a = {SM_BIAS, SM_BIAS, SM_BIAS, SM_BIAS};
      #pragma unroll
      for (int hh = 0; hh < 2; ++hh){
        short8 kf = *(const short8*)(Kc + (s*16 + c)*128 + ((hh*64 + g*16) ^ xr));
        a = __builtin_amdgcn_mfma_f32_16x16x32_bf16(kf, hh ? qf1 : qf0, a, 0, 0, 0);
      }
      sv[s] = a;
    }
    __builtin_amdgcn_s_setprio(0);

    if (kt == 32){
      #pragma unroll
      for (int s = 0; s < 4; ++s)
        #pragma unroll
        for (int r = 0; r < 4; ++r)
          if (s | r) sv[s][r] = -1e30f;
      if (g) sv[0][0] = -1e30f;
    }

    float psum = 0.f;
    #pragma unroll
    for (int s = 0; s < 4; ++s){
      const float p0 = EXP2(sv[s][0]);
      const float p1 = EXP2(sv[s][1]);
      const float p2 = EXP2(sv[s][2]);
      const float p3 = EXP2(sv[s][3]);
      psum += (p0 + p1) + (p2 + p3);
      uint2 pk;
      pk.x = bfpk(p0, p1);
      pk.y = bfpk(p2, p3);
      *(uint2*)(Pw + c*128 + ((((2*s + (g>>1)) ^ (c&7)) << 4) | ((g&1)*8))) = pk;
    }
    psum += __shfl_xor(psum, 16);
    psum += __shfl_xor(psum, 32);
    l_c += psum;

    __builtin_amdgcn_s_setprio(1);
    #pragma unroll
    for (int hh = 0; hh < 2; ++hh){
      short8 pf = *(const short8*)(Pw + c*128 + (((hh*4 + g) ^ (c&7)) << 4));
      #pragma unroll
      for (int D = 0; D < 4; ++D){
        short8 vf = *(const short8*)(Vc + (D*16 + c)*128 + ((hh*64 + g*16) ^ xr));
        o[D] = __builtin_amdgcn_mfma_f32_16x16x32_bf16(pf, vf, o[D], 0, 0, 0);
      }
    }
    __builtin_amdgcn_s_setprio(0);

    if (kt < 32){
      char* Kn = (char*)Kl[cur ^ 1];
      char* Vn = (char*)Vl[cur ^ 1];
      *(uint4*)(Kn + srow*128 + swz0) = rk0;
      *(uint4*)(Kn + srow*128 + swz1) = rk1;
      *(uint4*)(Vn + srow*128 + swz0) = rv0;
      *(uint4*)(Vn + srow*128 + swz1) = rv1;
      cur ^= 1;
    }
  }

  const float inv = 1.f / l_c;
  #pragma unroll
  for (int r = 0; r < 4; ++r){
    const float ir = __shfl(inv, g*4 + r, 16);
    const size_t nrow = (size_t)(b*N_) + qbase + g*4 + r;
    #pragma unroll
    for (int D = 0; D < 4; ++D)
      aob[nrow * INNER + h*DH + D*16 + c] = bfc(o[D][r] * ir);
  }
}

extern "C" void kernel_launch(void* const* d_in, const int* in_sizes, int n_in,
                              void* d_out, int out_size, void* d_ws, size_t ws_size,
                              hipStream_t stream)
{
  const float* x    = (const float*)d_in[0];
  const float* ctx  = (const float*)d_in[1];
  const float* Wq   = (const float*)d_in[2];
  const float* Wkv  = (const float*)d_in[3];
  const float* nk   = (const float*)d_in[4];
  const float* nv   = (const float*)d_in[5];
  const float* Wout = (const float*)d_in[6];
  const float* bout = (const float*)d_in[7];
  float* out = (float*)d_out;

  char* ws = (char*)d_ws;
  u16* qb    = (u16*)(ws);                       //  8,388,608
  u16* kbB   = (u16*)(ws +  8388608);            //  8,650,752
  u16* vbB   = (u16*)(ws + 17039360);            //  8,650,752
  u16* vtb   = (u16*)(ws + 25690112);            //  8,650,752
  u16* Wqt   = (u16*)(ws + 34340864);            //    524,288
  u16* Wkvt  = (u16*)(ws + 34865152);            //  1,048,576
  u16* Woutt = (u16*)(ws + 35913728);            //    524,288  (end ~36.4MB)
  u16* aoB   = vbB;                              // alias: vbB dead after vtrans

  // weight transposes (fp32 -> bf16 [N][K]), one dispatch
  transpose_all<<<dim3(16, 8, 3), 256, 0, stream>>>(Wq, Wkv, Wout, Wqt, Wkvt, Woutt);

  // fused q + kv projections (dbuf + XCD swizzle)
  fused_proj<<<768, 256, 0, stream>>>(x, ctx, Wqt, Wkvt, qb, kbB, vbB);
  // v -> v^T [bh][d][m], fused null k/v fill
  vtrans<<<dim3(33, 32), 256, 0, stream>>>(vbB, vtb, nk, nv, kbB);
  // MFMA flash attention -> ao bf16 (aliases vbB)
  attn_mfma<<<dim3(32, 32), 256, 0, stream>>>(qb, kbB, vtb, aoB);
  // out = ao @ Wout + bout (dbuf + swizzle, fp32 out)
  mgemm_out<<<256, 256, 0, stream>>>(aoB, Woutt, out, bout);
}

// Round 9
// 118.559 us; speedup vs baseline: 11.7909x; 1.0278x over previous
//
#include <hip/hip_runtime.h>
#include <hip/hip_bf16.h>
#include <stdint.h>

#define B_    4
#define N_    2048
#define M_    2048
#define DIMX  512
#define INNER 512
#define H_    8
#define DH    64
#define MK    2049   // M+1 keys (null token at slot 0)
#define MKP   2112   // padded to 33 tiles of 64 (tail masked in-kernel)

#define QSCALE  0.18033688011f   // 0.125 * log2(e): softmax in exp2 domain
#define SM_BIAS -11.5415605f     // static softmax max: |S_log2| <= 64*QSCALE

using u16 = unsigned short;
using u32 = unsigned int;

typedef __attribute__((ext_vector_type(8))) short short8;
typedef __attribute__((ext_vector_type(4))) float f32x4;

#if defined(__has_builtin)
# if __has_builtin(__builtin_amdgcn_exp2f)
#  define EXP2(x) __builtin_amdgcn_exp2f(x)
# endif
#endif
#ifndef EXP2
# define EXP2(x) exp2f(x)
#endif

__device__ __forceinline__ u16 bfc(float f){
  __hip_bfloat16 h = __float2bfloat16(f);
  return *reinterpret_cast<u16*>(&h);
}
__device__ __forceinline__ u32 bfpk(float lo, float hi){
  return (u32)bfc(lo) | ((u32)bfc(hi) << 16);
}

// ---------------------------------------------------------------------------
// fp32 -> bf16 streaming convert for x (z=0) and ctx (z=1). 8 elems/thread.
// ---------------------------------------------------------------------------
__global__ __launch_bounds__(256) void convert_bf(
    const float* __restrict__ x, const float* __restrict__ ctx,
    u16* __restrict__ xb, u16* __restrict__ cb)
{
  const float* in = blockIdx.z ? ctx : x;
  u16* out        = blockIdx.z ? cb : xb;
  const int i = blockIdx.x * 256 + threadIdx.x;   // 524288 threads = 4M elems
  float4 a = ((const float4*)in)[i*2];
  float4 b = ((const float4*)in)[i*2+1];
  uint4 t;
  t.x = bfpk(a.x, a.y); t.y = bfpk(a.z, a.w);
  t.z = bfpk(b.x, b.y); t.w = bfpk(b.z, b.w);
  ((uint4*)out)[i] = t;
}

// ---------------------------------------------------------------------------
// All three weight transposes in one dispatch: fp32 [R][C] -> bf16 [C][R].
// ---------------------------------------------------------------------------
__global__ __launch_bounds__(256) void transpose_all(
    const float* __restrict__ Wq, const float* __restrict__ Wkv,
    const float* __restrict__ Wout,
    u16* __restrict__ Wqt, u16* __restrict__ Wkvt, u16* __restrict__ Woutt)
{
  const int z = blockIdx.z;
  const float* in = (z == 0) ? Wq : (z == 1) ? Wkv : Wout;
  u16* out        = (z == 0) ? Wqt : (z == 1) ? Wkvt : Woutt;
  const int C     = (z == 1) ? 1024 : 512;   // R = 512 for all
  const int R     = 512;
  if (blockIdx.x * 64 >= C) return;

  __shared__ float tl[64][65];
  const int t = threadIdx.x;
  const int c0 = blockIdx.x * 64, r0 = blockIdx.y * 64;
  const int col = t & 63, rb = t >> 6;
  #pragma unroll
  for (int j = 0; j < 16; ++j){
    const int row = rb + j*4;
    tl[row][col] = in[(size_t)(r0 + row) * C + c0 + col];
  }
  __syncthreads();
  #pragma unroll
  for (int j = 0; j < 16; ++j){
    const int orow = rb + j*4;
    out[(size_t)(c0 + orow) * R + r0 + col] = bfc(tl[col][orow]);
  }
}

// frag-read + 16 MFMA from LDS buffer `bi` (compile-time)
#define PROJ_COMPUTE(bi)                                                      \
  {                                                                           \
    short8 af[4], bf[4];                                                      \
    _Pragma("unroll")                                                         \
    for (int m = 0; m < 4; ++m){                                              \
      const int row = wr + m*16 + c;                                          \
      af[m] = *(const short8*)((char*)At[bi] + row*64 + ((g ^ ((row>>1)&3)) << 4)); \
    }                                                                         \
    _Pragma("unroll")                                                         \
    for (int n = 0; n < 4; ++n){                                              \
      const int row = wc + n*16 + c;                                          \
      bf[n] = *(const short8*)((char*)Bl[bi] + row*64 + ((g ^ ((row>>1)&3)) << 4)); \
    }                                                                         \
    __builtin_amdgcn_s_setprio(1);                                            \
    _Pragma("unroll")                                                         \
    for (int m = 0; m < 4; ++m)                                               \
      _Pragma("unroll")                                                       \
      for (int n = 0; n < 4; ++n)                                             \
        acc[m][n] = __builtin_amdgcn_mfma_f32_16x16x32_bf16(af[m], bf[n], acc[m][n], 0, 0, 0); \
    __builtin_amdgcn_s_setprio(0);                                            \
  }

// ---------------------------------------------------------------------------
// Fused q + kv projection GEMM, all-bf16 inputs. 768 blocks (XCD-chunked):
// tile<256 -> q (gx=4), else kv (gx=8). 128x128 tile, BK=32, 16 K-steps.
// Depth-2 register prefetch + double-buffered LDS: tile k+2 issued before
// computing tile k -> ~2 compute-phases of latency coverage.
// ---------------------------------------------------------------------------
__global__ __launch_bounds__(256, 3) void fused_proj(
    const u16* __restrict__ xb, const u16* __restrict__ cb,
    const u16* __restrict__ Wqt, const u16* __restrict__ Wkvt,
    u16* __restrict__ qb, u16* __restrict__ kb, u16* __restrict__ vb)
{
  __shared__ __align__(16) short At[2][128*32];
  __shared__ __align__(16) short Bl[2][128*32];

  const int flat = blockIdx.x;
  const int tile = (flat & 7) * 96 + (flat >> 3);    // XCD-chunked, bijective
  const bool isq = tile < 256;
  const int lt   = isq ? tile : tile - 256;
  const int gx   = isq ? 4 : 8;
  const int row0 = (lt / gx) * 128, col0 = (lt % gx) * 128;
  const u16* A  = isq ? xb : cb;
  const u16* Bt = isq ? Wqt : Wkvt;

  const int tid = threadIdx.x;
  const int w = tid >> 6, lane = tid & 63;
  const int c = lane & 15, g = lane >> 4;
  const int wr = (w >> 1) * 64, wc = (w & 1) * 64;

  f32x4 acc[4][4] = {};

  const int srow = tid >> 1, sj = (tid & 1) * 2;
  const int swz0 = ((sj  ) ^ ((srow >> 1) & 3)) << 4;
  const int swz1 = ((sj+1) ^ ((srow >> 1) & 3)) << 4;

  const u16* asrc = A  + (size_t)(row0 + srow) * DIMX + sj*8;
  const u16* bsrc = Bt + (size_t)(col0 + srow) * DIMX + sj*8;

  uint4 aA0, aA1, bA0, bA1;      // slot A
  uint4 aB0, aB1, bB0, bB1;      // slot B

  // prologue: tiles 0 (slot A) and 1 (slot B) both in flight
  aA0 = ((const uint4*)asrc)[0];        aA1 = ((const uint4*)asrc)[1];
  bA0 = ((const uint4*)bsrc)[0];        bA1 = ((const uint4*)bsrc)[1];
  aB0 = ((const uint4*)(asrc + 32))[0]; aB1 = ((const uint4*)(asrc + 32))[1];
  bB0 = ((const uint4*)(bsrc + 32))[0]; bB1 = ((const uint4*)(bsrc + 32))[1];
  *(uint4*)((char*)At[0] + srow*64 + swz0) = aA0;
  *(uint4*)((char*)At[0] + srow*64 + swz1) = aA1;
  *(uint4*)((char*)Bl[0] + srow*64 + swz0) = bA0;
  *(uint4*)((char*)Bl[0] + srow*64 + swz1) = bA1;

  for (int kk = 0; kk < 16; kk += 2){
    // ---- even: compute buf0 (tile kk); issue kk+2 -> slot A; write slot B -> buf1
    __syncthreads();
    if (kk + 2 < 16){
      const u16* an = asrc + (kk+2)*32;
      const u16* bn = bsrc + (kk+2)*32;
      aA0 = ((const uint4*)an)[0]; aA1 = ((const uint4*)an)[1];
      bA0 = ((const uint4*)bn)[0]; bA1 = ((const uint4*)bn)[1];
    }
    PROJ_COMPUTE(0);
    *(uint4*)((char*)At[1] + srow*64 + swz0) = aB0;   // tile kk+1 (always valid)
    *(uint4*)((char*)At[1] + srow*64 + swz1) = aB1;
    *(uint4*)((char*)Bl[1] + srow*64 + swz0) = bB0;
    *(uint4*)((char*)Bl[1] + srow*64 + swz1) = bB1;

    // ---- odd: compute buf1 (tile kk+1); issue kk+3 -> slot B; write slot A -> buf0
    __syncthreads();
    if (kk + 3 < 16){
      const u16* an = asrc + (kk+3)*32;
      const u16* bn = bsrc + (kk+3)*32;
      aB0 = ((const uint4*)an)[0]; aB1 = ((const uint4*)an)[1];
      bB0 = ((const uint4*)bn)[0]; bB1 = ((const uint4*)bn)[1];
    }
    PROJ_COMPUTE(1);
    if (kk + 2 < 16){
      *(uint4*)((char*)At[0] + srow*64 + swz0) = aA0; // tile kk+2
      *(uint4*)((char*)At[0] + srow*64 + swz1) = aA1;
      *(uint4*)((char*)Bl[0] + srow*64 + swz0) = bA0;
      *(uint4*)((char*)Bl[0] + srow*64 + swz1) = bA1;
    }
  }

  #pragma unroll
  for (int m = 0; m < 4; ++m){
    #pragma unroll
    for (int n = 0; n < 4; ++n){
      #pragma unroll
      for (int rr = 0; rr < 4; ++rr){
        const int R = row0 + wr + m*16 + g*4 + rr;
        const int col = col0 + wc + n*16 + c;
        const float v = acc[m][n][rr];
        if (isq){
          qb[(size_t)R * INNER + col] = bfc(tanhf(v) * QSCALE);
        } else {
          const int bidx = R >> 11, mm = R & 2047;
          if (col < INNER){
            const int h = col >> 6, d = col & 63;
            kb[((size_t)(bidx*H_ + h) * MKP + (mm + 1)) * DH + d] = bfc(tanhf(v));
          } else {
            const int cc = col - INNER;
            const int h = cc >> 6, d = cc & 63;
            vb[((size_t)(bidx*H_ + h) * MKP + (mm + 1)) * DH + d] = bfc(v);
          }
        }
      }
    }
  }
}

// ---------------------------------------------------------------------------
// Out-projection GEMM: out = ao @ Wout^T + bias. Same depth-2 pipeline.
// ---------------------------------------------------------------------------
__global__ __launch_bounds__(256, 3) void mgemm_out(
    const u16* __restrict__ A, const u16* __restrict__ Bt,
    float* __restrict__ Cf, const float* __restrict__ bias)
{
  __shared__ __align__(16) short At[2][128*32];
  __shared__ __align__(16) short Bl[2][128*32];

  const int flat = blockIdx.x;                       // 256 blocks
  const int tile = (flat & 7) * 32 + (flat >> 3);    // XCD-chunked
  const int row0 = (tile >> 2) * 128, col0 = (tile & 3) * 128;

  const int tid = threadIdx.x;
  const int w = tid >> 6, lane = tid & 63;
  const int c = lane & 15, g = lane >> 4;
  const int wr = (w >> 1) * 64, wc = (w & 1) * 64;

  f32x4 acc[4][4] = {};

  const int srow = tid >> 1, sj = (tid & 1) * 2;
  const int swz0 = ((sj  ) ^ ((srow >> 1) & 3)) << 4;
  const int swz1 = ((sj+1) ^ ((srow >> 1) & 3)) << 4;

  const u16* asrc = A  + (size_t)(row0 + srow) * INNER + sj*8;
  const u16* bsrc = Bt + (size_t)(col0 + srow) * INNER + sj*8;

  uint4 aA0, aA1, bA0, bA1;
  uint4 aB0, aB1, bB0, bB1;

  aA0 = ((const uint4*)asrc)[0];        aA1 = ((const uint4*)asrc)[1];
  bA0 = ((const uint4*)bsrc)[0];        bA1 = ((const uint4*)bsrc)[1];
  aB0 = ((const uint4*)(asrc + 32))[0]; aB1 = ((const uint4*)(asrc + 32))[1];
  bB0 = ((const uint4*)(bsrc + 32))[0]; bB1 = ((const uint4*)(bsrc + 32))[1];
  *(uint4*)((char*)At[0] + srow*64 + swz0) = aA0;
  *(uint4*)((char*)At[0] + srow*64 + swz1) = aA1;
  *(uint4*)((char*)Bl[0] + srow*64 + swz0) = bA0;
  *(uint4*)((char*)Bl[0] + srow*64 + swz1) = bA1;

  for (int kk = 0; kk < 16; kk += 2){
    __syncthreads();
    if (kk + 2 < 16){
      const u16* an = asrc + (kk+2)*32;
      const u16* bn = bsrc + (kk+2)*32;
      aA0 = ((const uint4*)an)[0]; aA1 = ((const uint4*)an)[1];
      bA0 = ((const uint4*)bn)[0]; bA1 = ((const uint4*)bn)[1];
    }
    PROJ_COMPUTE(0);
    *(uint4*)((char*)At[1] + srow*64 + swz0) = aB0;
    *(uint4*)((char*)At[1] + srow*64 + swz1) = aB1;
    *(uint4*)((char*)Bl[1] + srow*64 + swz0) = bB0;
    *(uint4*)((char*)Bl[1] + srow*64 + swz1) = bB1;

    __syncthreads();
    if (kk + 3 < 16){
      const u16* an = asrc + (kk+3)*32;
      const u16* bn = bsrc + (kk+3)*32;
      aB0 = ((const uint4*)an)[0]; aB1 = ((const uint4*)an)[1];
      bB0 = ((const uint4*)bn)[0]; bB1 = ((const uint4*)bn)[1];
    }
    PROJ_COMPUTE(1);
    if (kk + 2 < 16){
      *(uint4*)((char*)At[0] + srow*64 + swz0) = aA0;
      *(uint4*)((char*)At[0] + srow*64 + swz1) = aA1;
      *(uint4*)((char*)Bl[0] + srow*64 + swz0) = bA0;
      *(uint4*)((char*)Bl[0] + srow*64 + swz1) = bA1;
    }
  }

  #pragma unroll
  for (int m = 0; m < 4; ++m){
    #pragma unroll
    for (int n = 0; n < 4; ++n){
      #pragma unroll
      for (int rr = 0; rr < 4; ++rr){
        const int R = row0 + wr + m*16 + g*4 + rr;
        const int col = col0 + wc + n*16 + c;
        Cf[(size_t)R * 512 + col] = acc[m][n][rr] + bias[col];
      }
    }
  }
}

// ---------------------------------------------------------------------------
// v [bh][m][d] bf16 -> vt [bh][d][m] bf16, 64x64 tiles per bh.
// Fused null-token fill (mt==0 blocks).
// ---------------------------------------------------------------------------
__global__ __launch_bounds__(256) void vtrans(
    const u16* __restrict__ vb, u16* __restrict__ vt,
    const float* __restrict__ nk, const float* __restrict__ nv,
    u16* __restrict__ kb)
{
  __shared__ short tl[64][72];
  const int t = threadIdx.x;
  const int mt = blockIdx.x, bh = blockIdx.y;
  {
    const int mr = t >> 2, chb = (t & 3) * 2;
    const u16* src = vb + ((size_t)bh * MKP + mt*64 + mr) * DH + chb*8;
    uint4 a = ((const uint4*)src)[0];
    uint4 b = ((const uint4*)src)[1];
    *(uint4*)((char*)tl + mr*144 + chb*16)     = a;
    *(uint4*)((char*)tl + mr*144 + (chb+1)*16) = b;
  }
  __syncthreads();
  {
    const int d = t >> 2, chb = (t & 3) * 2;
    #pragma unroll
    for (int j = 0; j < 2; ++j){
      const int mbase = (chb + j) * 8;
      u16 s[8];
      #pragma unroll
      for (int e = 0; e < 8; ++e) s[e] = (u16)tl[mbase + e][d];
      if (mt == 0 && mbase == 0) s[0] = bfc(nv[d]);   // null v at key 0
      uint4 o;
      o.x = (u32)s[0] | ((u32)s[1] << 16);
      o.y = (u32)s[2] | ((u32)s[3] << 16);
      o.z = (u32)s[4] | ((u32)s[5] << 16);
      o.w = (u32)s[6] | ((u32)s[7] << 16);
      *(uint4*)(vt + ((size_t)bh * DH + d) * MKP + mt*64 + mbase) = o;
    }
    if (mt == 0 && (t & 3) == 0)                      // null k at key 0
      kb[(size_t)bh * MKP * DH + d] = bfc(tanhf(nk[d]));
  }
}

// ---------------------------------------------------------------------------
// MFMA flash attention. 4 waves x 16 query rows, KVBLK=64. Swapped QK^T,
// static softmax max folded into MFMA C-init, p = exp2(sv) directly.
// bh-chunked XCD swizzle: XCD x owns bh in [4x, 4x+4) -> per-XCD K/V working
// set 2.2MB fits the 4MB L2 (K/V fetched once per XCD, not 32x).
// ---------------------------------------------------------------------------
__global__ __launch_bounds__(256) void attn_mfma(
    const u16* __restrict__ qb, const u16* __restrict__ kb,
    const u16* __restrict__ vt, u16* __restrict__ aob)
{
  __shared__ __align__(16) short Kl[2][64*64];
  __shared__ __align__(16) short Vl[2][64*64];
  __shared__ __align__(16) short Pl[4][16*64];

  const int tid  = threadIdx.x;
  const int w    = tid >> 6;
  const int lane = tid & 63;
  const int c    = lane & 15;
  const int g    = lane >> 4;
  const int L    = blockIdx.x;                 // 1024 blocks, bh-chunked
  const int cc   = L >> 3;
  const int bh   = (L & 7) * 4 + (cc >> 5);
  const int b    = bh >> 3, h = bh & 7;
  const int qbase = (cc & 31) * 64 + w * 16;
  const int xr   = (c & 7) << 4;

  short8 qf0, qf1;
  {
    const u16* qrow = qb + ((size_t)(b*N_) + qbase + c) * INNER + h * DH;
    qf0 = *(const short8*)(qrow + g*8);
    qf1 = *(const short8*)(qrow + 32 + g*8);
  }

  f32x4 o[4] = {};
  float l_c = 0.f;

  const u16* kbase = kb + (size_t)bh * MKP * DH;
  const u16* vbase = vt + (size_t)bh * DH * MKP;
  const int srow = tid >> 2, sch = (tid & 3) * 2;
  const int swz0 = ((sch  ) ^ (srow & 7)) << 4;
  const int swz1 = ((sch+1) ^ (srow & 7)) << 4;

  uint4 rk0, rk1, rv0, rv1;
  {
    const u16* ksrc = kbase + (size_t)srow * DH + sch*8;
    rk0 = ((const uint4*)ksrc)[0]; rk1 = ((const uint4*)ksrc)[1];
    const u16* vsrc = vbase + (size_t)srow * MKP + sch*8;
    rv0 = ((const uint4*)vsrc)[0]; rv1 = ((const uint4*)vsrc)[1];
  }
  *(uint4*)((char*)Kl[0] + srow*128 + swz0) = rk0;
  *(uint4*)((char*)Kl[0] + srow*128 + swz1) = rk1;
  *(uint4*)((char*)Vl[0] + srow*128 + swz0) = rv0;
  *(uint4*)((char*)Vl[0] + srow*128 + swz1) = rv1;

  int cur = 0;
  for (int kt = 0; kt < 33; ++kt){
    __syncthreads();
    if (kt < 32){
      const u16* ksrc = kbase + (size_t)((kt+1)*64 + srow) * DH + sch*8;
      rk0 = ((const uint4*)ksrc)[0]; rk1 = ((const uint4*)ksrc)[1];
      const u16* vsrc = vbase + (size_t)srow * MKP + (kt+1)*64 + sch*8;
      rv0 = ((const uint4*)vsrc)[0]; rv1 = ((const uint4*)vsrc)[1];
    }

    const char* Kc = (const char*)Kl[cur];
    const char* Vc = (const char*)Vl[cur];
    char*       Pw = (char*)Pl + w*2048;

    f32x4 sv[4];
    __builtin_amdgcn_s_setprio(1);
    #pragma unroll
    for (int s = 0; s < 4; ++s){
      f32x4 a = {SM_BIAS, SM_BIAS, SM_BIAS, SM_BIAS};
      #pragma unroll
      for (int hh = 0; hh < 2; ++hh){
        short8 kf = *(const short8*)(Kc + (s*16 + c)*128 + ((hh*64 + g*16) ^ xr));
        a = __builtin_amdgcn_mfma_f32_16x16x32_bf16(kf, hh ? qf1 : qf0, a, 0, 0, 0);
      }
      sv[s] = a;
    }
    __builtin_amdgcn_s_setprio(0);

    if (kt == 32){
      #pragma unroll
      for (int s = 0; s < 4; ++s)
        #pragma unroll
        for (int r = 0; r < 4; ++r)
          if (s | r) sv[s][r] = -1e30f;
      if (g) sv[0][0] = -1e30f;
    }

    float psum = 0.f;
    #pragma unroll
    for (int s = 0; s < 4; ++s){
      const float p0 = EXP2(sv[s][0]);
      const float p1 = EXP2(sv[s][1]);
      const float p2 = EXP2(sv[s][2]);
      const float p3 = EXP2(sv[s][3]);
      psum += (p0 + p1) + (p2 + p3);
      uint2 pk;
      pk.x = bfpk(p0, p1);
      pk.y = bfpk(p2, p3);
      *(uint2*)(Pw + c*128 + ((((2*s + (g>>1)) ^ (c&7)) << 4) | ((g&1)*8))) = pk;
    }
    psum += __shfl_xor(psum, 16);
    psum += __shfl_xor(psum, 32);
    l_c += psum;

    __builtin_amdgcn_s_setprio(1);
    #pragma unroll
    for (int hh = 0; hh < 2; ++hh){
      short8 pf = *(const short8*)(Pw + c*128 + (((hh*4 + g) ^ (c&7)) << 4));
      #pragma unroll
      for (int D = 0; D < 4; ++D){
        short8 vf = *(const short8*)(Vc + (D*16 + c)*128 + ((hh*64 + g*16) ^ xr));
        o[D] = __builtin_amdgcn_mfma_f32_16x16x32_bf16(pf, vf, o[D], 0, 0, 0);
      }
    }
    __builtin_amdgcn_s_setprio(0);

    if (kt < 32){
      char* Kn = (char*)Kl[cur ^ 1];
      char* Vn = (char*)Vl[cur ^ 1];
      *(uint4*)(Kn + srow*128 + swz0) = rk0;
      *(uint4*)(Kn + srow*128 + swz1) = rk1;
      *(uint4*)(Vn + srow*128 + swz0) = rv0;
      *(uint4*)(Vn + srow*128 + swz1) = rv1;
      cur ^= 1;
    }
  }

  const float inv = 1.f / l_c;
  #pragma unroll
  for (int r = 0; r < 4; ++r){
    const float ir = __shfl(inv, g*4 + r, 16);
    const size_t nrow = (size_t)(b*N_) + qbase + g*4 + r;
    #pragma unroll
    for (int D = 0; D < 4; ++D)
      aob[nrow * INNER + h*DH + D*16 + c] = bfc(o[D][r] * ir);
  }
}

extern "C" void kernel_launch(void* const* d_in, const int* in_sizes, int n_in,
                              void* d_out, int out_size, void* d_ws, size_t ws_size,
                              hipStream_t stream)
{
  const float* x    = (const float*)d_in[0];
  const float* ctx  = (const float*)d_in[1];
  const float* Wq   = (const float*)d_in[2];
  const float* Wkv  = (const float*)d_in[3];
  const float* nk   = (const float*)d_in[4];
  const float* nv   = (const float*)d_in[5];
  const float* Wout = (const float*)d_in[6];
  const float* bout = (const float*)d_in[7];
  float* out = (float*)d_out;

  char* ws = (char*)d_ws;
  u16* xb    = (u16*)(ws);                       //  8,388,608
  u16* cb    = (u16*)(ws +  8388608);            //  8,388,608
  u16* qb    = (u16*)(ws + 16777216);            //  8,388,608
  u16* kbB   = (u16*)(ws + 25165824);            //  8,650,752
  u16* vbB   = (u16*)(ws + 33816576);            //  8,650,752
  u16* vtb   = (u16*)(ws + 42467328);            //  8,650,752
  u16* Wqt   = (u16*)(ws + 51118080);            //    524,288
  u16* Wkvt  = (u16*)(ws + 51642368);            //  1,048,576
  u16* Woutt = (u16*)(ws + 52690944);            //    524,288  (end ~53.2MB)
  u16* aoB   = vbB;                              // alias: vbB dead after vtrans

  // x/ctx -> bf16 (one pass), weight transposes (one dispatch)
  convert_bf<<<dim3(2048, 1, 2), 256, 0, stream>>>(x, ctx, xb, cb);
  transpose_all<<<dim3(16, 8, 3), 256, 0, stream>>>(Wq, Wkv, Wout, Wqt, Wkvt, Woutt);

  // fused q + kv projections (depth-2 prefetch + dbuf + XCD swizzle)
  fused_proj<<<768, 256, 0, stream>>>(xb, cb, Wqt, Wkvt, qb, kbB, vbB);
  // v -> v^T [bh][d][m], fused null k/v fill
  vtrans<<<dim3(33, 32), 256, 0, stream>>>(vbB, vtb, nk, nv, kbB);
  // MFMA flash attention -> ao bf16 (aliases vbB), bh-chunked XCD swizzle
  attn_mfma<<<1024, 256, 0, stream>>>(qb, kbB, vtb, aoB);
  // out = ao @ Wout + bout (depth-2 prefetch, fp32 out)
  mgemm_out<<<256, 256, 0, stream>>>(aoB, Woutt, out, bout);
}

// Round 10
// 118.480 us; speedup vs baseline: 11.7988x; 1.0007x over previous
//
#include <hip/hip_runtime.h>
#include <hip/hip_bf16.h>
#include <stdint.h>

#define B_    4
#define N_    2048
#define M_    2048
#define DIMX  512
#define INNER 512
#define H_    8
#define DH    64
#define MK    2049   // M+1 keys (null token at slot 0)
#define MKP   2112   // padded to 33 tiles of 64 (tail masked in-kernel)

#define QSCALE  0.18033688011f   // 0.125 * log2(e): softmax in exp2 domain
#define SM_BIAS -11.5415605f     // static softmax max: |S_log2| <= 64*QSCALE

using u16 = unsigned short;
using u32 = unsigned int;

typedef __attribute__((ext_vector_type(8))) short short8;
typedef __attribute__((ext_vector_type(4))) float f32x4;

#if defined(__has_builtin)
# if __has_builtin(__builtin_amdgcn_exp2f)
#  define EXP2(x) __builtin_amdgcn_exp2f(x)
# endif
#endif
#ifndef EXP2
# define EXP2(x) exp2f(x)
#endif

__device__ __forceinline__ u16 bfc(float f){
  __hip_bfloat16 h = __float2bfloat16(f);
  return *reinterpret_cast<u16*>(&h);
}
__device__ __forceinline__ u32 bfpk(float lo, float hi){
  return (u32)bfc(lo) | ((u32)bfc(hi) << 16);
}

// ---------------------------------------------------------------------------
// fp32 -> bf16 streaming convert for x (z=0) and ctx (z=1). 8 elems/thread.
// ---------------------------------------------------------------------------
__global__ __launch_bounds__(256) void convert_bf(
    const float* __restrict__ x, const float* __restrict__ ctx,
    u16* __restrict__ xb, u16* __restrict__ cb)
{
  const float* in = blockIdx.z ? ctx : x;
  u16* out        = blockIdx.z ? cb : xb;
  const int i = blockIdx.x * 256 + threadIdx.x;   // 524288 threads = 4M elems
  float4 a = ((const float4*)in)[i*2];
  float4 b = ((const float4*)in)[i*2+1];
  uint4 t;
  t.x = bfpk(a.x, a.y); t.y = bfpk(a.z, a.w);
  t.z = bfpk(b.x, b.y); t.w = bfpk(b.z, b.w);
  ((uint4*)out)[i] = t;
}

// ---------------------------------------------------------------------------
// All three weight transposes in one dispatch: fp32 [R][C] -> bf16 [C][R].
// ---------------------------------------------------------------------------
__global__ __launch_bounds__(256) void transpose_all(
    const float* __restrict__ Wq, const float* __restrict__ Wkv,
    const float* __restrict__ Wout,
    u16* __restrict__ Wqt, u16* __restrict__ Wkvt, u16* __restrict__ Woutt)
{
  const int z = blockIdx.z;
  const float* in = (z == 0) ? Wq : (z == 1) ? Wkv : Wout;
  u16* out        = (z == 0) ? Wqt : (z == 1) ? Wkvt : Woutt;
  const int C     = (z == 1) ? 1024 : 512;   // R = 512 for all
  const int R     = 512;
  if (blockIdx.x * 64 >= C) return;

  __shared__ float tl[64][65];
  const int t = threadIdx.x;
  const int c0 = blockIdx.x * 64, r0 = blockIdx.y * 64;
  const int col = t & 63, rb = t >> 6;
  #pragma unroll
  for (int j = 0; j < 16; ++j){
    const int row = rb + j*4;
    tl[row][col] = in[(size_t)(r0 + row) * C + c0 + col];
  }
  __syncthreads();
  #pragma unroll
  for (int j = 0; j < 16; ++j){
    const int orow = rb + j*4;
    out[(size_t)(c0 + orow) * R + r0 + col] = bfc(tl[col][orow]);
  }
}

// frag-read + 16 MFMA from LDS buffer `bi` (compile-time)
#define PROJ_COMPUTE(bi)                                                      \
  {                                                                           \
    short8 af[4], bf[4];                                                      \
    _Pragma("unroll")                                                         \
    for (int m = 0; m < 4; ++m){                                              \
      const int row = wr + m*16 + c;                                          \
      af[m] = *(const short8*)((char*)At[bi] + row*64 + ((g ^ ((row>>1)&3)) << 4)); \
    }                                                                         \
    _Pragma("unroll")                                                         \
    for (int n = 0; n < 4; ++n){                                              \
      const int row = wc + n*16 + c;                                          \
      bf[n] = *(const short8*)((char*)Bl[bi] + row*64 + ((g ^ ((row>>1)&3)) << 4)); \
    }                                                                         \
    __builtin_amdgcn_s_setprio(1);                                            \
    _Pragma("unroll")                                                         \
    for (int m = 0; m < 4; ++m)                                               \
      _Pragma("unroll")                                                       \
      for (int n = 0; n < 4; ++n)                                             \
        acc[m][n] = __builtin_amdgcn_mfma_f32_16x16x32_bf16(af[m], bf[n], acc[m][n], 0, 0, 0); \
    __builtin_amdgcn_s_setprio(0);                                            \
  }

// ---------------------------------------------------------------------------
// Fused q + kv projection GEMM, all-bf16 inputs. 768 blocks (XCD-chunked):
// tile<256 -> q (gx=4), else kv (gx=8). 128x128 tile, BK=32, 16 K-steps.
// Depth-2 register prefetch + double-buffered LDS.
// ---------------------------------------------------------------------------
__global__ __launch_bounds__(256, 3) void fused_proj(
    const u16* __restrict__ xb, const u16* __restrict__ cb,
    const u16* __restrict__ Wqt, const u16* __restrict__ Wkvt,
    u16* __restrict__ qb, u16* __restrict__ kb, u16* __restrict__ vb)
{
  __shared__ __align__(16) short At[2][128*32];
  __shared__ __align__(16) short Bl[2][128*32];

  const int flat = blockIdx.x;
  const int tile = (flat & 7) * 96 + (flat >> 3);    // XCD-chunked, bijective
  const bool isq = tile < 256;
  const int lt   = isq ? tile : tile - 256;
  const int gx   = isq ? 4 : 8;
  const int row0 = (lt / gx) * 128, col0 = (lt % gx) * 128;
  const u16* A  = isq ? xb : cb;
  const u16* Bt = isq ? Wqt : Wkvt;

  const int tid = threadIdx.x;
  const int w = tid >> 6, lane = tid & 63;
  const int c = lane & 15, g = lane >> 4;
  const int wr = (w >> 1) * 64, wc = (w & 1) * 64;

  f32x4 acc[4][4] = {};

  const int srow = tid >> 1, sj = (tid & 1) * 2;
  const int swz0 = ((sj  ) ^ ((srow >> 1) & 3)) << 4;
  const int swz1 = ((sj+1) ^ ((srow >> 1) & 3)) << 4;

  const u16* asrc = A  + (size_t)(row0 + srow) * DIMX + sj*8;
  const u16* bsrc = Bt + (size_t)(col0 + srow) * DIMX + sj*8;

  uint4 aA0, aA1, bA0, bA1;      // slot A
  uint4 aB0, aB1, bB0, bB1;      // slot B

  // prologue: tiles 0 (slot A) and 1 (slot B) both in flight
  aA0 = ((const uint4*)asrc)[0];        aA1 = ((const uint4*)asrc)[1];
  bA0 = ((const uint4*)bsrc)[0];        bA1 = ((const uint4*)bsrc)[1];
  aB0 = ((const uint4*)(asrc + 32))[0]; aB1 = ((const uint4*)(asrc + 32))[1];
  bB0 = ((const uint4*)(bsrc + 32))[0]; bB1 = ((const uint4*)(bsrc + 32))[1];
  *(uint4*)((char*)At[0] + srow*64 + swz0) = aA0;
  *(uint4*)((char*)At[0] + srow*64 + swz1) = aA1;
  *(uint4*)((char*)Bl[0] + srow*64 + swz0) = bA0;
  *(uint4*)((char*)Bl[0] + srow*64 + swz1) = bA1;

  for (int kk = 0; kk < 16; kk += 2){
    // ---- even: compute buf0 (tile kk); issue kk+2 -> slot A; write slot B -> buf1
    __syncthreads();
    if (kk + 2 < 16){
      const u16* an = asrc + (kk+2)*32;
      const u16* bn = bsrc + (kk+2)*32;
      aA0 = ((const uint4*)an)[0]; aA1 = ((const uint4*)an)[1];
      bA0 = ((const uint4*)bn)[0]; bA1 = ((const uint4*)bn)[1];
    }
    PROJ_COMPUTE(0);
    *(uint4*)((char*)At[1] + srow*64 + swz0) = aB0;   // tile kk+1 (always valid)
    *(uint4*)((char*)At[1] + srow*64 + swz1) = aB1;
    *(uint4*)((char*)Bl[1] + srow*64 + swz0) = bB0;
    *(uint4*)((char*)Bl[1] + srow*64 + swz1) = bB1;

    // ---- odd: compute buf1 (tile kk+1); issue kk+3 -> slot B; write slot A -> buf0
    __syncthreads();
    if (kk + 3 < 16){
      const u16* an = asrc + (kk+3)*32;
      const u16* bn = bsrc + (kk+3)*32;
      aB0 = ((const uint4*)an)[0]; aB1 = ((const uint4*)an)[1];
      bB0 = ((const uint4*)bn)[0]; bB1 = ((const uint4*)bn)[1];
    }
    PROJ_COMPUTE(1);
    if (kk + 2 < 16){
      *(uint4*)((char*)At[0] + srow*64 + swz0) = aA0; // tile kk+2
      *(uint4*)((char*)At[0] + srow*64 + swz1) = aA1;
      *(uint4*)((char*)Bl[0] + srow*64 + swz0) = bA0;
      *(uint4*)((char*)Bl[0] + srow*64 + swz1) = bA1;
    }
  }

  #pragma unroll
  for (int m = 0; m < 4; ++m){
    #pragma unroll
    for (int n = 0; n < 4; ++n){
      #pragma unroll
      for (int rr = 0; rr < 4; ++rr){
        const int R = row0 + wr + m*16 + g*4 + rr;
        const int col = col0 + wc + n*16 + c;
        const float v = acc[m][n][rr];
        if (isq){
          qb[(size_t)R * INNER + col] = bfc(tanhf(v) * QSCALE);
        } else {
          const int bidx = R >> 11, mm = R & 2047;
          if (col < INNER){
            const int h = col >> 6, d = col & 63;
            kb[((size_t)(bidx*H_ + h) * MKP + (mm + 1)) * DH + d] = bfc(tanhf(v));
          } else {
            const int cc = col - INNER;
            const int h = cc >> 6, d = cc & 63;
            vb[((size_t)(bidx*H_ + h) * MKP + (mm + 1)) * DH + d] = bfc(v);
          }
        }
      }
    }
  }
}

// ---------------------------------------------------------------------------
// Out-projection GEMM: out = ao @ Wout^T + bias. Same depth-2 pipeline.
// ---------------------------------------------------------------------------
__global__ __launch_bounds__(256, 3) void mgemm_out(
    const u16* __restrict__ A, const u16* __restrict__ Bt,
    float* __restrict__ Cf, const float* __restrict__ bias)
{
  __shared__ __align__(16) short At[2][128*32];
  __shared__ __align__(16) short Bl[2][128*32];

  const int flat = blockIdx.x;                       // 256 blocks
  const int tile = (flat & 7) * 32 + (flat >> 3);    // XCD-chunked
  const int row0 = (tile >> 2) * 128, col0 = (tile & 3) * 128;

  const int tid = threadIdx.x;
  const int w = tid >> 6, lane = tid & 63;
  const int c = lane & 15, g = lane >> 4;
  const int wr = (w >> 1) * 64, wc = (w & 1) * 64;

  f32x4 acc[4][4] = {};

  const int srow = tid >> 1, sj = (tid & 1) * 2;
  const int swz0 = ((sj  ) ^ ((srow >> 1) & 3)) << 4;
  const int swz1 = ((sj+1) ^ ((srow >> 1) & 3)) << 4;

  const u16* asrc = A  + (size_t)(row0 + srow) * INNER + sj*8;
  const u16* bsrc = Bt + (size_t)(col0 + srow) * INNER + sj*8;

  uint4 aA0, aA1, bA0, bA1;
  uint4 aB0, aB1, bB0, bB1;

  aA0 = ((const uint4*)asrc)[0];        aA1 = ((const uint4*)asrc)[1];
  bA0 = ((const uint4*)bsrc)[0];        bA1 = ((const uint4*)bsrc)[1];
  aB0 = ((const uint4*)(asrc + 32))[0]; aB1 = ((const uint4*)(asrc + 32))[1];
  bB0 = ((const uint4*)(bsrc + 32))[0]; bB1 = ((const uint4*)(bsrc + 32))[1];
  *(uint4*)((char*)At[0] + srow*64 + swz0) = aA0;
  *(uint4*)((char*)At[0] + srow*64 + swz1) = aA1;
  *(uint4*)((char*)Bl[0] + srow*64 + swz0) = bA0;
  *(uint4*)((char*)Bl[0] + srow*64 + swz1) = bA1;

  for (int kk = 0; kk < 16; kk += 2){
    __syncthreads();
    if (kk + 2 < 16){
      const u16* an = asrc + (kk+2)*32;
      const u16* bn = bsrc + (kk+2)*32;
      aA0 = ((const uint4*)an)[0]; aA1 = ((const uint4*)an)[1];
      bA0 = ((const uint4*)bn)[0]; bA1 = ((const uint4*)bn)[1];
    }
    PROJ_COMPUTE(0);
    *(uint4*)((char*)At[1] + srow*64 + swz0) = aB0;
    *(uint4*)((char*)At[1] + srow*64 + swz1) = aB1;
    *(uint4*)((char*)Bl[1] + srow*64 + swz0) = bB0;
    *(uint4*)((char*)Bl[1] + srow*64 + swz1) = bB1;

    __syncthreads();
    if (kk + 3 < 16){
      const u16* an = asrc + (kk+3)*32;
      const u16* bn = bsrc + (kk+3)*32;
      aB0 = ((const uint4*)an)[0]; aB1 = ((const uint4*)an)[1];
      bB0 = ((const uint4*)bn)[0]; bB1 = ((const uint4*)bn)[1];
    }
    PROJ_COMPUTE(1);
    if (kk + 2 < 16){
      *(uint4*)((char*)At[0] + srow*64 + swz0) = aA0;
      *(uint4*)((char*)At[0] + srow*64 + swz1) = aA1;
      *(uint4*)((char*)Bl[0] + srow*64 + swz0) = bA0;
      *(uint4*)((char*)Bl[0] + srow*64 + swz1) = bA1;
    }
  }

  #pragma unroll
  for (int m = 0; m < 4; ++m){
    #pragma unroll
    for (int n = 0; n < 4; ++n){
      #pragma unroll
      for (int rr = 0; rr < 4; ++rr){
        const int R = row0 + wr + m*16 + g*4 + rr;
        const int col = col0 + wc + n*16 + c;
        Cf[(size_t)R * 512 + col] = acc[m][n][rr] + bias[col];
      }
    }
  }
}

// ---------------------------------------------------------------------------
// v [bh][m][d] bf16 -> vt [bh][d][m] bf16, 64x64 tiles per bh.
// Fused null-token fill (mt==0 blocks).
// ---------------------------------------------------------------------------
__global__ __launch_bounds__(256) void vtrans(
    const u16* __restrict__ vb, u16* __restrict__ vt,
    const float* __restrict__ nk, const float* __restrict__ nv,
    u16* __restrict__ kb)
{
  __shared__ short tl[64][72];
  const int t = threadIdx.x;
  const int mt = blockIdx.x, bh = blockIdx.y;
  {
    const int mr = t >> 2, chb = (t & 3) * 2;
    const u16* src = vb + ((size_t)bh * MKP + mt*64 + mr) * DH + chb*8;
    uint4 a = ((const uint4*)src)[0];
    uint4 b = ((const uint4*)src)[1];
    *(uint4*)((char*)tl + mr*144 + chb*16)     = a;
    *(uint4*)((char*)tl + mr*144 + (chb+1)*16) = b;
  }
  __syncthreads();
  {
    const int d = t >> 2, chb = (t & 3) * 2;
    #pragma unroll
    for (int j = 0; j < 2; ++j){
      const int mbase = (chb + j) * 8;
      u16 s[8];
      #pragma unroll
      for (int e = 0; e < 8; ++e) s[e] = (u16)tl[mbase + e][d];
      if (mt == 0 && mbase == 0) s[0] = bfc(nv[d]);   // null v at key 0
      uint4 o;
      o.x = (u32)s[0] | ((u32)s[1] << 16);
      o.y = (u32)s[2] | ((u32)s[3] << 16);
      o.z = (u32)s[4] | ((u32)s[5] << 16);
      o.w = (u32)s[6] | ((u32)s[7] << 16);
      *(uint4*)(vt + ((size_t)bh * DH + d) * MKP + mt*64 + mbase) = o;
    }
    if (mt == 0 && (t & 3) == 0)                      // null k at key 0
      kb[(size_t)bh * MKP * DH + d] = bfc(tanhf(nk[d]));
  }
}

// ---------------------------------------------------------------------------
// MFMA flash attention. 4 waves x 16 query rows, KVBLK=64. Swapped QK^T,
// static softmax max folded into MFMA C-init, p = exp2(sv) directly.
// Natural grid mapping (blockIdx.y = bh) — bh-chunked XCD swizzle REVERTED:
// r9 showed it cuts FETCH 72->12.6MB but costs 2.6x time (lockstep same-line
// L2 contention; the over-fetch was L3-served and already latency-hidden).
// ---------------------------------------------------------------------------
__global__ __launch_bounds__(256) void attn_mfma(
    const u16* __restrict__ qb, const u16* __restrict__ kb,
    const u16* __restrict__ vt, u16* __restrict__ aob)
{
  __shared__ __align__(16) short Kl[2][64*64];
  __shared__ __align__(16) short Vl[2][64*64];
  __shared__ __align__(16) short Pl[4][16*64];

  const int tid  = threadIdx.x;
  const int w    = tid >> 6;
  const int lane = tid & 63;
  const int c    = lane & 15;
  const int g    = lane >> 4;
  const int bh   = blockIdx.y, b = bh >> 3, h = bh & 7;
  const int qbase = blockIdx.x * 64 + w * 16;
  const int xr   = (c & 7) << 4;

  short8 qf0, qf1;
  {
    const u16* qrow = qb + ((size_t)(b*N_) + qbase + c) * INNER + h * DH;
    qf0 = *(const short8*)(qrow + g*8);
    qf1 = *(const short8*)(qrow + 32 + g*8);
  }

  f32x4 o[4] = {};
  float l_c = 0.f;

  const u16* kbase = kb + (size_t)bh * MKP * DH;
  const u16* vbase = vt + (size_t)bh * DH * MKP;
  const int srow = tid >> 2, sch = (tid & 3) * 2;
  const int swz0 = ((sch  ) ^ (srow & 7)) << 4;
  const int swz1 = ((sch+1) ^ (srow & 7)) << 4;

  uint4 rk0, rk1, rv0, rv1;
  {
    const u16* ksrc = kbase + (size_t)srow * DH + sch*8;
    rk0 = ((const uint4*)ksrc)[0]; rk1 = ((const uint4*)ksrc)[1];
    const u16* vsrc = vbase + (size_t)srow * MKP + sch*8;
    rv0 = ((const uint4*)vsrc)[0]; rv1 = ((const uint4*)vsrc)[1];
  }
  *(uint4*)((char*)Kl[0] + srow*128 + swz0) = rk0;
  *(uint4*)((char*)Kl[0] + srow*128 + swz1) = rk1;
  *(uint4*)((char*)Vl[0] + srow*128 + swz0) = rv0;
  *(uint4*)((char*)Vl[0] + srow*128 + swz1) = rv1;

  int cur = 0;
  for (int kt = 0; kt < 33; ++kt){
    __syncthreads();
    if (kt < 32){
      const u16* ksrc = kbase + (size_t)((kt+1)*64 + srow) * DH + sch*8;
      rk0 = ((const uint4*)ksrc)[0]; rk1 = ((const uint4*)ksrc)[1];
      const u16* vsrc = vbase + (size_t)srow * MKP + (kt+1)*64 + sch*8;
      rv0 = ((const uint4*)vsrc)[0]; rv1 = ((const uint4*)vsrc)[1];
    }

    const char* Kc = (const char*)Kl[cur];
    const char* Vc = (const char*)Vl[cur];
    char*       Pw = (char*)Pl + w*2048;

    f32x4 sv[4];
    __builtin_amdgcn_s_setprio(1);
    #pragma unroll
    for (int s = 0; s < 4; ++s){
      f32x4 a = {SM_BIAS, SM_BIAS, SM_BIAS, SM_BIAS};
      #pragma unroll
      for (int hh = 0; hh < 2; ++hh){
        short8 kf = *(const short8*)(Kc + (s*16 + c)*128 + ((hh*64 + g*16) ^ xr));
        a = __builtin_amdgcn_mfma_f32_16x16x32_bf16(kf, hh ? qf1 : qf0, a, 0, 0, 0);
      }
      sv[s] = a;
    }
    __builtin_amdgcn_s_setprio(0);

    if (kt == 32){
      #pragma unroll
      for (int s = 0; s < 4; ++s)
        #pragma unroll
        for (int r = 0; r < 4; ++r)
          if (s | r) sv[s][r] = -1e30f;
      if (g) sv[0][0] = -1e30f;
    }

    float psum = 0.f;
    #pragma unroll
    for (int s = 0; s < 4; ++s){
      const float p0 = EXP2(sv[s][0]);
      const float p1 = EXP2(sv[s][1]);
      const float p2 = EXP2(sv[s][2]);
      const float p3 = EXP2(sv[s][3]);
      psum += (p0 + p1) + (p2 + p3);
      uint2 pk;
      pk.x = bfpk(p0, p1);
      pk.y = bfpk(p2, p3);
      *(uint2*)(Pw + c*128 + ((((2*s + (g>>1)) ^ (c&7)) << 4) | ((g&1)*8))) = pk;
    }
    psum += __shfl_xor(psum, 16);
    psum += __shfl_xor(psum, 32);
    l_c += psum;

    __builtin_amdgcn_s_setprio(1);
    #pragma unroll
    for (int hh = 0; hh < 2; ++hh){
      short8 pf = *(const short8*)(Pw + c*128 + (((hh*4 + g) ^ (c&7)) << 4));
      #pragma unroll
      for (int D = 0; D < 4; ++D){
        short8 vf = *(const short8*)(Vc + (D*16 + c)*128 + ((hh*64 + g*16) ^ xr));
        o[D] = __builtin_amdgcn_mfma_f32_16x16x32_bf16(pf, vf, o[D], 0, 0, 0);
      }
    }
    __builtin_amdgcn_s_setprio(0);

    if (kt < 32){
      char* Kn = (char*)Kl[cur ^ 1];
      char* Vn = (char*)Vl[cur ^ 1];
      *(uint4*)(Kn + srow*128 + swz0) = rk0;
      *(uint4*)(Kn + srow*128 + swz1) = rk1;
      *(uint4*)(Vn + srow*128 + swz0) = rv0;
      *(uint4*)(Vn + srow*128 + swz1) = rv1;
      cur ^= 1;
    }
  }

  const float inv = 1.f / l_c;
  #pragma unroll
  for (int r = 0; r < 4; ++r){
    const float ir = __shfl(inv, g*4 + r, 16);
    const size_t nrow = (size_t)(b*N_) + qbase + g*4 + r;
    #pragma unroll
    for (int D = 0; D < 4; ++D)
      aob[nrow * INNER + h*DH + D*16 + c] = bfc(o[D][r] * ir);
  }
}

extern "C" void kernel_launch(void* const* d_in, const int* in_sizes, int n_in,
                              void* d_out, int out_size, void* d_ws, size_t ws_size,
                              hipStream_t stream)
{
  const float* x    = (const float*)d_in[0];
  const float* ctx  = (const float*)d_in[1];
  const float* Wq   = (const float*)d_in[2];
  const float* Wkv  = (const float*)d_in[3];
  const float* nk   = (const float*)d_in[4];
  const float* nv   = (const float*)d_in[5];
  const float* Wout = (const float*)d_in[6];
  const float* bout = (const float*)d_in[7];
  float* out = (float*)d_out;

  char* ws = (char*)d_ws;
  u16* xb    = (u16*)(ws);                       //  8,388,608
  u16* cb    = (u16*)(ws +  8388608);            //  8,388,608
  u16* qb    = (u16*)(ws + 16777216);            //  8,388,608
  u16* kbB   = (u16*)(ws + 25165824);            //  8,650,752
  u16* vbB   = (u16*)(ws + 33816576);            //  8,650,752
  u16* vtb   = (u16*)(ws + 42467328);            //  8,650,752
  u16* Wqt   = (u16*)(ws + 51118080);            //    524,288
  u16* Wkvt  = (u16*)(ws + 51642368);            //  1,048,576
  u16* Woutt = (u16*)(ws + 52690944);            //    524,288  (end ~53.2MB)
  u16* aoB   = vbB;                              // alias: vbB dead after vtrans

  // x/ctx -> bf16 (one pass), weight transposes (one dispatch)
  convert_bf<<<dim3(2048, 1, 2), 256, 0, stream>>>(x, ctx, xb, cb);
  transpose_all<<<dim3(16, 8, 3), 256, 0, stream>>>(Wq, Wkv, Wout, Wqt, Wkvt, Woutt);

  // fused q + kv projections (depth-2 prefetch + dbuf + XCD swizzle)
  fused_proj<<<768, 256, 0, stream>>>(xb, cb, Wqt, Wkvt, qb, kbB, vbB);
  // v -> v^T [bh][d][m], fused null k/v fill
  vtrans<<<dim3(33, 32), 256, 0, stream>>>(vbB, vtb, nk, nv, kbB);
  // MFMA flash attention -> ao bf16 (aliases vbB), natural mapping (r8)
  attn_mfma<<<dim3(32, 32), 256, 0, stream>>>(qb, kbB, vtb, aoB);
  // out = ao @ Wout + bout (depth-2 prefetch, fp32 out)
  mgemm_out<<<256, 256, 0, stream>>>(aoB, Woutt, out, bout);
}

// Round 11
// 116.980 us; speedup vs baseline: 11.9501x; 1.0128x over previous
//
#include <hip/hip_runtime.h>
#include <hip/hip_bf16.h>
#include <stdint.h>

#define B_    4
#define N_    2048
#define M_    2048
#define DIMX  512
#define INNER 512
#define H_    8
#define DH    64
#define MK    2049   // M+1 keys (null token at slot 0)
#define MKP   2112   // padded to 33 tiles of 64 (tail masked in-kernel)

#define QSCALE  0.18033688011f   // 0.125 * log2(e): softmax in exp2 domain
#define SM_BIAS -11.5415605f     // static softmax max: |S_log2| <= 64*QSCALE

using u16 = unsigned short;
using u32 = unsigned int;

typedef __attribute__((ext_vector_type(8))) short short8;
typedef __attribute__((ext_vector_type(4))) float f32x4;

#if defined(__has_builtin)
# if __has_builtin(__builtin_amdgcn_exp2f)
#  define EXP2(x) __builtin_amdgcn_exp2f(x)
# endif
#endif
#ifndef EXP2
# define EXP2(x) exp2f(x)
#endif

__device__ __forceinline__ u16 bfc(float f){
  __hip_bfloat16 h = __float2bfloat16(f);
  return *reinterpret_cast<u16*>(&h);
}
__device__ __forceinline__ u32 bfpk(float lo, float hi){
  return (u32)bfc(lo) | ((u32)bfc(hi) << 16);
}

// ---------------------------------------------------------------------------
// All three weight transposes in one dispatch: fp32 [R][C] -> bf16 [C][R].
// ---------------------------------------------------------------------------
__global__ __launch_bounds__(256) void transpose_all(
    const float* __restrict__ Wq, const float* __restrict__ Wkv,
    const float* __restrict__ Wout,
    u16* __restrict__ Wqt, u16* __restrict__ Wkvt, u16* __restrict__ Woutt)
{
  const int z = blockIdx.z;
  const float* in = (z == 0) ? Wq : (z == 1) ? Wkv : Wout;
  u16* out        = (z == 0) ? Wqt : (z == 1) ? Wkvt : Woutt;
  const int C     = (z == 1) ? 1024 : 512;   // R = 512 for all
  const int R     = 512;
  if (blockIdx.x * 64 >= C) return;

  __shared__ float tl[64][65];
  const int t = threadIdx.x;
  const int c0 = blockIdx.x * 64, r0 = blockIdx.y * 64;
  const int col = t & 63, rb = t >> 6;
  #pragma unroll
  for (int j = 0; j < 16; ++j){
    const int row = rb + j*4;
    tl[row][col] = in[(size_t)(r0 + row) * C + c0 + col];
  }
  __syncthreads();
  #pragma unroll
  for (int j = 0; j < 16; ++j){
    const int orow = rb + j*4;
    out[(size_t)(c0 + orow) * R + r0 + col] = bfc(tl[col][orow]);
  }
}

// frag-read + 16 MFMA from LDS buffer `bi` (compile-time)
#define PROJ_COMPUTE(bi)                                                      \
  {                                                                           \
    short8 af[4], bf[4];                                                      \
    _Pragma("unroll")                                                         \
    for (int m = 0; m < 4; ++m){                                              \
      const int row = wr + m*16 + c;                                          \
      af[m] = *(const short8*)((char*)At[bi] + row*64 + ((g ^ ((row>>1)&3)) << 4)); \
    }                                                                         \
    _Pragma("unroll")                                                         \
    for (int n = 0; n < 4; ++n){                                              \
      const int row = wc + n*16 + c;                                          \
      bf[n] = *(const short8*)((char*)Bl[bi] + row*64 + ((g ^ ((row>>1)&3)) << 4)); \
    }                                                                         \
    __builtin_amdgcn_s_setprio(1);                                            \
    _Pragma("unroll")                                                         \
    for (int m = 0; m < 4; ++m)                                               \
      _Pragma("unroll")                                                       \
      for (int n = 0; n < 4; ++n)                                             \
        acc[m][n] = __builtin_amdgcn_mfma_f32_16x16x32_bf16(af[m], bf[n], acc[m][n], 0, 0, 0); \
    __builtin_amdgcn_s_setprio(0);                                            \
  }

#define PACK_A(t0, t1, q0, q1, q2, q3)                                        \
  t0.x = bfpk(q0.x, q0.y); t0.y = bfpk(q0.z, q0.w);                           \
  t0.z = bfpk(q1.x, q1.y); t0.w = bfpk(q1.z, q1.w);                           \
  t1.x = bfpk(q2.x, q2.y); t1.y = bfpk(q2.z, q2.w);                           \
  t1.z = bfpk(q3.x, q3.y); t1.w = bfpk(q3.z, q3.w);

// ---------------------------------------------------------------------------
// Fused q + kv projection GEMM. A = fp32 x/ctx read directly (converted to
// bf16 during LDS staging — the separate convert pass is deleted). 768 blocks
// (XCD-chunked): tile<256 -> q (gx=4), else kv (gx=8). 128x128 tile, BK=32.
// Depth-2 register prefetch + double-buffered LDS.
// ---------------------------------------------------------------------------
__global__ __launch_bounds__(256, 3) void fused_proj(
    const float* __restrict__ x, const float* __restrict__ ctx,
    const u16* __restrict__ Wqt, const u16* __restrict__ Wkvt,
    u16* __restrict__ qb, u16* __restrict__ kb, u16* __restrict__ vb)
{
  __shared__ __align__(16) short At[2][128*32];
  __shared__ __align__(16) short Bl[2][128*32];

  const int flat = blockIdx.x;
  const int tile = (flat & 7) * 96 + (flat >> 3);    // XCD-chunked, bijective
  const bool isq = tile < 256;
  const int lt   = isq ? tile : tile - 256;
  const int gx   = isq ? 4 : 8;
  const int row0 = (lt / gx) * 128, col0 = (lt % gx) * 128;
  const float* A = isq ? x : ctx;
  const u16*  Bt = isq ? Wqt : Wkvt;

  const int tid = threadIdx.x;
  const int w = tid >> 6, lane = tid & 63;
  const int c = lane & 15, g = lane >> 4;
  const int wr = (w >> 1) * 64, wc = (w & 1) * 64;

  f32x4 acc[4][4] = {};

  const int srow = tid >> 1, sj = (tid & 1) * 2;
  const int swz0 = ((sj  ) ^ ((srow >> 1) & 3)) << 4;
  const int swz1 = ((sj+1) ^ ((srow >> 1) & 3)) << 4;

  const float* asrc = A  + (size_t)(row0 + srow) * DIMX + sj*8;
  const u16*   bsrc = Bt + (size_t)(col0 + srow) * DIMX + sj*8;

  float4 aA0, aA1, aA2, aA3;  uint4 bA0, bA1;   // slot A
  float4 aB0, aB1, aB2, aB3;  uint4 bB0, bB1;   // slot B

  // prologue: tiles 0 (slot A) and 1 (slot B) both in flight
  aA0 = ((const float4*)asrc)[0]; aA1 = ((const float4*)asrc)[1];
  aA2 = ((const float4*)asrc)[2]; aA3 = ((const float4*)asrc)[3];
  bA0 = ((const uint4*)bsrc)[0];  bA1 = ((const uint4*)bsrc)[1];
  {
    const float* an = asrc + 32;
    aB0 = ((const float4*)an)[0]; aB1 = ((const float4*)an)[1];
    aB2 = ((const float4*)an)[2]; aB3 = ((const float4*)an)[3];
    bB0 = ((const uint4*)(bsrc + 32))[0]; bB1 = ((const uint4*)(bsrc + 32))[1];
  }
  {
    uint4 t0, t1;
    PACK_A(t0, t1, aA0, aA1, aA2, aA3);
    *(uint4*)((char*)At[0] + srow*64 + swz0) = t0;
    *(uint4*)((char*)At[0] + srow*64 + swz1) = t1;
    *(uint4*)((char*)Bl[0] + srow*64 + swz0) = bA0;
    *(uint4*)((char*)Bl[0] + srow*64 + swz1) = bA1;
  }

  for (int kk = 0; kk < 16; kk += 2){
    // ---- even: compute buf0 (tile kk); issue kk+2 -> slot A; write slot B -> buf1
    __syncthreads();
    if (kk + 2 < 16){
      const float* an = asrc + (kk+2)*32;
      const u16*   bn = bsrc + (kk+2)*32;
      aA0 = ((const float4*)an)[0]; aA1 = ((const float4*)an)[1];
      aA2 = ((const float4*)an)[2]; aA3 = ((const float4*)an)[3];
      bA0 = ((const uint4*)bn)[0];  bA1 = ((const uint4*)bn)[1];
    }
    PROJ_COMPUTE(0);
    {
      uint4 t0, t1;
      PACK_A(t0, t1, aB0, aB1, aB2, aB3);
      *(uint4*)((char*)At[1] + srow*64 + swz0) = t0;   // tile kk+1 (always valid)
      *(uint4*)((char*)At[1] + srow*64 + swz1) = t1;
      *(uint4*)((char*)Bl[1] + srow*64 + swz0) = bB0;
      *(uint4*)((char*)Bl[1] + srow*64 + swz1) = bB1;
    }

    // ---- odd: compute buf1 (tile kk+1); issue kk+3 -> slot B; write slot A -> buf0
    __syncthreads();
    if (kk + 3 < 16){
      const float* an = asrc + (kk+3)*32;
      const u16*   bn = bsrc + (kk+3)*32;
      aB0 = ((const float4*)an)[0]; aB1 = ((const float4*)an)[1];
      aB2 = ((const float4*)an)[2]; aB3 = ((const float4*)an)[3];
      bB0 = ((const uint4*)bn)[0];  bB1 = ((const uint4*)bn)[1];
    }
    PROJ_COMPUTE(1);
    if (kk + 2 < 16){
      uint4 t0, t1;
      PACK_A(t0, t1, aA0, aA1, aA2, aA3);
      *(uint4*)((char*)At[0] + srow*64 + swz0) = t0;   // tile kk+2
      *(uint4*)((char*)At[0] + srow*64 + swz1) = t1;
      *(uint4*)((char*)Bl[0] + srow*64 + swz0) = bA0;
      *(uint4*)((char*)Bl[0] + srow*64 + swz1) = bA1;
    }
  }

  #pragma unroll
  for (int m = 0; m < 4; ++m){
    #pragma unroll
    for (int n = 0; n < 4; ++n){
      #pragma unroll
      for (int rr = 0; rr < 4; ++rr){
        const int R = row0 + wr + m*16 + g*4 + rr;
        const int col = col0 + wc + n*16 + c;
        const float v = acc[m][n][rr];
        if (isq){
          qb[(size_t)R * INNER + col] = bfc(tanhf(v) * QSCALE);
        } else {
          const int bidx = R >> 11, mm = R & 2047;
          if (col < INNER){
            const int h = col >> 6, d = col & 63;
            kb[((size_t)(bidx*H_ + h) * MKP + (mm + 1)) * DH + d] = bfc(tanhf(v));
          } else {
            const int cc = col - INNER;
            const int h = cc >> 6, d = cc & 63;
            vb[((size_t)(bidx*H_ + h) * MKP + (mm + 1)) * DH + d] = bfc(v);
          }
        }
      }
    }
  }
}

// ---------------------------------------------------------------------------
// Out-projection GEMM: out = ao @ Wout^T + bias. Depth-2 pipeline (bf16 A).
// ---------------------------------------------------------------------------
__global__ __launch_bounds__(256, 3) void mgemm_out(
    const u16* __restrict__ A, const u16* __restrict__ Bt,
    float* __restrict__ Cf, const float* __restrict__ bias)
{
  __shared__ __align__(16) short At[2][128*32];
  __shared__ __align__(16) short Bl[2][128*32];

  const int flat = blockIdx.x;                       // 256 blocks
  const int tile = (flat & 7) * 32 + (flat >> 3);    // XCD-chunked
  const int row0 = (tile >> 2) * 128, col0 = (tile & 3) * 128;

  const int tid = threadIdx.x;
  const int w = tid >> 6, lane = tid & 63;
  const int c = lane & 15, g = lane >> 4;
  const int wr = (w >> 1) * 64, wc = (w & 1) * 64;

  f32x4 acc[4][4] = {};

  const int srow = tid >> 1, sj = (tid & 1) * 2;
  const int swz0 = ((sj  ) ^ ((srow >> 1) & 3)) << 4;
  const int swz1 = ((sj+1) ^ ((srow >> 1) & 3)) << 4;

  const u16* asrc = A  + (size_t)(row0 + srow) * INNER + sj*8;
  const u16* bsrc = Bt + (size_t)(col0 + srow) * INNER + sj*8;

  uint4 aA0, aA1, bA0, bA1;
  uint4 aB0, aB1, bB0, bB1;

  aA0 = ((const uint4*)asrc)[0];        aA1 = ((const uint4*)asrc)[1];
  bA0 = ((const uint4*)bsrc)[0];        bA1 = ((const uint4*)bsrc)[1];
  aB0 = ((const uint4*)(asrc + 32))[0]; aB1 = ((const uint4*)(asrc + 32))[1];
  bB0 = ((const uint4*)(bsrc + 32))[0]; bB1 = ((const uint4*)(bsrc + 32))[1];
  *(uint4*)((char*)At[0] + srow*64 + swz0) = aA0;
  *(uint4*)((char*)At[0] + srow*64 + swz1) = aA1;
  *(uint4*)((char*)Bl[0] + srow*64 + swz0) = bA0;
  *(uint4*)((char*)Bl[0] + srow*64 + swz1) = bA1;

  for (int kk = 0; kk < 16; kk += 2){
    __syncthreads();
    if (kk + 2 < 16){
      const u16* an = asrc + (kk+2)*32;
      const u16* bn = bsrc + (kk+2)*32;
      aA0 = ((const uint4*)an)[0]; aA1 = ((const uint4*)an)[1];
      bA0 = ((const uint4*)bn)[0]; bA1 = ((const uint4*)bn)[1];
    }
    PROJ_COMPUTE(0);
    *(uint4*)((char*)At[1] + srow*64 + swz0) = aB0;
    *(uint4*)((char*)At[1] + srow*64 + swz1) = aB1;
    *(uint4*)((char*)Bl[1] + srow*64 + swz0) = bB0;
    *(uint4*)((char*)Bl[1] + srow*64 + swz1) = bB1;

    __syncthreads();
    if (kk + 3 < 16){
      const u16* an = asrc + (kk+3)*32;
      const u16* bn = bsrc + (kk+3)*32;
      aB0 = ((const uint4*)an)[0]; aB1 = ((const uint4*)an)[1];
      bB0 = ((const uint4*)bn)[0]; bB1 = ((const uint4*)bn)[1];
    }
    PROJ_COMPUTE(1);
    if (kk + 2 < 16){
      *(uint4*)((char*)At[0] + srow*64 + swz0) = aA0;
      *(uint4*)((char*)At[0] + srow*64 + swz1) = aA1;
      *(uint4*)((char*)Bl[0] + srow*64 + swz0) = bA0;
      *(uint4*)((char*)Bl[0] + srow*64 + swz1) = bA1;
    }
  }

  #pragma unroll
  for (int m = 0; m < 4; ++m){
    #pragma unroll
    for (int n = 0; n < 4; ++n){
      #pragma unroll
      for (int rr = 0; rr < 4; ++rr){
        const int R = row0 + wr + m*16 + g*4 + rr;
        const int col = col0 + wc + n*16 + c;
        Cf[(size_t)R * 512 + col] = acc[m][n][rr] + bias[col];
      }
    }
  }
}

// ---------------------------------------------------------------------------
// v [bh][m][d] bf16 -> vt [bh][d][m] bf16, 64x64 tiles per bh.
// Fused null-token fill (mt==0 blocks).
// ---------------------------------------------------------------------------
__global__ __launch_bounds__(256) void vtrans(
    const u16* __restrict__ vb, u16* __restrict__ vt,
    const float* __restrict__ nk, const float* __restrict__ nv,
    u16* __restrict__ kb)
{
  __shared__ short tl[64][72];
  const int t = threadIdx.x;
  const int mt = blockIdx.x, bh = blockIdx.y;
  {
    const int mr = t >> 2, chb = (t & 3) * 2;
    const u16* src = vb + ((size_t)bh * MKP + mt*64 + mr) * DH + chb*8;
    uint4 a = ((const uint4*)src)[0];
    uint4 b = ((const uint4*)src)[1];
    *(uint4*)((char*)tl + mr*144 + chb*16)     = a;
    *(uint4*)((char*)tl + mr*144 + (chb+1)*16) = b;
  }
  __syncthreads();
  {
    const int d = t >> 2, chb = (t & 3) * 2;
    #pragma unroll
    for (int j = 0; j < 2; ++j){
      const int mbase = (chb + j) * 8;
      u16 s[8];
      #pragma unroll
      for (int e = 0; e < 8; ++e) s[e] = (u16)tl[mbase + e][d];
      if (mt == 0 && mbase == 0) s[0] = bfc(nv[d]);   // null v at key 0
      uint4 o;
      o.x = (u32)s[0] | ((u32)s[1] << 16);
      o.y = (u32)s[2] | ((u32)s[3] << 16);
      o.z = (u32)s[4] | ((u32)s[5] << 16);
      o.w = (u32)s[6] | ((u32)s[7] << 16);
      *(uint4*)(vt + ((size_t)bh * DH + d) * MKP + mt*64 + mbase) = o;
    }
    if (mt == 0 && (t & 3) == 0)                      // null k at key 0
      kb[(size_t)bh * MKP * DH + d] = bfc(tanhf(nk[d]));
  }
}

// ---------------------------------------------------------------------------
// MFMA flash attention, Q32-per-wave. 4 waves x 32 query rows (block = 128 q),
// KVBLK=64, grid (16,32)=512 blocks. Swapped QK^T: each K/V LDS fragment is
// read ONCE and feeds TWO MFMAs (query halves u=0/1) -> 1.7x less LDS traffic
// per MFMA (r10 analysis: kernel is LDS-BW-bound). Static softmax max in
// MFMA C-init; p = exp2(sv). K/V/P in 128B XOR-swizzled rows, dbuf K/V.
// ---------------------------------------------------------------------------
__global__ __launch_bounds__(256) void attn_mfma(
    const u16* __restrict__ qb, const u16* __restrict__ kb,
    const u16* __restrict__ vt, u16* __restrict__ aob)
{
  __shared__ __align__(16) short Kl[2][64*64];   // 16KB [key][dim] swizzled
  __shared__ __align__(16) short Vl[2][64*64];   // 16KB [dim][key] swizzled
  __shared__ __align__(16) short Pl[4][32*64];   // 16KB per-wave [32q][64k]

  const int tid  = threadIdx.x;
  const int w    = tid >> 6;
  const int lane = tid & 63;
  const int c    = lane & 15;
  const int g    = lane >> 4;
  const int bh   = blockIdx.y, b = bh >> 3, h = bh & 7;
  const int qbase = blockIdx.x * 128 + w * 32;
  const int xr   = (c & 7) << 4;

  short8 qf[2][2];
  #pragma unroll
  for (int u = 0; u < 2; ++u){
    const u16* qrow = qb + ((size_t)(b*N_) + qbase + u*16 + c) * INNER + h * DH;
    qf[u][0] = *(const short8*)(qrow + g*8);
    qf[u][1] = *(const short8*)(qrow + 32 + g*8);
  }

  f32x4 o[2][4] = {};              // [qhalf][dimblock]: row=q g*4+r, col=dim c
  float l0 = 0.f, l1 = 0.f;

  const u16* kbase = kb + (size_t)bh * MKP * DH;
  const u16* vbase = vt + (size_t)bh * DH * MKP;
  const int srow = tid >> 2, sch = (tid & 3) * 2;
  const int swz0 = ((sch  ) ^ (srow & 7)) << 4;
  const int swz1 = ((sch+1) ^ (srow & 7)) << 4;

  uint4 rk0, rk1, rv0, rv1;
  {
    const u16* ksrc = kbase + (size_t)srow * DH + sch*8;
    rk0 = ((const uint4*)ksrc)[0]; rk1 = ((const uint4*)ksrc)[1];
    const u16* vsrc = vbase + (size_t)srow * MKP + sch*8;
    rv0 = ((const uint4*)vsrc)[0]; rv1 = ((const uint4*)vsrc)[1];
  }
  *(uint4*)((char*)Kl[0] + srow*128 + swz0) = rk0;
  *(uint4*)((char*)Kl[0] + srow*128 + swz1) = rk1;
  *(uint4*)((char*)Vl[0] + srow*128 + swz0) = rv0;
  *(uint4*)((char*)Vl[0] + srow*128 + swz1) = rv1;

  int cur = 0;
  for (int kt = 0; kt < 33; ++kt){
    __syncthreads();
    if (kt < 32){
      const u16* ksrc = kbase + (size_t)((kt+1)*64 + srow) * DH + sch*8;
      rk0 = ((const uint4*)ksrc)[0]; rk1 = ((const uint4*)ksrc)[1];
      const u16* vsrc = vbase + (size_t)srow * MKP + (kt+1)*64 + sch*8;
      rv0 = ((const uint4*)vsrc)[0]; rv1 = ((const uint4*)vsrc)[1];
    }

    const char* Kc = (const char*)Kl[cur];
    const char* Vc = (const char*)Vl[cur];
    char*       Pw = (char*)Pl + w*4096;

    // ---- swapped QK^T: each kf pair feeds BOTH query halves ----
    f32x4 sv[2][4];
    __builtin_amdgcn_s_setprio(1);
    #pragma unroll
    for (int s = 0; s < 4; ++s){
      const int row = s*16 + c;
      short8 kf0 = *(const short8*)(Kc + row*128 + ((     g*16) ^ xr));
      short8 kf1 = *(const short8*)(Kc + row*128 + ((64 + g*16) ^ xr));
      f32x4 a0 = {SM_BIAS, SM_BIAS, SM_BIAS, SM_BIAS};
      f32x4 a1 = {SM_BIAS, SM_BIAS, SM_BIAS, SM_BIAS};
      a0 = __builtin_amdgcn_mfma_f32_16x16x32_bf16(kf0, qf[0][0], a0, 0, 0, 0);
      a1 = __builtin_amdgcn_mfma_f32_16x16x32_bf16(kf0, qf[1][0], a1, 0, 0, 0);
      a0 = __builtin_amdgcn_mfma_f32_16x16x32_bf16(kf1, qf[0][1], a0, 0, 0, 0);
      a1 = __builtin_amdgcn_mfma_f32_16x16x32_bf16(kf1, qf[1][1], a1, 0, 0, 0);
      sv[0][s] = a0; sv[1][s] = a1;
    }
    __builtin_amdgcn_s_setprio(0);

    if (kt == 32){                    // only key 2048 (tile-local 0) is valid
      #pragma unroll
      for (int u = 0; u < 2; ++u)
        #pragma unroll
        for (int s = 0; s < 4; ++s)
          #pragma unroll
          for (int r = 0; r < 4; ++r)
            if (s | r) sv[u][s][r] = -1e30f;
      if (g){ sv[0][0][0] = -1e30f; sv[1][0][0] = -1e30f; }
    }

    // ---- softmax numerators (static max): p = exp2(sv), P -> LDS bf16 ----
    #pragma unroll
    for (int u = 0; u < 2; ++u){
      float psum = 0.f;
      #pragma unroll
      for (int s = 0; s < 4; ++s){
        const float p0 = EXP2(sv[u][s][0]);
        const float p1 = EXP2(sv[u][s][1]);
        const float p2 = EXP2(sv[u][s][2]);
        const float p3 = EXP2(sv[u][s][3]);
        psum += (p0 + p1) + (p2 + p3);
        uint2 pk;
        pk.x = bfpk(p0, p1);
        pk.y = bfpk(p2, p3);
        *(uint2*)(Pw + (u*16 + c)*128
                  + ((((2*s + (g>>1)) ^ (c&7)) << 4) | ((g&1)*8))) = pk;
      }
      psum += __shfl_xor(psum, 16);
      psum += __shfl_xor(psum, 32);
      if (u == 0) l0 += psum; else l1 += psum;
    }

    // ---- PV: each vf feeds BOTH query halves ----
    __builtin_amdgcn_s_setprio(1);
    #pragma unroll
    for (int hh = 0; hh < 2; ++hh){
      short8 pf0 = *(const short8*)(Pw + (     c)*128 + (((hh*4 + g) ^ (c&7)) << 4));
      short8 pf1 = *(const short8*)(Pw + (16 + c)*128 + (((hh*4 + g) ^ (c&7)) << 4));
      #pragma unroll
      for (int D = 0; D < 4; ++D){
        short8 vf = *(const short8*)(Vc + (D*16 + c)*128 + ((hh*64 + g*16) ^ xr));
        o[0][D] = __builtin_amdgcn_mfma_f32_16x16x32_bf16(pf0, vf, o[0][D], 0, 0, 0);
        o[1][D] = __builtin_amdgcn_mfma_f32_16x16x32_bf16(pf1, vf, o[1][D], 0, 0, 0);
      }
    }
    __builtin_amdgcn_s_setprio(0);

    if (kt < 32){
      char* Kn = (char*)Kl[cur ^ 1];
      char* Vn = (char*)Vl[cur ^ 1];
      *(uint4*)(Kn + srow*128 + swz0) = rk0;
      *(uint4*)(Kn + srow*128 + swz1) = rk1;
      *(uint4*)(Vn + srow*128 + swz0) = rv0;
      *(uint4*)(Vn + srow*128 + swz1) = rv1;
      cur ^= 1;
    }
  }

  // ---- epilogue: normalize, write bf16 ao[b, n, h*64+d] ----
  #pragma unroll
  for (int u = 0; u < 2; ++u){
    const float inv = 1.f / (u ? l1 : l0);
    #pragma unroll
    for (int r = 0; r < 4; ++r){
      const float ir = __shfl(inv, g*4 + r, 16);
      const size_t nrow = (size_t)(b*N_) + qbase + u*16 + g*4 + r;
      #pragma unroll
      for (int D = 0; D < 4; ++D)
        aob[nrow * INNER + h*DH + D*16 + c] = bfc(o[u][D][r] * ir);
    }
  }
}

extern "C" void kernel_launch(void* const* d_in, const int* in_sizes, int n_in,
                              void* d_out, int out_size, void* d_ws, size_t ws_size,
                              hipStream_t stream)
{
  const float* x    = (const float*)d_in[0];
  const float* ctx  = (const float*)d_in[1];
  const float* Wq   = (const float*)d_in[2];
  const float* Wkv  = (const float*)d_in[3];
  const float* nk   = (const float*)d_in[4];
  const float* nv   = (const float*)d_in[5];
  const float* Wout = (const float*)d_in[6];
  const float* bout = (const float*)d_in[7];
  float* out = (float*)d_out;

  char* ws = (char*)d_ws;
  u16* qb    = (u16*)(ws);                       //  8,388,608
  u16* kbB   = (u16*)(ws +  8388608);            //  8,650,752
  u16* vbB   = (u16*)(ws + 17039360);            //  8,650,752
  u16* vtb   = (u16*)(ws + 25690112);            //  8,650,752
  u16* Wqt   = (u16*)(ws + 34340864);            //    524,288
  u16* Wkvt  = (u16*)(ws + 34865152);            //  1,048,576
  u16* Woutt = (u16*)(ws + 35913728);            //    524,288  (end ~36.4MB)
  u16* aoB   = vbB;                              // alias: vbB dead after vtrans

  // weight transposes (fp32 -> bf16 [N][K]), one dispatch
  transpose_all<<<dim3(16, 8, 3), 256, 0, stream>>>(Wq, Wkv, Wout, Wqt, Wkvt, Woutt);

  // fused q + kv projections (fp32 A converted in staging; depth-2 + dbuf)
  fused_proj<<<768, 256, 0, stream>>>(x, ctx, Wqt, Wkvt, qb, kbB, vbB);
  // v -> v^T [bh][d][m], fused null k/v fill
  vtrans<<<dim3(33, 32), 256, 0, stream>>>(vbB, vtb, nk, nv, kbB);
  // MFMA flash attention, Q32/wave -> ao bf16 (aliases vbB)
  attn_mfma<<<dim3(16, 32), 256, 0, stream>>>(qb, kbB, vtb, aoB);
  // out = ao @ Wout + bout (depth-2 prefetch, fp32 out)
  mgemm_out<<<256, 256, 0, stream>>>(aoB, Woutt, out, bout);
}

// Round 12
// 113.868 us; speedup vs baseline: 12.2768x; 1.0273x over previous
//
#include <hip/hip_runtime.h>
#include <hip/hip_bf16.h>
#include <stdint.h>

#define B_    4
#define N_    2048
#define M_    2048
#define DIMX  512
#define INNER 512
#define H_    8
#define DH    64
#define MK    2049   // M+1 keys (null token at slot 0)
#define MKP   2112   // padded to 33 tiles of 64 (tail masked in-kernel)

#define QSCALE  0.18033688011f   // 0.125 * log2(e): softmax in exp2 domain
#define SM_BIAS -11.5415605f     // static softmax max: |S_log2| <= 64*QSCALE

using u16 = unsigned short;
using u32 = unsigned int;

typedef __attribute__((ext_vector_type(8))) short short8;
typedef __attribute__((ext_vector_type(4))) float f32x4;

#if defined(__has_builtin)
# if __has_builtin(__builtin_amdgcn_exp2f)
#  define EXP2(x) __builtin_amdgcn_exp2f(x)
# endif
#endif
#ifndef EXP2
# define EXP2(x) exp2f(x)
#endif

__device__ __forceinline__ u16 bfc(float f){
  __hip_bfloat16 h = __float2bfloat16(f);
  return *reinterpret_cast<u16*>(&h);
}
__device__ __forceinline__ u32 bfpk(float lo, float hi){
  return (u32)bfc(lo) | ((u32)bfc(hi) << 16);
}

// ---------------------------------------------------------------------------
// fp32 -> bf16 streaming convert for x (z=0) and ctx (z=1). 8 elems/thread.
// Keeping this as a SEPARATE pass is deliberate (r11 lesson): the cold 32MB
// HBM read happens here at streaming BW; fused_proj then reads L3-warm bf16.
// Fusing it into the GEMM costs 55 us of unhideable latency for 10 us saved.
// ---------------------------------------------------------------------------
__global__ __launch_bounds__(256) void convert_bf(
    const float* __restrict__ x, const float* __restrict__ ctx,
    u16* __restrict__ xb, u16* __restrict__ cb)
{
  const float* in = blockIdx.z ? ctx : x;
  u16* out        = blockIdx.z ? cb : xb;
  const int i = blockIdx.x * 256 + threadIdx.x;   // 524288 threads = 4M elems
  float4 a = ((const float4*)in)[i*2];
  float4 b = ((const float4*)in)[i*2+1];
  uint4 t;
  t.x = bfpk(a.x, a.y); t.y = bfpk(a.z, a.w);
  t.z = bfpk(b.x, b.y); t.w = bfpk(b.z, b.w);
  ((uint4*)out)[i] = t;
}

// ---------------------------------------------------------------------------
// All three weight transposes in one dispatch: fp32 [R][C] -> bf16 [C][R].
// ---------------------------------------------------------------------------
__global__ __launch_bounds__(256) void transpose_all(
    const float* __restrict__ Wq, const float* __restrict__ Wkv,
    const float* __restrict__ Wout,
    u16* __restrict__ Wqt, u16* __restrict__ Wkvt, u16* __restrict__ Woutt)
{
  const int z = blockIdx.z;
  const float* in = (z == 0) ? Wq : (z == 1) ? Wkv : Wout;
  u16* out        = (z == 0) ? Wqt : (z == 1) ? Wkvt : Woutt;
  const int C     = (z == 1) ? 1024 : 512;   // R = 512 for all
  const int R     = 512;
  if (blockIdx.x * 64 >= C) return;

  __shared__ float tl[64][65];
  const int t = threadIdx.x;
  const int c0 = blockIdx.x * 64, r0 = blockIdx.y * 64;
  const int col = t & 63, rb = t >> 6;
  #pragma unroll
  for (int j = 0; j < 16; ++j){
    const int row = rb + j*4;
    tl[row][col] = in[(size_t)(r0 + row) * C + c0 + col];
  }
  __syncthreads();
  #pragma unroll
  for (int j = 0; j < 16; ++j){
    const int orow = rb + j*4;
    out[(size_t)(c0 + orow) * R + r0 + col] = bfc(tl[col][orow]);
  }
}

// frag-read + 16 MFMA from LDS buffer `bi` (compile-time)
#define PROJ_COMPUTE(bi)                                                      \
  {                                                                           \
    short8 af[4], bf[4];                                                      \
    _Pragma("unroll")                                                         \
    for (int m = 0; m < 4; ++m){                                              \
      const int row = wr + m*16 + c;                                          \
      af[m] = *(const short8*)((char*)At[bi] + row*64 + ((g ^ ((row>>1)&3)) << 4)); \
    }                                                                         \
    _Pragma("unroll")                                                         \
    for (int n = 0; n < 4; ++n){                                              \
      const int row = wc + n*16 + c;                                          \
      bf[n] = *(const short8*)((char*)Bl[bi] + row*64 + ((g ^ ((row>>1)&3)) << 4)); \
    }                                                                         \
    __builtin_amdgcn_s_setprio(1);                                            \
    _Pragma("unroll")                                                         \
    for (int m = 0; m < 4; ++m)                                               \
      _Pragma("unroll")                                                       \
      for (int n = 0; n < 4; ++n)                                             \
        acc[m][n] = __builtin_amdgcn_mfma_f32_16x16x32_bf16(af[m], bf[n], acc[m][n], 0, 0, 0); \
    __builtin_amdgcn_s_setprio(0);                                            \
  }

// ---------------------------------------------------------------------------
// Fused q + kv projection GEMM, all-bf16 inputs. 768 blocks (XCD-chunked):
// tile<256 -> q (gx=4), else kv (gx=8). 128x128 tile, BK=32, 16 K-steps.
// Depth-2 register prefetch + double-buffered LDS.
// ---------------------------------------------------------------------------
__global__ __launch_bounds__(256, 3) void fused_proj(
    const u16* __restrict__ xb, const u16* __restrict__ cb,
    const u16* __restrict__ Wqt, const u16* __restrict__ Wkvt,
    u16* __restrict__ qb, u16* __restrict__ kb, u16* __restrict__ vb)
{
  __shared__ __align__(16) short At[2][128*32];
  __shared__ __align__(16) short Bl[2][128*32];

  const int flat = blockIdx.x;
  const int tile = (flat & 7) * 96 + (flat >> 3);    // XCD-chunked, bijective
  const bool isq = tile < 256;
  const int lt   = isq ? tile : tile - 256;
  const int gx   = isq ? 4 : 8;
  const int row0 = (lt / gx) * 128, col0 = (lt % gx) * 128;
  const u16* A  = isq ? xb : cb;
  const u16* Bt = isq ? Wqt : Wkvt;

  const int tid = threadIdx.x;
  const int w = tid >> 6, lane = tid & 63;
  const int c = lane & 15, g = lane >> 4;
  const int wr = (w >> 1) * 64, wc = (w & 1) * 64;

  f32x4 acc[4][4] = {};

  const int srow = tid >> 1, sj = (tid & 1) * 2;
  const int swz0 = ((sj  ) ^ ((srow >> 1) & 3)) << 4;
  const int swz1 = ((sj+1) ^ ((srow >> 1) & 3)) << 4;

  const u16* asrc = A  + (size_t)(row0 + srow) * DIMX + sj*8;
  const u16* bsrc = Bt + (size_t)(col0 + srow) * DIMX + sj*8;

  uint4 aA0, aA1, bA0, bA1;      // slot A
  uint4 aB0, aB1, bB0, bB1;      // slot B

  // prologue: tiles 0 (slot A) and 1 (slot B) both in flight
  aA0 = ((const uint4*)asrc)[0];        aA1 = ((const uint4*)asrc)[1];
  bA0 = ((const uint4*)bsrc)[0];        bA1 = ((const uint4*)bsrc)[1];
  aB0 = ((const uint4*)(asrc + 32))[0]; aB1 = ((const uint4*)(asrc + 32))[1];
  bB0 = ((const uint4*)(bsrc + 32))[0]; bB1 = ((const uint4*)(bsrc + 32))[1];
  *(uint4*)((char*)At[0] + srow*64 + swz0) = aA0;
  *(uint4*)((char*)At[0] + srow*64 + swz1) = aA1;
  *(uint4*)((char*)Bl[0] + srow*64 + swz0) = bA0;
  *(uint4*)((char*)Bl[0] + srow*64 + swz1) = bA1;

  for (int kk = 0; kk < 16; kk += 2){
    // ---- even: compute buf0 (tile kk); issue kk+2 -> slot A; write slot B -> buf1
    __syncthreads();
    if (kk + 2 < 16){
      const u16* an = asrc + (kk+2)*32;
      const u16* bn = bsrc + (kk+2)*32;
      aA0 = ((const uint4*)an)[0]; aA1 = ((const uint4*)an)[1];
      bA0 = ((const uint4*)bn)[0]; bA1 = ((const uint4*)bn)[1];
    }
    PROJ_COMPUTE(0);
    *(uint4*)((char*)At[1] + srow*64 + swz0) = aB0;   // tile kk+1 (always valid)
    *(uint4*)((char*)At[1] + srow*64 + swz1) = aB1;
    *(uint4*)((char*)Bl[1] + srow*64 + swz0) = bB0;
    *(uint4*)((char*)Bl[1] + srow*64 + swz1) = bB1;

    // ---- odd: compute buf1 (tile kk+1); issue kk+3 -> slot B; write slot A -> buf0
    __syncthreads();
    if (kk + 3 < 16){
      const u16* an = asrc + (kk+3)*32;
      const u16* bn = bsrc + (kk+3)*32;
      aB0 = ((const uint4*)an)[0]; aB1 = ((const uint4*)an)[1];
      bB0 = ((const uint4*)bn)[0]; bB1 = ((const uint4*)bn)[1];
    }
    PROJ_COMPUTE(1);
    if (kk + 2 < 16){
      *(uint4*)((char*)At[0] + srow*64 + swz0) = aA0; // tile kk+2
      *(uint4*)((char*)At[0] + srow*64 + swz1) = aA1;
      *(uint4*)((char*)Bl[0] + srow*64 + swz0) = bA0;
      *(uint4*)((char*)Bl[0] + srow*64 + swz1) = bA1;
    }
  }

  #pragma unroll
  for (int m = 0; m < 4; ++m){
    #pragma unroll
    for (int n = 0; n < 4; ++n){
      #pragma unroll
      for (int rr = 0; rr < 4; ++rr){
        const int R = row0 + wr + m*16 + g*4 + rr;
        const int col = col0 + wc + n*16 + c;
        const float v = acc[m][n][rr];
        if (isq){
          qb[(size_t)R * INNER + col] = bfc(tanhf(v) * QSCALE);
        } else {
          const int bidx = R >> 11, mm = R & 2047;
          if (col < INNER){
            const int h = col >> 6, d = col & 63;
            kb[((size_t)(bidx*H_ + h) * MKP + (mm + 1)) * DH + d] = bfc(tanhf(v));
          } else {
            const int cc = col - INNER;
            const int h = cc >> 6, d = cc & 63;
            vb[((size_t)(bidx*H_ + h) * MKP + (mm + 1)) * DH + d] = bfc(v);
          }
        }
      }
    }
  }
}

// ---------------------------------------------------------------------------
// Out-projection GEMM: out = ao @ Wout^T + bias. Same depth-2 pipeline.
// ---------------------------------------------------------------------------
__global__ __launch_bounds__(256, 3) void mgemm_out(
    const u16* __restrict__ A, const u16* __restrict__ Bt,
    float* __restrict__ Cf, const float* __restrict__ bias)
{
  __shared__ __align__(16) short At[2][128*32];
  __shared__ __align__(16) short Bl[2][128*32];

  const int flat = blockIdx.x;                       // 256 blocks
  const int tile = (flat & 7) * 32 + (flat >> 3);    // XCD-chunked
  const int row0 = (tile >> 2) * 128, col0 = (tile & 3) * 128;

  const int tid = threadIdx.x;
  const int w = tid >> 6, lane = tid & 63;
  const int c = lane & 15, g = lane >> 4;
  const int wr = (w >> 1) * 64, wc = (w & 1) * 64;

  f32x4 acc[4][4] = {};

  const int srow = tid >> 1, sj = (tid & 1) * 2;
  const int swz0 = ((sj  ) ^ ((srow >> 1) & 3)) << 4;
  const int swz1 = ((sj+1) ^ ((srow >> 1) & 3)) << 4;

  const u16* asrc = A  + (size_t)(row0 + srow) * INNER + sj*8;
  const u16* bsrc = Bt + (size_t)(col0 + srow) * INNER + sj*8;

  uint4 aA0, aA1, bA0, bA1;
  uint4 aB0, aB1, bB0, bB1;

  aA0 = ((const uint4*)asrc)[0];        aA1 = ((const uint4*)asrc)[1];
  bA0 = ((const uint4*)bsrc)[0];        bA1 = ((const uint4*)bsrc)[1];
  aB0 = ((const uint4*)(asrc + 32))[0]; aB1 = ((const uint4*)(asrc + 32))[1];
  bB0 = ((const uint4*)(bsrc + 32))[0]; bB1 = ((const uint4*)(bsrc + 32))[1];
  *(uint4*)((char*)At[0] + srow*64 + swz0) = aA0;
  *(uint4*)((char*)At[0] + srow*64 + swz1) = aA1;
  *(uint4*)((char*)Bl[0] + srow*64 + swz0) = bA0;
  *(uint4*)((char*)Bl[0] + srow*64 + swz1) = bA1;

  for (int kk = 0; kk < 16; kk += 2){
    __syncthreads();
    if (kk + 2 < 16){
      const u16* an = asrc + (kk+2)*32;
      const u16* bn = bsrc + (kk+2)*32;
      aA0 = ((const uint4*)an)[0]; aA1 = ((const uint4*)an)[1];
      bA0 = ((const uint4*)bn)[0]; bA1 = ((const uint4*)bn)[1];
    }
    PROJ_COMPUTE(0);
    *(uint4*)((char*)At[1] + srow*64 + swz0) = aB0;
    *(uint4*)((char*)At[1] + srow*64 + swz1) = aB1;
    *(uint4*)((char*)Bl[1] + srow*64 + swz0) = bB0;
    *(uint4*)((char*)Bl[1] + srow*64 + swz1) = bB1;

    __syncthreads();
    if (kk + 3 < 16){
      const u16* an = asrc + (kk+3)*32;
      const u16* bn = bsrc + (kk+3)*32;
      aB0 = ((const uint4*)an)[0]; aB1 = ((const uint4*)an)[1];
      bB0 = ((const uint4*)bn)[0]; bB1 = ((const uint4*)bn)[1];
    }
    PROJ_COMPUTE(1);
    if (kk + 2 < 16){
      *(uint4*)((char*)At[0] + srow*64 + swz0) = aA0;
      *(uint4*)((char*)At[0] + srow*64 + swz1) = aA1;
      *(uint4*)((char*)Bl[0] + srow*64 + swz0) = bA0;
      *(uint4*)((char*)Bl[0] + srow*64 + swz1) = bA1;
    }
  }

  #pragma unroll
  for (int m = 0; m < 4; ++m){
    #pragma unroll
    for (int n = 0; n < 4; ++n){
      #pragma unroll
      for (int rr = 0; rr < 4; ++rr){
        const int R = row0 + wr + m*16 + g*4 + rr;
        const int col = col0 + wc + n*16 + c;
        Cf[(size_t)R * 512 + col] = acc[m][n][rr] + bias[col];
      }
    }
  }
}

// ---------------------------------------------------------------------------
// v [bh][m][d] bf16 -> vt [bh][d][m] bf16, 64x64 tiles per bh.
// Fused null-token fill (mt==0 blocks).
// ---------------------------------------------------------------------------
__global__ __launch_bounds__(256) void vtrans(
    const u16* __restrict__ vb, u16* __restrict__ vt,
    const float* __restrict__ nk, const float* __restrict__ nv,
    u16* __restrict__ kb)
{
  __shared__ short tl[64][72];
  const int t = threadIdx.x;
  const int mt = blockIdx.x, bh = blockIdx.y;
  {
    const int mr = t >> 2, chb = (t & 3) * 2;
    const u16* src = vb + ((size_t)bh * MKP + mt*64 + mr) * DH + chb*8;
    uint4 a = ((const uint4*)src)[0];
    uint4 b = ((const uint4*)src)[1];
    *(uint4*)((char*)tl + mr*144 + chb*16)     = a;
    *(uint4*)((char*)tl + mr*144 + (chb+1)*16) = b;
  }
  __syncthreads();
  {
    const int d = t >> 2, chb = (t & 3) * 2;
    #pragma unroll
    for (int j = 0; j < 2; ++j){
      const int mbase = (chb + j) * 8;
      u16 s[8];
      #pragma unroll
      for (int e = 0; e < 8; ++e) s[e] = (u16)tl[mbase + e][d];
      if (mt == 0 && mbase == 0) s[0] = bfc(nv[d]);   // null v at key 0
      uint4 o;
      o.x = (u32)s[0] | ((u32)s[1] << 16);
      o.y = (u32)s[2] | ((u32)s[3] << 16);
      o.z = (u32)s[4] | ((u32)s[5] << 16);
      o.w = (u32)s[6] | ((u32)s[7] << 16);
      *(uint4*)(vt + ((size_t)bh * DH + d) * MKP + mt*64 + mbase) = o;
    }
    if (mt == 0 && (t & 3) == 0)                      // null k at key 0
      kb[(size_t)bh * MKP * DH + d] = bfc(tanhf(nk[d]));
  }
}

// ---------------------------------------------------------------------------
// MFMA flash attention, Q32-per-wave (r11 win: -45 us vs Q16). 4 waves x 32
// query rows, KVBLK=64, grid (16,32). Each K/V LDS fragment read once feeds
// TWO MFMAs. Static softmax max in MFMA C-init; p = exp2(sv). K/V/P in 128B
// XOR-swizzled rows, dbuf K/V.
// ---------------------------------------------------------------------------
__global__ __launch_bounds__(256) void attn_mfma(
    const u16* __restrict__ qb, const u16* __restrict__ kb,
    const u16* __restrict__ vt, u16* __restrict__ aob)
{
  __shared__ __align__(16) short Kl[2][64*64];   // 16KB [key][dim] swizzled
  __shared__ __align__(16) short Vl[2][64*64];   // 16KB [dim][key] swizzled
  __shared__ __align__(16) short Pl[4][32*64];   // 16KB per-wave [32q][64k]

  const int tid  = threadIdx.x;
  const int w    = tid >> 6;
  const int lane = tid & 63;
  const int c    = lane & 15;
  const int g    = lane >> 4;
  const int bh   = blockIdx.y, b = bh >> 3, h = bh & 7;
  const int qbase = blockIdx.x * 128 + w * 32;
  const int xr   = (c & 7) << 4;

  short8 qf[2][2];
  #pragma unroll
  for (int u = 0; u < 2; ++u){
    const u16* qrow = qb + ((size_t)(b*N_) + qbase + u*16 + c) * INNER + h * DH;
    qf[u][0] = *(const short8*)(qrow + g*8);
    qf[u][1] = *(const short8*)(qrow + 32 + g*8);
  }

  f32x4 o[2][4] = {};              // [qhalf][dimblock]: row=q g*4+r, col=dim c
  float l0 = 0.f, l1 = 0.f;

  const u16* kbase = kb + (size_t)bh * MKP * DH;
  const u16* vbase = vt + (size_t)bh * DH * MKP;
  const int srow = tid >> 2, sch = (tid & 3) * 2;
  const int swz0 = ((sch  ) ^ (srow & 7)) << 4;
  const int swz1 = ((sch+1) ^ (srow & 7)) << 4;

  uint4 rk0, rk1, rv0, rv1;
  {
    const u16* ksrc = kbase + (size_t)srow * DH + sch*8;
    rk0 = ((const uint4*)ksrc)[0]; rk1 = ((const uint4*)ksrc)[1];
    const u16* vsrc = vbase + (size_t)srow * MKP + sch*8;
    rv0 = ((const uint4*)vsrc)[0]; rv1 = ((const uint4*)vsrc)[1];
  }
  *(uint4*)((char*)Kl[0] + srow*128 + swz0) = rk0;
  *(uint4*)((char*)Kl[0] + srow*128 + swz1) = rk1;
  *(uint4*)((char*)Vl[0] + srow*128 + swz0) = rv0;
  *(uint4*)((char*)Vl[0] + srow*128 + swz1) = rv1;

  int cur = 0;
  for (int kt = 0; kt < 33; ++kt){
    __syncthreads();
    if (kt < 32){
      const u16* ksrc = kbase + (size_t)((kt+1)*64 + srow) * DH + sch*8;
      rk0 = ((const uint4*)ksrc)[0]; rk1 = ((const uint4*)ksrc)[1];
      const u16* vsrc = vbase + (size_t)srow * MKP + (kt+1)*64 + sch*8;
      rv0 = ((const uint4*)vsrc)[0]; rv1 = ((const uint4*)vsrc)[1];
    }

    const char* Kc = (const char*)Kl[cur];
    const char* Vc = (const char*)Vl[cur];
    char*       Pw = (char*)Pl + w*4096;

    // ---- swapped QK^T: each kf pair feeds BOTH query halves ----
    f32x4 sv[2][4];
    __builtin_amdgcn_s_setprio(1);
    #pragma unroll
    for (int s = 0; s < 4; ++s){
      const int row = s*16 + c;
      short8 kf0 = *(const short8*)(Kc + row*128 + ((     g*16) ^ xr));
      short8 kf1 = *(const short8*)(Kc + row*128 + ((64 + g*16) ^ xr));
      f32x4 a0 = {SM_BIAS, SM_BIAS, SM_BIAS, SM_BIAS};
      f32x4 a1 = {SM_BIAS, SM_BIAS, SM_BIAS, SM_BIAS};
      a0 = __builtin_amdgcn_mfma_f32_16x16x32_bf16(kf0, qf[0][0], a0, 0, 0, 0);
      a1 = __builtin_amdgcn_mfma_f32_16x16x32_bf16(kf0, qf[1][0], a1, 0, 0, 0);
      a0 = __builtin_amdgcn_mfma_f32_16x16x32_bf16(kf1, qf[0][1], a0, 0, 0, 0);
      a1 = __builtin_amdgcn_mfma_f32_16x16x32_bf16(kf1, qf[1][1], a1, 0, 0, 0);
      sv[0][s] = a0; sv[1][s] = a1;
    }
    __builtin_amdgcn_s_setprio(0);

    if (kt == 32){                    // only key 2048 (tile-local 0) is valid
      #pragma unroll
      for (int u = 0; u < 2; ++u)
        #pragma unroll
        for (int s = 0; s < 4; ++s)
          #pragma unroll
          for (int r = 0; r < 4; ++r)
            if (s | r) sv[u][s][r] = -1e30f;
      if (g){ sv[0][0][0] = -1e30f; sv[1][0][0] = -1e30f; }
    }

    // ---- softmax numerators (static max): p = exp2(sv), P -> LDS bf16 ----
    #pragma unroll
    for (int u = 0; u < 2; ++u){
      float psum = 0.f;
      #pragma unroll
      for (int s = 0; s < 4; ++s){
        const float p0 = EXP2(sv[u][s][0]);
        const float p1 = EXP2(sv[u][s][1]);
        const float p2 = EXP2(sv[u][s][2]);
        const float p3 = EXP2(sv[u][s][3]);
        psum += (p0 + p1) + (p2 + p3);
        uint2 pk;
        pk.x = bfpk(p0, p1);
        pk.y = bfpk(p2, p3);
        *(uint2*)(Pw + (u*16 + c)*128
                  + ((((2*s + (g>>1)) ^ (c&7)) << 4) | ((g&1)*8))) = pk;
      }
      psum += __shfl_xor(psum, 16);
      psum += __shfl_xor(psum, 32);
      if (u == 0) l0 += psum; else l1 += psum;
    }

    // ---- PV: each vf feeds BOTH query halves ----
    __builtin_amdgcn_s_setprio(1);
    #pragma unroll
    for (int hh = 0; hh < 2; ++hh){
      short8 pf0 = *(const short8*)(Pw + (     c)*128 + (((hh*4 + g) ^ (c&7)) << 4));
      short8 pf1 = *(const short8*)(Pw + (16 + c)*128 + (((hh*4 + g) ^ (c&7)) << 4));
      #pragma unroll
      for (int D = 0; D < 4; ++D){
        short8 vf = *(const short8*)(Vc + (D*16 + c)*128 + ((hh*64 + g*16) ^ xr));
        o[0][D] = __builtin_amdgcn_mfma_f32_16x16x32_bf16(pf0, vf, o[0][D], 0, 0, 0);
        o[1][D] = __builtin_amdgcn_mfma_f32_16x16x32_bf16(pf1, vf, o[1][D], 0, 0, 0);
      }
    }
    __builtin_amdgcn_s_setprio(0);

    if (kt < 32){
      char* Kn = (char*)Kl[cur ^ 1];
      char* Vn = (char*)Vl[cur ^ 1];
      *(uint4*)(Kn + srow*128 + swz0) = rk0;
      *(uint4*)(Kn + srow*128 + swz1) = rk1;
      *(uint4*)(Vn + srow*128 + swz0) = rv0;
      *(uint4*)(Vn + srow*128 + swz1) = rv1;
      cur ^= 1;
    }
  }

  // ---- epilogue: normalize, write bf16 ao[b, n, h*64+d] ----
  #pragma unroll
  for (int u = 0; u < 2; ++u){
    const float inv = 1.f / (u ? l1 : l0);
    #pragma unroll
    for (int r = 0; r < 4; ++r){
      const float ir = __shfl(inv, g*4 + r, 16);
      const size_t nrow = (size_t)(b*N_) + qbase + u*16 + g*4 + r;
      #pragma unroll
      for (int D = 0; D < 4; ++D)
        aob[nrow * INNER + h*DH + D*16 + c] = bfc(o[u][D][r] * ir);
    }
  }
}

extern "C" void kernel_launch(void* const* d_in, const int* in_sizes, int n_in,
                              void* d_out, int out_size, void* d_ws, size_t ws_size,
                              hipStream_t stream)
{
  const float* x    = (const float*)d_in[0];
  const float* ctx  = (const float*)d_in[1];
  const float* Wq   = (const float*)d_in[2];
  const float* Wkv  = (const float*)d_in[3];
  const float* nk   = (const float*)d_in[4];
  const float* nv   = (const float*)d_in[5];
  const float* Wout = (const float*)d_in[6];
  const float* bout = (const float*)d_in[7];
  float* out = (float*)d_out;

  char* ws = (char*)d_ws;
  u16* xb    = (u16*)(ws);                       //  8,388,608
  u16* cb    = (u16*)(ws +  8388608);            //  8,388,608
  u16* qb    = (u16*)(ws + 16777216);            //  8,388,608
  u16* kbB   = (u16*)(ws + 25165824);            //  8,650,752
  u16* vbB   = (u16*)(ws + 33816576);            //  8,650,752
  u16* vtb   = (u16*)(ws + 42467328);            //  8,650,752
  u16* Wqt   = (u16*)(ws + 51118080);            //    524,288
  u16* Wkvt  = (u16*)(ws + 51642368);            //  1,048,576
  u16* Woutt = (u16*)(ws + 52690944);            //    524,288  (end ~53.2MB)
  u16* aoB   = vbB;                              // alias: vbB dead after vtrans

  // x/ctx -> bf16 (streaming pass; leaves bf16 L3-warm), weight transposes
  convert_bf<<<dim3(2048, 1, 2), 256, 0, stream>>>(x, ctx, xb, cb);
  transpose_all<<<dim3(16, 8, 3), 256, 0, stream>>>(Wq, Wkv, Wout, Wqt, Wkvt, Woutt);

  // fused q + kv projections (bf16 inputs, depth-2 prefetch + dbuf + swizzle)
  fused_proj<<<768, 256, 0, stream>>>(xb, cb, Wqt, Wkvt, qb, kbB, vbB);
  // v -> v^T [bh][d][m], fused null k/v fill
  vtrans<<<dim3(33, 32), 256, 0, stream>>>(vbB, vtb, nk, nv, kbB);
  // MFMA flash attention, Q32/wave -> ao bf16 (aliases vbB)
  attn_mfma<<<dim3(16, 32), 256, 0, stream>>>(qb, kbB, vtb, aoB);
  // out = ao @ Wout + bout (depth-2 prefetch, fp32 out)
  mgemm_out<<<256, 256, 0, stream>>>(aoB, Woutt, out, bout);
}